// Round 5
// baseline (702.715 us; speedup 1.0000x reference)
//
#include <hip/hip_runtime.h>

#define NB 4096      // N = H*W
#define BATCH 4
#define CD 256       // channels
#define ED 64        // embedding dim
#define KNN 24

typedef __attribute__((ext_vector_type(8))) short bf16x8;
typedef __attribute__((ext_vector_type(4))) float f32x4;

__device__ __forceinline__ unsigned short f2bf(float x) {
  unsigned u = __float_as_uint(x);
  unsigned r = (u + 0x7fffu + ((u >> 16) & 1u)) >> 16;
  return (unsigned short)r;
}

// ---------------- K1: emb = x @ dist_w^T  -> emb_hl (bf16 hi/lo, XOR-swizzled chunks) + sq (fp32)
// Also inits thr_g (per-row global kNN threshold) to bits(100.0f).
__global__ __launch_bounds__(256) void k_emb(const float* __restrict__ x,
                                             const float* __restrict__ dist_w,
                                             unsigned* __restrict__ emb_hl,
                                             float* __restrict__ sq,
                                             unsigned* __restrict__ thr_g) {
  __shared__ float wds[ED * CD];   // 64 KB
  __shared__ float red[64 * 4];
  const int b = blockIdx.x >> 6;
  const int n0 = (blockIdx.x & 63) << 6;
  const int tid = threadIdx.x;
  const float4* wsrc = (const float4*)dist_w;
  float4* wdst = (float4*)wds;
#pragma unroll
  for (int k = 0; k < 16; ++k) wdst[tid + 256 * k] = wsrc[tid + 256 * k];
  __syncthreads();
  const int eg = tid >> 6;   // 0..3
  const int nl = tid & 63;
  const int n = n0 + nl;
  float acc[16];
#pragma unroll
  for (int t = 0; t < 16; ++t) acc[t] = 0.f;
  const float* xb = x + (size_t)b * CD * NB + n;
#pragma unroll 2
  for (int c4 = 0; c4 < CD; c4 += 4) {
    float x0 = xb[(size_t)(c4 + 0) * NB];
    float x1 = xb[(size_t)(c4 + 1) * NB];
    float x2 = xb[(size_t)(c4 + 2) * NB];
    float x3 = xb[(size_t)(c4 + 3) * NB];
#pragma unroll
    for (int t = 0; t < 16; ++t) {
      float4 wv = *(const float4*)&wds[(eg * 16 + t) * CD + c4];
      acc[t] = fmaf(x0, wv.x, acc[t]);
      acc[t] = fmaf(x1, wv.y, acc[t]);
      acc[t] = fmaf(x2, wv.z, acc[t]);
      acc[t] = fmaf(x3, wv.w, acc[t]);
    }
  }
  float s = 0.f;
#pragma unroll
  for (int t = 0; t < 16; ++t) s = fmaf(acc[t], acc[t], s);
  unsigned hw[8], lw[8];
#pragma unroll
  for (int i = 0; i < 8; ++i) {
    unsigned short h0 = f2bf(acc[2 * i]);
    unsigned short h1 = f2bf(acc[2 * i + 1]);
    float l0f = acc[2 * i] - __uint_as_float((unsigned)h0 << 16);
    float l1f = acc[2 * i + 1] - __uint_as_float((unsigned)h1 << 16);
    hw[i] = (unsigned)h0 | ((unsigned)h1 << 16);
    lw[i] = (unsigned)f2bf(l0f) | ((unsigned)f2bf(l1f) << 16);
  }
  uint4* g = (uint4*)emb_hl;
  const size_t gb = ((size_t)(b * NB + n)) * 16;
  const int k15 = n & 15;
  g[gb + ((2 * eg) ^ k15)]     = make_uint4(hw[0], hw[1], hw[2], hw[3]);
  g[gb + ((2 * eg + 1) ^ k15)] = make_uint4(hw[4], hw[5], hw[6], hw[7]);
  g[gb + ((8 + 2 * eg) ^ k15)]     = make_uint4(lw[0], lw[1], lw[2], lw[3]);
  g[gb + ((8 + 2 * eg + 1) ^ k15)] = make_uint4(lw[4], lw[5], lw[6], lw[7]);
  red[nl * 4 + eg] = s;
  __syncthreads();
  if (tid < 64) {
    sq[b * NB + n0 + tid] = red[tid * 4] + red[tid * 4 + 1] + red[tid * 4 + 2] + red[tid * 4 + 3];
    thr_g[(b << 12) + n0 + tid] = 0x42C80000u;  // bits(100.0f)
  }
}

// ---------------- K2: X_lin[b,n,c] = sum_k x[b,k,n]*fc_w[c,k] + fc_b[c]
__global__ __launch_bounds__(256) void k_xlin(const float* __restrict__ x,
                                              const float* __restrict__ fc_w,
                                              const float* __restrict__ fc_b,
                                              float* __restrict__ xlin) {
  __shared__ float xt[64 * 64];     // [k][n]
  __shared__ float wt[64 * 260];    // [k][c] padded
  const int b = blockIdx.x >> 6;
  const int n0 = (blockIdx.x & 63) << 6;
  const int tid = threadIdx.x;
  const int nl4 = tid & 15;
  const int cg = tid >> 4;
  float acc[4][16];
#pragma unroll
  for (int i = 0; i < 4; ++i)
#pragma unroll
    for (int j = 0; j < 16; ++j) acc[i][j] = 0.f;

  for (int kt = 0; kt < 4; ++kt) {
    __syncthreads();
#pragma unroll 4
    for (int i = 0; i < 16; ++i) {
      int idx = tid + 256 * i;
      int k = idx >> 6, n = idx & 63;
      xt[idx] = x[((size_t)(b * CD + kt * 64 + k)) * NB + n0 + n];
    }
#pragma unroll 4
    for (int i = 0; i < 16; ++i) {
      int q = tid + 256 * i;
      int c = q >> 4, k4 = (q & 15) * 4;
      float4 v = *(const float4*)&fc_w[(size_t)c * CD + kt * 64 + k4];
      wt[(k4 + 0) * 260 + c] = v.x;
      wt[(k4 + 1) * 260 + c] = v.y;
      wt[(k4 + 2) * 260 + c] = v.z;
      wt[(k4 + 3) * 260 + c] = v.w;
    }
    __syncthreads();
#pragma unroll 2
    for (int k = 0; k < 64; ++k) {
      float4 xv = *(const float4*)&xt[k * 64 + 4 * nl4];
#pragma unroll
      for (int j = 0; j < 4; ++j) {
        float4 wv = *(const float4*)&wt[k * 260 + 4 * cg + 64 * j];
        const float* wp = &wv.x;
#pragma unroll
        for (int l = 0; l < 4; ++l) {
          acc[0][4 * j + l] = fmaf(xv.x, wp[l], acc[0][4 * j + l]);
          acc[1][4 * j + l] = fmaf(xv.y, wp[l], acc[1][4 * j + l]);
          acc[2][4 * j + l] = fmaf(xv.z, wp[l], acc[2][4 * j + l]);
          acc[3][4 * j + l] = fmaf(xv.w, wp[l], acc[3][4 * j + l]);
        }
      }
    }
  }
#pragma unroll
  for (int i = 0; i < 4; ++i) {
    int n = n0 + 4 * nl4 + i;
    float* dst = xlin + ((size_t)(b * NB + n)) * CD;
#pragma unroll
    for (int j = 0; j < 4; ++j) {
      int c = 4 * cg + 64 * j;
      float4 bv = *(const float4*)&fc_b[c];
      float4 o;
      o.x = acc[i][4 * j + 0] + bv.x;
      o.y = acc[i][4 * j + 1] + bv.y;
      o.z = acc[i][4 * j + 2] + bv.z;
      o.w = acc[i][4 * j + 3] + bv.w;
      *(float4*)&dst[c] = o;
    }
  }
}

// insert p into sorted 24-list (ascending, strict compares -> stable, exact)
#define INSERT24(p)                                        \
  if ((p) < lst[23]) {                                     \
    lst[23] = (p);                                         \
    _Pragma("unroll")                                      \
    for (int t = 23; t >= 1; --t) {                        \
      unsigned long long a_ = lst[t - 1], b_ = lst[t];     \
      bool sw_ = b_ < a_;                                  \
      lst[t - 1] = sw_ ? b_ : a_;                          \
      lst[t] = sw_ ? a_ : b_;                              \
    }                                                      \
  }

// 8-slot flush: bodies issue only up to wave-max qc; per-lane arrival order preserved
#define FLUSH8()                                           \
  {                                                        \
    if (qc > 0) { INSERT24(q0) }                           \
    if (qc > 1) { INSERT24(q1) }                           \
    if (qc > 2) { INSERT24(q2) }                           \
    if (qc > 3) { INSERT24(q3) }                           \
    if (qc > 4) { INSERT24(q4) }                           \
    if (qc > 5) { INSERT24(q5) }                           \
    if (qc > 6) { INSERT24(q6) }                           \
    if (qc > 7) { INSERT24(q7) }                           \
    qc = 0;                                                \
    atomicMin(&thr[dr], (unsigned)(lst[23] >> 32));        \
  }

// ---------------- K3 v14 = v13 + adaptive flush depth.
// Measured (v13 PMC): ~85% of k_distp VALU = INSERT24 flush bodies; late-chunk events
// are sparse-but-spread accepts where any single lane hitting 4 forces a wave-wide
// 4-body issue. Fix: chunks 0-2 keep flush@qc>=4 (this cadence populates lst[23] ->
// atomicMin(thr), the main measured bound-tightener); chunks 3-7 (bounds converged)
// flush only at qc>=8; leftovers drain in ONE final post-loop flush (off the per-chunk
// critical path -- v11's mistake). Per-lane insert order unchanged -> selection
// BIT-IDENTICAL (absmax tripwire 0.0546875).
__global__ __launch_bounds__(512, 4) void k_distp(const unsigned* __restrict__ emb_hl,
                                                  const float* __restrict__ sq,
                                                  unsigned* __restrict__ thr_g,
                                                  unsigned long long* __restrict__ part) {
  __shared__ __align__(16) unsigned char smem[61440];
  unsigned* eN = (unsigned*)smem;                        // 16384 B
  unsigned* eM = (unsigned*)(smem + 16384);              // 16384 B
  float* d2f   = (float*)(smem + 32768);                 // 16640 B (64 x 65)
  float* sqN   = (float*)(smem + 49408);                 // 256 B
  float* sqMp  = (float*)(smem + 49664);                 // 2048 B
  unsigned* thr  = (unsigned*)(smem + 51712);            // 256 B (per-row hi-bits bound)
  unsigned* thr2 = (unsigned*)(smem + 51968);            // 256 B (per-chunk max_s lst[2])
  unsigned long long* dump = (unsigned long long*)smem;            // phase2 [24][256] 49152 B
  unsigned long long* runM = (unsigned long long*)(smem + 49152);  // phase2 [24][64] 12288 B

  const int bid = blockIdx.x;
  const int mp = bid & 7;
  const int nt = (bid >> 3) & 63;
  const int b  = bid >> 9;
  const int n0 = nt << 6;
  const int m00 = mp << 9;   // global m base of this part
  const int tid = threadIdx.x;
  const uint4* embg = (const uint4*)emb_hl;
  const size_t bbase = (size_t)b * NB;
  const int gbase = (b << 12) + n0;  // thr_g row base for this block

#pragma unroll
  for (int k = 0; k < 2; ++k) {
    int q = tid + 512 * k;
    int r = q >> 4, ch = q & 15;
    *(uint4*)&eN[r * 64 + ch * 4] = embg[(bbase + n0 + r) * 16 + ch];
  }
  if (tid < 64) sqN[tid] = sq[b * NB + n0 + tid];
  sqMp[tid] = sq[b * NB + m00 + tid];
  if (tid < 64) { thr[tid] = thr_g[gbase + tid]; thr2[tid] = 0u; }  // import global bound

  const int w = tid >> 6, lane = tid & 63;
  const int quad = lane >> 4, lr = lane & 15;
  const int rt = w >> 1;            // row tile 0..3
  const int ct0 = (w & 1) * 2;      // first of my 2 col tiles (of 4)
  const int rowA = rt * 16 + lr;

  const int seg = w;                // all 8 waves drain, 8 cols each
  const int dr = lane;

  // eM chunk0: load -> write; then prefetch chunk1 into regs
  const int rA = tid >> 4, chA = tid & 15;
  const int rB = rA + 32;
  uint4 pf0 = embg[(bbase + m00 + rA) * 16 + chA];
  uint4 pf1 = embg[(bbase + m00 + rB) * 16 + chA];
  *(uint4*)&eM[rA * 64 + chA * 4] = pf0;
  *(uint4*)&eM[rB * 64 + chA * 4] = pf1;
  pf0 = embg[(bbase + m00 + 64 + rA) * 16 + chA];
  pf1 = embg[(bbase + m00 + 64 + rB) * 16 + chA];

  unsigned long long lst[24];
#pragma unroll
  for (int i = 0; i < 24; ++i) lst[i] = ~0ULL;
  unsigned long long q0 = 0, q1 = 0, q2 = 0, q3 = 0, q4 = 0, q5 = 0, q6 = 0, q7 = 0;
  int qc = 0;
  unsigned tgNext = 0x42C80000u;  // w0: prefetched global bound (refreshed per chunk)

#pragma unroll 1
  for (int ci = 0; ci < 8; ++ci) {
    const int m0 = ci << 6;  // local m offset
    __syncthreads();  // B1: eM(ci) visible; previous drain done (d2f free)

    // w0 merges {last chunk's Sigma-rank bound, prefetched global bound} into thr and
    // publishes improvements to thr_g. All thr/thr2 LDS ops pre-B2; others read thr
    // only post-B2 -> ordered. Skip ci==0 (thr2 is 0-init; thr already global-seeded).
    if (w == 0 && ci > 0) {
      unsigned t2 = thr2[lane];
      unsigned cur = thr[lane];
      unsigned m = cur;
      if (t2 < m) m = t2;
      if (tgNext < m) m = tgNext;        // import other parts' bounds
      if (m < cur) thr[lane] = m;
      if (m < tgNext) atomicMin(&thr_g[gbase + lane], m);  // publish (device-scope)
      thr2[lane] = 0u;
    }

    f32x4 acc0 = {0.f, 0.f, 0.f, 0.f};
    f32x4 acc1 = {0.f, 0.f, 0.f, 0.f};
#pragma unroll
    for (int kk = 0; kk < 2; ++kk) {
      const int cb = quad + 4 * kk;
      bf16x8 a_hi = *(const bf16x8*)&eN[rowA * 64 + ((cb) ^ lr) * 4];
      bf16x8 a_lo = *(const bf16x8*)&eN[rowA * 64 + ((cb + 8) ^ lr) * 4];
      int rowB0 = ct0 * 16 + lr, rowB1 = rowB0 + 16;
      bf16x8 b0_hi = *(const bf16x8*)&eM[rowB0 * 64 + ((cb) ^ lr) * 4];
      bf16x8 b0_lo = *(const bf16x8*)&eM[rowB0 * 64 + ((cb + 8) ^ lr) * 4];
      bf16x8 b1_hi = *(const bf16x8*)&eM[rowB1 * 64 + ((cb) ^ lr) * 4];
      bf16x8 b1_lo = *(const bf16x8*)&eM[rowB1 * 64 + ((cb + 8) ^ lr) * 4];
      acc0 = __builtin_amdgcn_mfma_f32_16x16x32_bf16(a_hi, b0_hi, acc0, 0, 0, 0);
      acc0 = __builtin_amdgcn_mfma_f32_16x16x32_bf16(a_hi, b0_lo, acc0, 0, 0, 0);
      acc0 = __builtin_amdgcn_mfma_f32_16x16x32_bf16(a_lo, b0_hi, acc0, 0, 0, 0);
      acc1 = __builtin_amdgcn_mfma_f32_16x16x32_bf16(a_hi, b1_hi, acc1, 0, 0, 0);
      acc1 = __builtin_amdgcn_mfma_f32_16x16x32_bf16(a_hi, b1_lo, acc1, 0, 0, 0);
      acc1 = __builtin_amdgcn_mfma_f32_16x16x32_bf16(a_lo, b1_hi, acc1, 0, 0, 0);
    }
#pragma unroll
    for (int reg = 0; reg < 4; ++reg) {
      int row = rt * 16 + quad * 4 + reg;
      int c0 = ct0 * 16 + lr, c1 = c0 + 16;
      float d20 = fmaxf(sqN[row] + sqMp[m0 + c0] - 2.f * acc0[reg], 0.f);
      float d21 = fmaxf(sqN[row] + sqMp[m0 + c1] - 2.f * acc1[reg], 0.f);
      d2f[row * 65 + c0] = d20;
      d2f[row * 65 + c1] = d21;
    }
    __syncthreads();  // B2: d2f ready; eM frag reads done -> eM restage safe

    if (ci < 7) {  // write next eM from prefetched regs, then issue chunk ci+2 loads
      *(uint4*)&eM[rA * 64 + chA * 4] = pf0;
      *(uint4*)&eM[rB * 64 + chA * 4] = pf1;
      if (ci < 6) {
        pf0 = embg[(bbase + m00 + m0 + 128 + rA) * 16 + chA];
        pf1 = embg[(bbase + m00 + m0 + 128 + rB) * 16 + chA];
      }
    }
    if (w == 0 && ci < 7) tgNext = thr_g[gbase + lane];  // prefetch; latency hides under drain

    const unsigned tCh = thr[dr];  // stale-safe (thr monotone decreasing)
    const int cbase = m00 + m0 + seg * 8;
    const int flushAt = (ci < 3) ? 4 : 8;  // wave-uniform: early = bound-building cadence
#pragma unroll 1
    for (int j = 0; j < 8; ++j) {
      float v = d2f[dr * 65 + seg * 8 + j];
      unsigned bits = __float_as_uint(v);
      if (bits <= tCh) {  // <=100 filter folded into thr init; prune is exact
        unsigned long long p = ((unsigned long long)bits << 32) | (unsigned)(cbase + j);
        q0 = (qc == 0) ? p : q0;
        q1 = (qc == 1) ? p : q1;
        q2 = (qc == 2) ? p : q2;
        q3 = (qc == 3) ? p : q3;
        q4 = (qc == 4) ? p : q4;
        q5 = (qc == 5) ? p : q5;
        q6 = (qc == 6) ? p : q6;
        q7 = (qc == 7) ? p : q7;
        ++qc;
      }
      if (__any(qc >= flushAt)) FLUSH8()
    }
    atomicMax(&thr2[dr], (unsigned)(lst[2] >> 32));  // Sigma-rank witness (pending queue
    // entries only shrink lst[2] later -> stale-larger bound is safe)
  }
  // final flush of pending candidates (once, off the per-chunk critical path)
  if (qc > 0) { INSERT24(q0) }
  if (qc > 1) { INSERT24(q1) }
  if (qc > 2) { INSERT24(q2) }
  if (qc > 3) { INSERT24(q3) }
  if (qc > 4) { INSERT24(q4) }
  if (qc > 5) { INSERT24(q5) }
  if (qc > 6) { INSERT24(q6) }
  if (qc > 7) { INSERT24(q7) }

  __syncthreads();  // tiles dead -> reuse as dump ([24][256] transposed: 2-way banks)
  if (seg < 4) {
#pragma unroll
    for (int i = 0; i < 24; ++i) dump[i * 256 + tid] = lst[i];
  }
  __syncthreads();
  if (tid < 64) {   // round A: 4-way merge segs 0..3 -> runM
    int pp[4] = {0, 0, 0, 0};
    unsigned long long h[4];
#pragma unroll
    for (int t = 0; t < 4; ++t) h[t] = dump[(t << 6) | tid];
#pragma unroll 1
    for (int k = 0; k < 24; ++k) {
      int bs = 0;
      unsigned long long mv = h[0];
#pragma unroll
      for (int t = 1; t < 4; ++t)
        if (h[t] < mv) { mv = h[t]; bs = t; }
      runM[k * 64 + tid] = mv;
      int np = ++pp[bs];
      h[bs] = (np < 24) ? dump[np * 256 + ((bs << 6) | tid)] : ~0ULL;
    }
  }
  __syncthreads();
  if (seg >= 4) {
#pragma unroll
    for (int i = 0; i < 24; ++i) dump[i * 256 + (tid - 256)] = lst[i];
  }
  __syncthreads();
  if (tid < 64) {   // round B: 5-way merge {runM, segs 4..7} -> part
    int pp[5] = {0, 0, 0, 0, 0};
    unsigned long long h[5];
    h[0] = runM[tid];
#pragma unroll
    for (int t = 0; t < 4; ++t) h[t + 1] = dump[(t << 6) | tid];
    unsigned long long* op = part + ((size_t)bid * 64 + tid) * 24;
#pragma unroll 1
    for (int k = 0; k < 24; ++k) {
      int bs = 0;
      unsigned long long mv = h[0];
#pragma unroll
      for (int t = 1; t < 5; ++t)
        if (h[t] < mv) { mv = h[t]; bs = t; }
      op[k] = mv;  // sentinels ok; k_merge cuts
      int np = ++pp[bs];
      if (bs == 0) h[0] = (np < 24) ? runM[np * 64 + tid] : ~0ULL;
      else h[bs] = (np < 24) ? dump[np * 256 + (((bs - 1) << 6) | tid)] : ~0ULL;
    }
  }
}

// ---------------- K3b: merge 8 sorted partials per row -> row_idx/row_cnt/col_cnt
// v14: 256 blocks x 64 threads (was 64x256) -> 4x more CUs on latency-bound gather
__global__ __launch_bounds__(64) void k_merge(const unsigned long long* __restrict__ part,
                                              int* __restrict__ row_idx,
                                              int* __restrict__ row_cnt,
                                              int* __restrict__ col_cnt) {
  const int row = blockIdx.x * 64 + threadIdx.x;  // b*4096 + n
  const int b = row >> 12;
  const int n = row & 4095;
  const int nt = n >> 6, r = n & 63;
  const size_t gb = (size_t)(((b << 6) | nt) << 3);  // block base (b,nt,mp=0)
  unsigned long long h[8];
  int pp[8];
#pragma unroll
  for (int t = 0; t < 8; ++t) {
    h[t] = part[((gb + t) * 64 + r) * 24];
    pp[t] = 0;
  }
  int cnt = 0;
  const int base = row * KNN;
  for (int k = 0; k < 24; ++k) {
    int bs = 0;
    unsigned long long mv = h[0];
#pragma unroll
    for (int t = 1; t < 8; ++t)
      if (h[t] < mv) { mv = h[t]; bs = t; }
    if ((unsigned)(mv >> 32) > 0x42C80000u) break;  // sentinel / beyond threshold
    int mi = (int)(mv & 0xFFFFFFFFu);
    row_idx[base + cnt] = mi;
    atomicAdd(&col_cnt[(b << 12) + mi], 1);
    ++cnt;
    int np = ++pp[bs];
    h[bs] = (np < 24) ? part[((gb + bs) * 64 + r) * 24 + np] : ~0ULL;
  }
  row_cnt[row] = cnt;
#pragma unroll 4
  for (int j = cnt; j < 24; ++j) row_idx[base + j] = n;  // pad with self (valid gather idx)
}

// ---------------- K4: exclusive scan of col_cnt (16384 entries), 1 block
__global__ __launch_bounds__(256) void k_scan(const int* __restrict__ col_cnt,
                                              int* __restrict__ col_start,
                                              int* __restrict__ col_cursor) {
  __shared__ int part[256];
  const int tid = threadIdx.x;
  const int base = tid * 64;
  int s = 0;
  for (int j = 0; j < 64; ++j) s += col_cnt[base + j];
  part[tid] = s;
  __syncthreads();
  for (int off = 1; off < 256; off <<= 1) {
    int v = (tid >= off) ? part[tid - off] : 0;
    __syncthreads();
    part[tid] += v;
    __syncthreads();
  }
  int run = part[tid] - s;
  for (int j = 0; j < 64; ++j) {
    col_start[base + j] = run;
    col_cursor[base + j] = run;
    run += col_cnt[base + j];
  }
}

// ---------------- K5: fill CSC column lists (v14: 256 blocks x 64 threads)
__global__ __launch_bounds__(64) void k_fill(const int* __restrict__ row_idx,
                                             const int* __restrict__ row_cnt,
                                             int* __restrict__ col_cursor,
                                             int* __restrict__ col_list) {
  const int row = blockIdx.x * 64 + threadIdx.x;
  const int b = row >> 12;
  const int cnt = row_cnt[row];
  for (int j = 0; j < cnt; ++j) {
    int m = row_idx[row * KNN + j];
    int pos = atomicAdd(&col_cursor[(b << 12) + m], 1);
    col_list[pos] = row & 4095;
  }
}

// ---------------- K6: Yd[e,c] = (sum_{m in col(e)} X_lin[m,c]) / De[e]
__global__ __launch_bounds__(256) void k_yd(const float* __restrict__ xlin,
                                            const int* __restrict__ col_cnt,
                                            const int* __restrict__ col_start,
                                            const int* __restrict__ col_list,
                                            float* __restrict__ yd) {
  const int le = threadIdx.x >> 6;
  const int c4 = threadIdx.x & 63;
  const int be = blockIdx.x * 4 + le;
  const int b = be >> 12;
  const int deg = col_cnt[be];
  const int start = col_start[be];
  float4 acc = make_float4(0.f, 0.f, 0.f, 0.f);
  int j = 0;
  for (; j + 3 < deg; j += 4) {
    int ma = col_list[start + j], mb2 = col_list[start + j + 1];
    int mc = col_list[start + j + 2], md = col_list[start + j + 3];
    float4 va = *(const float4*)&xlin[(((size_t)(b << 12) + ma) << 8) + c4 * 4];
    float4 vb = *(const float4*)&xlin[(((size_t)(b << 12) + mb2) << 8) + c4 * 4];
    float4 vc = *(const float4*)&xlin[(((size_t)(b << 12) + mc) << 8) + c4 * 4];
    float4 vd = *(const float4*)&xlin[(((size_t)(b << 12) + md) << 8) + c4 * 4];
    acc.x += (va.x + vb.x) + (vc.x + vd.x);
    acc.y += (va.y + vb.y) + (vc.y + vd.y);
    acc.z += (va.z + vb.z) + (vc.z + vd.z);
    acc.w += (va.w + vb.w) + (vc.w + vd.w);
  }
  for (; j < deg; ++j) {
    int m = col_list[start + j];
    float4 v = *(const float4*)&xlin[(((size_t)(b << 12) + m) << 8) + c4 * 4];
    acc.x += v.x; acc.y += v.y; acc.z += v.z; acc.w += v.w;
  }
  float inv = 1.f / (float)deg;
  acc.x *= inv; acc.y *= inv; acc.z *= inv; acc.w *= inv;
  *(float4*)&yd[((size_t)be << 8) + c4 * 4] = acc;
}

// ---------------- K7: g[n,c] = (sum_{e in row(n)} Yd[e,c]) / Dv[n]
__global__ __launch_bounds__(256) void k_out2(const float* __restrict__ yd,
                                              const int* __restrict__ row_idx,
                                              const int* __restrict__ row_cnt,
                                              float* __restrict__ outf) {
  const int b = blockIdx.x >> 8;
  const int nt = blockIdx.x & 255;
  const int le = threadIdx.x >> 6;
  const int c4 = threadIdx.x & 63;
  for (int ii = 0; ii < 4; ++ii) {
    int n = nt * 16 + le * 4 + ii;
    int row = (b << 12) + n;
    int cnt = row_cnt[row];
    int idx[24];
    const int4* ip = (const int4*)(row_idx + (size_t)row * KNN);
#pragma unroll
    for (int t = 0; t < 6; ++t) {
      int4 v = ip[t];
      idx[4 * t] = v.x; idx[4 * t + 1] = v.y; idx[4 * t + 2] = v.z; idx[4 * t + 3] = v.w;
    }
    float4 acc = make_float4(0.f, 0.f, 0.f, 0.f);
#pragma unroll
    for (int j = 0; j < 24; ++j) {
      float wgt = (j < cnt) ? 1.f : 0.f;
      float4 v = *(const float4*)&yd[(((size_t)(b << 12) + idx[j]) << 8) + c4 * 4];
      acc.x = fmaf(wgt, v.x, acc.x);
      acc.y = fmaf(wgt, v.y, acc.y);
      acc.z = fmaf(wgt, v.z, acc.z);
      acc.w = fmaf(wgt, v.w, acc.w);
    }
    float inv = 1.f / (float)cnt;
    acc.x *= inv; acc.y *= inv; acc.z *= inv; acc.w *= inv;
    *(float4*)&outf[((size_t)row << 8) + c4 * 4] = acc;
  }
}

// ---------------- K8: outf += x (residual, via LDS transpose); accumulate BN sums
__global__ __launch_bounds__(256) void k_res_bn(const float* __restrict__ x,
                                                float* __restrict__ outf,
                                                float* __restrict__ bn_sum,
                                                float* __restrict__ bn_sumsq) {
  __shared__ float xt[256 * 69];
  const int b = blockIdx.x >> 6;
  const int n0 = (blockIdx.x & 63) << 6;
  const int tid = threadIdx.x;
#pragma unroll 4
  for (int k = 0; k < 16; ++k) {
    int q = tid + 256 * k;
    int c = q >> 4, f = q & 15;
    float4 v = *(const float4*)&x[((size_t)(b * CD + c)) * NB + n0 + 4 * f];
    xt[c * 69 + 4 * f + 0] = v.x;
    xt[c * 69 + 4 * f + 1] = v.y;
    xt[c * 69 + 4 * f + 2] = v.z;
    xt[c * 69 + 4 * f + 3] = v.w;
  }
  __syncthreads();
  float s = 0.f, q = 0.f;
  const size_t rbase = ((size_t)((b << 12) + n0)) << 8;
#pragma unroll 4
  for (int i = 0; i < 64; ++i) {
    float v = outf[rbase + (size_t)i * 256 + tid] + xt[tid * 69 + i];
    outf[rbase + (size_t)i * 256 + tid] = v;
    s += v;
    q = fmaf(v, v, q);
  }
  atomicAdd(&bn_sum[tid], s);
  atomicAdd(&bn_sumsq[tid], q);
}

// ---------------- K9: BN scale/shift per channel
__global__ __launch_bounds__(256) void k_bn(const float* __restrict__ bn_sum,
                                            const float* __restrict__ bn_sumsq,
                                            const float* __restrict__ gamma,
                                            const float* __restrict__ beta,
                                            float* __restrict__ scale,
                                            float* __restrict__ shift) {
  const int c = threadIdx.x;
  const float inv = 1.f / 16384.f;
  float mean = bn_sum[c] * inv;
  float var = bn_sumsq[c] * inv - mean * mean;
  float sc = gamma[c] * rsqrtf(var + 1e-5f);
  scale[c] = sc;
  shift[c] = beta[c] - mean * sc;
}

// ---------------- K10: normalize + SiLU + transpose to [B,C,N]
__global__ __launch_bounds__(256) void k_write(const float* __restrict__ outf,
                                               const float* __restrict__ scale,
                                               const float* __restrict__ shift,
                                               float* __restrict__ out) {
  __shared__ float tile[64 * 257];
  __shared__ float sc[256], sh[256];
  const int b = blockIdx.x >> 6;
  const int n0 = (blockIdx.x & 63) << 6;
  const int tid = threadIdx.x;
  sc[tid] = scale[tid];
  sh[tid] = shift[tid];
  __syncthreads();
#pragma unroll 4
  for (int i = 0; i < 64; ++i) {
    int idx = tid + 256 * i;
    int n = idx >> 8, c = idx & 255;
    float v = outf[(((size_t)(b << 12) + n0 + n) << 8) + c];
    v = fmaf(v, sc[c], sh[c]);
    float w = v / (1.f + expf(-v));  // SiLU
    tile[n * 257 + c] = w;
  }
  __syncthreads();
  const int nl = tid & 63;
  const int cg = tid >> 6;
#pragma unroll 4
  for (int j = 0; j < 64; ++j) {
    int c = cg * 64 + j;
    out[((size_t)(b * CD + c)) * NB + n0 + nl] = tile[nl * 257 + c];
  }
}

extern "C" void kernel_launch(void* const* d_in, const int* in_sizes, int n_in,
                              void* d_out, int out_size, void* d_ws, size_t ws_size,
                              hipStream_t stream) {
  const float* x      = (const float*)d_in[0];
  const float* fc_w   = (const float*)d_in[1];
  const float* fc_b   = (const float*)d_in[2];
  const float* dist_w = (const float*)d_in[3];
  const float* gamma  = (const float*)d_in[4];
  const float* beta   = (const float*)d_in[5];
  float* out = (float*)d_out;
  char* ws = (char*)d_ws;

  const size_t OFF_EHL   = 0;                   // 4 MB
  const size_t OFF_XLIN  = (size_t)4 << 20;     // 16 MB
  const size_t OFF_YD    = (size_t)20 << 20;    // 16 MB (part buffer overlays yd+outf: both dead then)
  const size_t OFF_OUTF  = (size_t)36 << 20;    // 16 MB
  const size_t OFF_SQ    = (size_t)52 << 20;
  const size_t OFF_RIDX  = OFF_SQ + 65536;
  const size_t OFF_RCNT  = OFF_RIDX + 1572864;
  const size_t OFF_CCNT  = OFF_RCNT + 65536;
  const size_t OFF_CSTART = OFF_CCNT + 65536;
  const size_t OFF_CCUR  = OFF_CSTART + 65536;
  const size_t OFF_CLIST = OFF_CCUR + 65536;
  const size_t OFF_BNS   = OFF_CLIST + 1572864;
  const size_t OFF_BNQ   = OFF_BNS + 1024;
  const size_t OFF_SCALE = OFF_BNQ + 1024;
  const size_t OFF_SHIFT = OFF_SCALE + 1024;
  const size_t OFF_THRG  = OFF_SHIFT + 1024;    // 64 KB global per-row kNN threshold
  const size_t TOTAL = OFF_THRG + 65536;
  if (ws_size < TOTAL) return;

  unsigned* emb_hl = (unsigned*)(ws + OFF_EHL);
  float* xlin  = (float*)(ws + OFF_XLIN);
  float* yd    = (float*)(ws + OFF_YD);
  float* outf  = (float*)(ws + OFF_OUTF);
  unsigned long long* part = (unsigned long long*)(ws + OFF_YD);  // 25.2 MB overlay (yd+outf dead here)
  float* sq    = (float*)(ws + OFF_SQ);
  int* row_idx = (int*)(ws + OFF_RIDX);
  int* row_cnt = (int*)(ws + OFF_RCNT);
  int* col_cnt = (int*)(ws + OFF_CCNT);
  int* col_start = (int*)(ws + OFF_CSTART);
  int* col_cursor = (int*)(ws + OFF_CCUR);
  int* col_list = (int*)(ws + OFF_CLIST);
  float* bn_sum = (float*)(ws + OFF_BNS);
  float* bn_sumsq = (float*)(ws + OFF_BNQ);
  float* scale = (float*)(ws + OFF_SCALE);
  float* shift = (float*)(ws + OFF_SHIFT);
  unsigned* thr_g = (unsigned*)(ws + OFF_THRG);

  hipMemsetAsync(col_cnt, 0, 65536, stream);
  hipMemsetAsync(bn_sum, 0, 2048, stream);

  k_emb<<<256, 256, 0, stream>>>(x, dist_w, emb_hl, sq, thr_g);
  k_xlin<<<256, 256, 0, stream>>>(x, fc_w, fc_b, xlin);
  k_distp<<<2048, 512, 0, stream>>>(emb_hl, sq, thr_g, part);
  k_merge<<<256, 64, 0, stream>>>(part, row_idx, row_cnt, col_cnt);
  k_scan<<<1, 256, 0, stream>>>(col_cnt, col_start, col_cursor);
  k_fill<<<256, 64, 0, stream>>>(row_idx, row_cnt, col_cursor, col_list);
  k_yd<<<4096, 256, 0, stream>>>(xlin, col_cnt, col_start, col_list, yd);
  k_out2<<<1024, 256, 0, stream>>>(yd, row_idx, row_cnt, outf);
  k_res_bn<<<256, 256, 0, stream>>>(x, outf, bn_sum, bn_sumsq);
  k_bn<<<1, 256, 0, stream>>>(bn_sum, bn_sumsq, gamma, beta, scale, shift);
  k_write<<<256, 256, 0, stream>>>(outf, scale, shift, out);
}

// Round 6
// 609.951 us; speedup vs baseline: 1.1521x; 1.1521x over previous
//
#include <hip/hip_runtime.h>

#define NB 4096      // N = H*W
#define BATCH 4
#define CD 256       // channels
#define ED 64        // embedding dim
#define KNN 24

typedef __attribute__((ext_vector_type(8))) short bf16x8;
typedef __attribute__((ext_vector_type(4))) float f32x4;

__device__ __forceinline__ unsigned short f2bf(float x) {
  unsigned u = __float_as_uint(x);
  unsigned r = (u + 0x7fffu + ((u >> 16) & 1u)) >> 16;
  return (unsigned short)r;
}

// ---------------- K1: emb = x @ dist_w^T  -> emb_hl (bf16 hi/lo, XOR-swizzled chunks) + sq (fp32)
// Also inits thr_g (per-row global kNN threshold) to bits(100.0f).
__global__ __launch_bounds__(256) void k_emb(const float* __restrict__ x,
                                             const float* __restrict__ dist_w,
                                             unsigned* __restrict__ emb_hl,
                                             float* __restrict__ sq,
                                             unsigned* __restrict__ thr_g) {
  __shared__ float wds[ED * CD];   // 64 KB
  __shared__ float red[64 * 4];
  const int b = blockIdx.x >> 6;
  const int n0 = (blockIdx.x & 63) << 6;
  const int tid = threadIdx.x;
  const float4* wsrc = (const float4*)dist_w;
  float4* wdst = (float4*)wds;
#pragma unroll
  for (int k = 0; k < 16; ++k) wdst[tid + 256 * k] = wsrc[tid + 256 * k];
  __syncthreads();
  const int eg = tid >> 6;   // 0..3
  const int nl = tid & 63;
  const int n = n0 + nl;
  float acc[16];
#pragma unroll
  for (int t = 0; t < 16; ++t) acc[t] = 0.f;
  const float* xb = x + (size_t)b * CD * NB + n;
#pragma unroll 2
  for (int c4 = 0; c4 < CD; c4 += 4) {
    float x0 = xb[(size_t)(c4 + 0) * NB];
    float x1 = xb[(size_t)(c4 + 1) * NB];
    float x2 = xb[(size_t)(c4 + 2) * NB];
    float x3 = xb[(size_t)(c4 + 3) * NB];
#pragma unroll
    for (int t = 0; t < 16; ++t) {
      float4 wv = *(const float4*)&wds[(eg * 16 + t) * CD + c4];
      acc[t] = fmaf(x0, wv.x, acc[t]);
      acc[t] = fmaf(x1, wv.y, acc[t]);
      acc[t] = fmaf(x2, wv.z, acc[t]);
      acc[t] = fmaf(x3, wv.w, acc[t]);
    }
  }
  float s = 0.f;
#pragma unroll
  for (int t = 0; t < 16; ++t) s = fmaf(acc[t], acc[t], s);
  unsigned hw[8], lw[8];
#pragma unroll
  for (int i = 0; i < 8; ++i) {
    unsigned short h0 = f2bf(acc[2 * i]);
    unsigned short h1 = f2bf(acc[2 * i + 1]);
    float l0f = acc[2 * i] - __uint_as_float((unsigned)h0 << 16);
    float l1f = acc[2 * i + 1] - __uint_as_float((unsigned)h1 << 16);
    hw[i] = (unsigned)h0 | ((unsigned)h1 << 16);
    lw[i] = (unsigned)f2bf(l0f) | ((unsigned)f2bf(l1f) << 16);
  }
  uint4* g = (uint4*)emb_hl;
  const size_t gb = ((size_t)(b * NB + n)) * 16;
  const int k15 = n & 15;
  g[gb + ((2 * eg) ^ k15)]     = make_uint4(hw[0], hw[1], hw[2], hw[3]);
  g[gb + ((2 * eg + 1) ^ k15)] = make_uint4(hw[4], hw[5], hw[6], hw[7]);
  g[gb + ((8 + 2 * eg) ^ k15)]     = make_uint4(lw[0], lw[1], lw[2], lw[3]);
  g[gb + ((8 + 2 * eg + 1) ^ k15)] = make_uint4(lw[4], lw[5], lw[6], lw[7]);
  red[nl * 4 + eg] = s;
  __syncthreads();
  if (tid < 64) {
    sq[b * NB + n0 + tid] = red[tid * 4] + red[tid * 4 + 1] + red[tid * 4 + 2] + red[tid * 4 + 3];
    thr_g[(b << 12) + n0 + tid] = 0x42C80000u;  // bits(100.0f)
  }
}

// ---------------- K2: X_lin[b,n,c] = sum_k x[b,k,n]*fc_w[c,k] + fc_b[c]
__global__ __launch_bounds__(256) void k_xlin(const float* __restrict__ x,
                                              const float* __restrict__ fc_w,
                                              const float* __restrict__ fc_b,
                                              float* __restrict__ xlin) {
  __shared__ float xt[64 * 64];     // [k][n]
  __shared__ float wt[64 * 260];    // [k][c] padded
  const int b = blockIdx.x >> 6;
  const int n0 = (blockIdx.x & 63) << 6;
  const int tid = threadIdx.x;
  const int nl4 = tid & 15;
  const int cg = tid >> 4;
  float acc[4][16];
#pragma unroll
  for (int i = 0; i < 4; ++i)
#pragma unroll
    for (int j = 0; j < 16; ++j) acc[i][j] = 0.f;

  for (int kt = 0; kt < 4; ++kt) {
    __syncthreads();
#pragma unroll 4
    for (int i = 0; i < 16; ++i) {
      int idx = tid + 256 * i;
      int k = idx >> 6, n = idx & 63;
      xt[idx] = x[((size_t)(b * CD + kt * 64 + k)) * NB + n0 + n];
    }
#pragma unroll 4
    for (int i = 0; i < 16; ++i) {
      int q = tid + 256 * i;
      int c = q >> 4, k4 = (q & 15) * 4;
      float4 v = *(const float4*)&fc_w[(size_t)c * CD + kt * 64 + k4];
      wt[(k4 + 0) * 260 + c] = v.x;
      wt[(k4 + 1) * 260 + c] = v.y;
      wt[(k4 + 2) * 260 + c] = v.z;
      wt[(k4 + 3) * 260 + c] = v.w;
    }
    __syncthreads();
#pragma unroll 2
    for (int k = 0; k < 64; ++k) {
      float4 xv = *(const float4*)&xt[k * 64 + 4 * nl4];
#pragma unroll
      for (int j = 0; j < 4; ++j) {
        float4 wv = *(const float4*)&wt[k * 260 + 4 * cg + 64 * j];
        const float* wp = &wv.x;
#pragma unroll
        for (int l = 0; l < 4; ++l) {
          acc[0][4 * j + l] = fmaf(xv.x, wp[l], acc[0][4 * j + l]);
          acc[1][4 * j + l] = fmaf(xv.y, wp[l], acc[1][4 * j + l]);
          acc[2][4 * j + l] = fmaf(xv.z, wp[l], acc[2][4 * j + l]);
          acc[3][4 * j + l] = fmaf(xv.w, wp[l], acc[3][4 * j + l]);
        }
      }
    }
  }
#pragma unroll
  for (int i = 0; i < 4; ++i) {
    int n = n0 + 4 * nl4 + i;
    float* dst = xlin + ((size_t)(b * NB + n)) * CD;
#pragma unroll
    for (int j = 0; j < 4; ++j) {
      int c = 4 * cg + 64 * j;
      float4 bv = *(const float4*)&fc_b[c];
      float4 o;
      o.x = acc[i][4 * j + 0] + bv.x;
      o.y = acc[i][4 * j + 1] + bv.y;
      o.z = acc[i][4 * j + 2] + bv.z;
      o.w = acc[i][4 * j + 3] + bv.w;
      *(float4*)&dst[c] = o;
    }
  }
}

// ---------------- K3 v15: two-pass histogram select (replaces INSERT24 lists entirely).
// v13 PMC showed ~85% of k_distp VALU was wave-wide INSERT24 cascades, while per-lane
// accepts (~6.4/part) never fill a 24-list -> bounds never tightened. MFMA is 3.5%
// utilized -> recomputing d2 is free. PASS 1: d2 -> per-row 64-bucket histogram
// (linear, width 1.5625 over [0,100]; bucket = min(63,(int)(d2*0.64f))). Bound: first
// bucket kb with cum>=24. EXACT: >=24 scanned values have bucket<=kb and ALL of them
// are collected in pass 2; bucket() is monotone (fp mult by +const, trunc) so any
// dropped v (bucket>kb) exceeds >=24 collected entries -> our part's top-24 output
// dominates v -> k_merge never needs it. Cross-part: publish conservative edge
// (kb+2)*1.5625 via atomicMin(thr_g); import kImp=(int)(tgf*0.64f) (v<=tg =>
// bucket(v)<=kImp by monotonicity) -> collect bucket <= min(kb,kImp). PASS 2:
// recompute d2, compact keys into cand[row][52] via LDS cursor. Expected collect
// ~24-30 (certified <=23+bucket-pop, pop@quantile ~4); CAP 52 drops are a correctness
// tripwire (absmax must stay 0.0546875). Tail: 8 lanes/row cooperative min-extract
// (shfl_xor) -> sorted 24 + sentinels to part.
__global__ __launch_bounds__(512, 4) void k_distp(const unsigned* __restrict__ emb_hl,
                                                  const float* __restrict__ sq,
                                                  unsigned* __restrict__ thr_g,
                                                  unsigned long long* __restrict__ part) {
  __shared__ __align__(16) unsigned char smem[78592];
  unsigned* eN = (unsigned*)smem;                         // 16384 B
  unsigned* eM = (unsigned*)(smem + 16384);               // 16384 B
  float* sqN   = (float*)(smem + 32768);                  // 256 B
  float* sqMp  = (float*)(smem + 33024);                  // 2048 B
  int* hist    = (int*)(smem + 35072);                    // 16384 B [bucket][row] (transposed: extraction reads lane-consecutive)
  int* collectK= (int*)(smem + 51456);                    // 256 B
  int* cnt     = (int*)(smem + 51712);                    // 256 B
  unsigned long long* cand = (unsigned long long*)(smem + 51968);  // 64 x 52 x 8 = 26624 B

  const int bid = blockIdx.x;
  const int mp = bid & 7;
  const int nt = (bid >> 3) & 63;
  const int b  = bid >> 9;
  const int n0 = nt << 6;
  const int m00 = mp << 9;   // global m base of this part
  const int tid = threadIdx.x;
  const uint4* embg = (const uint4*)emb_hl;
  const size_t bbase = (size_t)b * NB;
  const int gbase = (b << 12) + n0;

#pragma unroll
  for (int k = 0; k < 2; ++k) {
    int q = tid + 512 * k;
    int r = q >> 4, ch = q & 15;
    *(uint4*)&eN[r * 64 + ch * 4] = embg[(bbase + n0 + r) * 16 + ch];
  }
  if (tid < 64) sqN[tid] = sq[b * NB + n0 + tid];
  sqMp[tid] = sq[b * NB + m00 + tid];
#pragma unroll
  for (int i = 0; i < 8; ++i) hist[tid + 512 * i] = 0;

  const int w = tid >> 6, lane = tid & 63;
  const int quad = lane >> 4, lr = lane & 15;
  const int rt = w >> 1;            // row tile 0..3
  const int ct0 = (w & 1) * 2;      // first of my 2 col tiles (of 4)
  const int rowA = rt * 16 + lr;
  const int rA = tid >> 4, chA = tid & 15;
  const int rB = rA + 32;

  uint4 pf0, pf1;

// MFMA chunk: d2 for 8 (row,col) pairs into d20_[reg]/d21_[reg]
#define CHUNK_MFMA(m0_)                                                            \
  f32x4 acc0 = {0.f, 0.f, 0.f, 0.f};                                               \
  f32x4 acc1 = {0.f, 0.f, 0.f, 0.f};                                               \
  _Pragma("unroll")                                                                \
  for (int kk = 0; kk < 2; ++kk) {                                                 \
    const int cb = quad + 4 * kk;                                                  \
    bf16x8 a_hi = *(const bf16x8*)&eN[rowA * 64 + ((cb) ^ lr) * 4];                \
    bf16x8 a_lo = *(const bf16x8*)&eN[rowA * 64 + ((cb + 8) ^ lr) * 4];            \
    int rowB0 = ct0 * 16 + lr, rowB1 = rowB0 + 16;                                 \
    bf16x8 b0_hi = *(const bf16x8*)&eM[rowB0 * 64 + ((cb) ^ lr) * 4];              \
    bf16x8 b0_lo = *(const bf16x8*)&eM[rowB0 * 64 + ((cb + 8) ^ lr) * 4];          \
    bf16x8 b1_hi = *(const bf16x8*)&eM[rowB1 * 64 + ((cb) ^ lr) * 4];              \
    bf16x8 b1_lo = *(const bf16x8*)&eM[rowB1 * 64 + ((cb + 8) ^ lr) * 4];          \
    acc0 = __builtin_amdgcn_mfma_f32_16x16x32_bf16(a_hi, b0_hi, acc0, 0, 0, 0);    \
    acc0 = __builtin_amdgcn_mfma_f32_16x16x32_bf16(a_hi, b0_lo, acc0, 0, 0, 0);    \
    acc0 = __builtin_amdgcn_mfma_f32_16x16x32_bf16(a_lo, b0_hi, acc0, 0, 0, 0);    \
    acc1 = __builtin_amdgcn_mfma_f32_16x16x32_bf16(a_hi, b1_hi, acc1, 0, 0, 0);    \
    acc1 = __builtin_amdgcn_mfma_f32_16x16x32_bf16(a_hi, b1_lo, acc1, 0, 0, 0);    \
    acc1 = __builtin_amdgcn_mfma_f32_16x16x32_bf16(a_lo, b1_hi, acc1, 0, 0, 0);    \
  }

#define STAGE_FIRST()                                                \
  pf0 = embg[(bbase + m00 + rA) * 16 + chA];                         \
  pf1 = embg[(bbase + m00 + rB) * 16 + chA];                         \
  *(uint4*)&eM[rA * 64 + chA * 4] = pf0;                             \
  *(uint4*)&eM[rB * 64 + chA * 4] = pf1;                             \
  pf0 = embg[(bbase + m00 + 64 + rA) * 16 + chA];                    \
  pf1 = embg[(bbase + m00 + 64 + rB) * 16 + chA];

#define RESTAGE(ci_, m0_)                                            \
  if ((ci_) < 7) {                                                   \
    *(uint4*)&eM[rA * 64 + chA * 4] = pf0;                           \
    *(uint4*)&eM[rB * 64 + chA * 4] = pf1;                           \
    if ((ci_) < 6) {                                                 \
      pf0 = embg[(bbase + m00 + (m0_) + 128 + rA) * 16 + chA];       \
      pf1 = embg[(bbase + m00 + (m0_) + 128 + rB) * 16 + chA];       \
    }                                                                \
  }

  // ================= PASS 1: histogram =================
  STAGE_FIRST()
#pragma unroll 1
  for (int ci = 0; ci < 8; ++ci) {
    const int m0 = ci << 6;
    __syncthreads();  // B1: eM(ci) visible
    CHUNK_MFMA(m0)
#pragma unroll
    for (int reg = 0; reg < 4; ++reg) {
      int row = rt * 16 + quad * 4 + reg;
      int c0 = ct0 * 16 + lr, c1 = c0 + 16;
      float d20 = fmaxf(sqN[row] + sqMp[m0 + c0] - 2.f * acc0[reg], 0.f);
      float d21 = fmaxf(sqN[row] + sqMp[m0 + c1] - 2.f * acc1[reg], 0.f);
      int bk0 = min(63, (int)(d20 * 0.64f));
      int bk1 = min(63, (int)(d21 * 0.64f));
      atomicAdd(&hist[bk0 * 64 + row], 1);
      atomicAdd(&hist[bk1 * 64 + row], 1);
    }
    __syncthreads();  // B2: hist adds + eM frag reads done -> restage safe
    RESTAGE(ci, m0)
  }

  // ============ bound extraction + cross-part share ============
  if (tid < 64) {
    int cum = 0, kb = 63;
#pragma unroll 1
    for (int k2 = 0; k2 < 64; ++k2) {
      cum += hist[k2 * 64 + tid];
      if (cum >= 24) { kb = k2; break; }
    }
    // publish conservative upper edge (+1 bucket fp slack); certificate: >=24 part
    // values <= edge survive into this part's output (all bucket<=kb get collected)
    float edge = (float)(kb + 2) * 1.5625f;
    atomicMin(&thr_g[gbase + tid], __float_as_uint(edge));
    unsigned tg = thr_g[gbase + tid];  // import (stale-larger is safe)
    int kImp = min(63, (int)(__uint_as_float(tg) * 0.64f));  // v<=tg => bucket(v)<=kImp
    collectK[tid] = min(kb, kImp);
    cnt[tid] = 0;
  }
#pragma unroll
  for (int i = 0; i < 7; ++i) {  // cand sentinel init (64*52 = 3328)
    int q = tid + 512 * i;
    if (q < 64 * 52) cand[q] = ~0ULL;
  }
  __syncthreads();

  // ================= PASS 2: collect =================
  STAGE_FIRST()
#pragma unroll 1
  for (int ci = 0; ci < 8; ++ci) {
    const int m0 = ci << 6;
    __syncthreads();  // B1
    CHUNK_MFMA(m0)
#pragma unroll
    for (int reg = 0; reg < 4; ++reg) {
      int row = rt * 16 + quad * 4 + reg;
      int c0 = ct0 * 16 + lr, c1 = c0 + 16;
      float d20 = fmaxf(sqN[row] + sqMp[m0 + c0] - 2.f * acc0[reg], 0.f);
      float d21 = fmaxf(sqN[row] + sqMp[m0 + c1] - 2.f * acc1[reg], 0.f);
      int kc = collectK[row];
      unsigned bi0 = __float_as_uint(d20), bi1 = __float_as_uint(d21);
      int bk0 = min(63, (int)(d20 * 0.64f));
      int bk1 = min(63, (int)(d21 * 0.64f));
      if (bk0 <= kc && bi0 <= 0x42C80000u) {
        int pos = atomicAdd(&cnt[row], 1);
        if (pos < 52) cand[row * 52 + pos] = ((unsigned long long)bi0 << 32) | (unsigned)(m00 + m0 + c0);
      }
      if (bk1 <= kc && bi1 <= 0x42C80000u) {
        int pos = atomicAdd(&cnt[row], 1);
        if (pos < 52) cand[row * 52 + pos] = ((unsigned long long)bi1 << 32) | (unsigned)(m00 + m0 + c1);
      }
    }
    __syncthreads();  // B2
    RESTAGE(ci, m0)
  }
  __syncthreads();  // cand complete, visible to all

  // ====== sorted top-24 extraction: 8 lanes per row, shfl_xor min-reduce ======
  {
    const int row8 = tid >> 3, sub = tid & 7;
    unsigned long long last = 0;
    unsigned long long* op = part + ((size_t)bid * 64 + row8) * 24;
#pragma unroll 1
    for (int k = 0; k < 24; ++k) {
      unsigned long long lm = ~0ULL;
#pragma unroll
      for (int j2 = 0; j2 < 7; ++j2) {
        int p2 = sub + 8 * j2;
        if (p2 < 52) {
          unsigned long long v2 = cand[row8 * 52 + p2];
          if ((k == 0 || v2 > last) && v2 < lm) lm = v2;
        }
      }
#pragma unroll
      for (int s2 = 1; s2 < 8; s2 <<= 1) {
        unsigned long long o2 = __shfl_xor(lm, s2);
        if (o2 < lm) lm = o2;
      }
      if (sub == 0) op[k] = lm;  // sentinels ok; k_merge cuts
      last = lm;
    }
  }
}

// ---------------- K3b: merge 8 sorted partials per row -> row_idx/row_cnt/col_cnt
__global__ __launch_bounds__(256) void k_merge(const unsigned long long* __restrict__ part,
                                               int* __restrict__ row_idx,
                                               int* __restrict__ row_cnt,
                                               int* __restrict__ col_cnt) {
  const int row = blockIdx.x * 256 + threadIdx.x;  // b*4096 + n
  const int b = row >> 12;
  const int n = row & 4095;
  const int nt = n >> 6, r = n & 63;
  const size_t gb = (size_t)(((b << 6) | nt) << 3);  // block base (b,nt,mp=0)
  unsigned long long h[8];
  int pp[8];
#pragma unroll
  for (int t = 0; t < 8; ++t) {
    h[t] = part[((gb + t) * 64 + r) * 24];
    pp[t] = 0;
  }
  int cnt = 0;
  const int base = row * KNN;
  for (int k = 0; k < 24; ++k) {
    int bs = 0;
    unsigned long long mv = h[0];
#pragma unroll
    for (int t = 1; t < 8; ++t)
      if (h[t] < mv) { mv = h[t]; bs = t; }
    if ((unsigned)(mv >> 32) > 0x42C80000u) break;  // sentinel / beyond threshold
    int mi = (int)(mv & 0xFFFFFFFFu);
    row_idx[base + cnt] = mi;
    atomicAdd(&col_cnt[(b << 12) + mi], 1);
    ++cnt;
    int np = ++pp[bs];
    h[bs] = (np < 24) ? part[((gb + bs) * 64 + r) * 24 + np] : ~0ULL;
  }
  row_cnt[row] = cnt;
#pragma unroll 4
  for (int j = cnt; j < 24; ++j) row_idx[base + j] = n;  // pad with self (valid gather idx)
}

// ---------------- K4: exclusive scan of col_cnt (16384 entries), 1 block
__global__ __launch_bounds__(256) void k_scan(const int* __restrict__ col_cnt,
                                              int* __restrict__ col_start,
                                              int* __restrict__ col_cursor) {
  __shared__ int part[256];
  const int tid = threadIdx.x;
  const int base = tid * 64;
  int s = 0;
  for (int j = 0; j < 64; ++j) s += col_cnt[base + j];
  part[tid] = s;
  __syncthreads();
  for (int off = 1; off < 256; off <<= 1) {
    int v = (tid >= off) ? part[tid - off] : 0;
    __syncthreads();
    part[tid] += v;
    __syncthreads();
  }
  int run = part[tid] - s;
  for (int j = 0; j < 64; ++j) {
    col_start[base + j] = run;
    col_cursor[base + j] = run;
    run += col_cnt[base + j];
  }
}

// ---------------- K5: fill CSC column lists
__global__ __launch_bounds__(256) void k_fill(const int* __restrict__ row_idx,
                                              const int* __restrict__ row_cnt,
                                              int* __restrict__ col_cursor,
                                              int* __restrict__ col_list) {
  const int row = blockIdx.x * 256 + threadIdx.x;
  const int b = row >> 12;
  const int cnt = row_cnt[row];
  for (int j = 0; j < cnt; ++j) {
    int m = row_idx[row * KNN + j];
    int pos = atomicAdd(&col_cursor[(b << 12) + m], 1);
    col_list[pos] = row & 4095;
  }
}

// ---------------- K6: Yd[e,c] = (sum_{m in col(e)} X_lin[m,c]) / De[e]
__global__ __launch_bounds__(256) void k_yd(const float* __restrict__ xlin,
                                            const int* __restrict__ col_cnt,
                                            const int* __restrict__ col_start,
                                            const int* __restrict__ col_list,
                                            float* __restrict__ yd) {
  const int le = threadIdx.x >> 6;
  const int c4 = threadIdx.x & 63;
  const int be = blockIdx.x * 4 + le;
  const int b = be >> 12;
  const int deg = col_cnt[be];
  const int start = col_start[be];
  float4 acc = make_float4(0.f, 0.f, 0.f, 0.f);
  int j = 0;
  for (; j + 3 < deg; j += 4) {
    int ma = col_list[start + j], mb2 = col_list[start + j + 1];
    int mc = col_list[start + j + 2], md = col_list[start + j + 3];
    float4 va = *(const float4*)&xlin[(((size_t)(b << 12) + ma) << 8) + c4 * 4];
    float4 vb = *(const float4*)&xlin[(((size_t)(b << 12) + mb2) << 8) + c4 * 4];
    float4 vc = *(const float4*)&xlin[(((size_t)(b << 12) + mc) << 8) + c4 * 4];
    float4 vd = *(const float4*)&xlin[(((size_t)(b << 12) + md) << 8) + c4 * 4];
    acc.x += (va.x + vb.x) + (vc.x + vd.x);
    acc.y += (va.y + vb.y) + (vc.y + vd.y);
    acc.z += (va.z + vb.z) + (vc.z + vd.z);
    acc.w += (va.w + vb.w) + (vc.w + vd.w);
  }
  for (; j < deg; ++j) {
    int m = col_list[start + j];
    float4 v = *(const float4*)&xlin[(((size_t)(b << 12) + m) << 8) + c4 * 4];
    acc.x += v.x; acc.y += v.y; acc.z += v.z; acc.w += v.w;
  }
  float inv = 1.f / (float)deg;
  acc.x *= inv; acc.y *= inv; acc.z *= inv; acc.w *= inv;
  *(float4*)&yd[((size_t)be << 8) + c4 * 4] = acc;
}

// ---------------- K7: g[n,c] = (sum_{e in row(n)} Yd[e,c]) / Dv[n]
__global__ __launch_bounds__(256) void k_out2(const float* __restrict__ yd,
                                              const int* __restrict__ row_idx,
                                              const int* __restrict__ row_cnt,
                                              float* __restrict__ outf) {
  const int b = blockIdx.x >> 8;
  const int nt = blockIdx.x & 255;
  const int le = threadIdx.x >> 6;
  const int c4 = threadIdx.x & 63;
  for (int ii = 0; ii < 4; ++ii) {
    int n = nt * 16 + le * 4 + ii;
    int row = (b << 12) + n;
    int cnt = row_cnt[row];
    int idx[24];
    const int4* ip = (const int4*)(row_idx + (size_t)row * KNN);
#pragma unroll
    for (int t = 0; t < 6; ++t) {
      int4 v = ip[t];
      idx[4 * t] = v.x; idx[4 * t + 1] = v.y; idx[4 * t + 2] = v.z; idx[4 * t + 3] = v.w;
    }
    float4 acc = make_float4(0.f, 0.f, 0.f, 0.f);
#pragma unroll
    for (int j = 0; j < 24; ++j) {
      float wgt = (j < cnt) ? 1.f : 0.f;
      float4 v = *(const float4*)&yd[(((size_t)(b << 12) + idx[j]) << 8) + c4 * 4];
      acc.x = fmaf(wgt, v.x, acc.x);
      acc.y = fmaf(wgt, v.y, acc.y);
      acc.z = fmaf(wgt, v.z, acc.z);
      acc.w = fmaf(wgt, v.w, acc.w);
    }
    float inv = 1.f / (float)cnt;
    acc.x *= inv; acc.y *= inv; acc.z *= inv; acc.w *= inv;
    *(float4*)&outf[((size_t)row << 8) + c4 * 4] = acc;
  }
}

// ---------------- K8: outf += x (residual, via LDS transpose); accumulate BN sums
__global__ __launch_bounds__(256) void k_res_bn(const float* __restrict__ x,
                                                float* __restrict__ outf,
                                                float* __restrict__ bn_sum,
                                                float* __restrict__ bn_sumsq) {
  __shared__ float xt[256 * 69];
  const int b = blockIdx.x >> 6;
  const int n0 = (blockIdx.x & 63) << 6;
  const int tid = threadIdx.x;
#pragma unroll 4
  for (int k = 0; k < 16; ++k) {
    int q = tid + 256 * k;
    int c = q >> 4, f = q & 15;
    float4 v = *(const float4*)&x[((size_t)(b * CD + c)) * NB + n0 + 4 * f];
    xt[c * 69 + 4 * f + 0] = v.x;
    xt[c * 69 + 4 * f + 1] = v.y;
    xt[c * 69 + 4 * f + 2] = v.z;
    xt[c * 69 + 4 * f + 3] = v.w;
  }
  __syncthreads();
  float s = 0.f, q = 0.f;
  const size_t rbase = ((size_t)((b << 12) + n0)) << 8;
#pragma unroll 4
  for (int i = 0; i < 64; ++i) {
    float v = outf[rbase + (size_t)i * 256 + tid] + xt[tid * 69 + i];
    outf[rbase + (size_t)i * 256 + tid] = v;
    s += v;
    q = fmaf(v, v, q);
  }
  atomicAdd(&bn_sum[tid], s);
  atomicAdd(&bn_sumsq[tid], q);
}

// ---------------- K9: BN scale/shift per channel
__global__ __launch_bounds__(256) void k_bn(const float* __restrict__ bn_sum,
                                            const float* __restrict__ bn_sumsq,
                                            const float* __restrict__ gamma,
                                            const float* __restrict__ beta,
                                            float* __restrict__ scale,
                                            float* __restrict__ shift) {
  const int c = threadIdx.x;
  const float inv = 1.f / 16384.f;
  float mean = bn_sum[c] * inv;
  float var = bn_sumsq[c] * inv - mean * mean;
  float sc = gamma[c] * rsqrtf(var + 1e-5f);
  scale[c] = sc;
  shift[c] = beta[c] - mean * sc;
}

// ---------------- K10: normalize + SiLU + transpose to [B,C,N]
__global__ __launch_bounds__(256) void k_write(const float* __restrict__ outf,
                                               const float* __restrict__ scale,
                                               const float* __restrict__ shift,
                                               float* __restrict__ out) {
  __shared__ float tile[64 * 257];
  __shared__ float sc[256], sh[256];
  const int b = blockIdx.x >> 6;
  const int n0 = (blockIdx.x & 63) << 6;
  const int tid = threadIdx.x;
  sc[tid] = scale[tid];
  sh[tid] = shift[tid];
  __syncthreads();
#pragma unroll 4
  for (int i = 0; i < 64; ++i) {
    int idx = tid + 256 * i;
    int n = idx >> 8, c = idx & 255;
    float v = outf[(((size_t)(b << 12) + n0 + n) << 8) + c];
    v = fmaf(v, sc[c], sh[c]);
    float w = v / (1.f + expf(-v));  // SiLU
    tile[n * 257 + c] = w;
  }
  __syncthreads();
  const int nl = tid & 63;
  const int cg = tid >> 6;
#pragma unroll 4
  for (int j = 0; j < 64; ++j) {
    int c = cg * 64 + j;
    out[((size_t)(b * CD + c)) * NB + n0 + nl] = tile[nl * 257 + c];
  }
}

extern "C" void kernel_launch(void* const* d_in, const int* in_sizes, int n_in,
                              void* d_out, int out_size, void* d_ws, size_t ws_size,
                              hipStream_t stream) {
  const float* x      = (const float*)d_in[0];
  const float* fc_w   = (const float*)d_in[1];
  const float* fc_b   = (const float*)d_in[2];
  const float* dist_w = (const float*)d_in[3];
  const float* gamma  = (const float*)d_in[4];
  const float* beta   = (const float*)d_in[5];
  float* out = (float*)d_out;
  char* ws = (char*)d_ws;

  const size_t OFF_EHL   = 0;                   // 4 MB
  const size_t OFF_XLIN  = (size_t)4 << 20;     // 16 MB
  const size_t OFF_YD    = (size_t)20 << 20;    // 16 MB (part buffer overlays yd+outf: both dead then)
  const size_t OFF_OUTF  = (size_t)36 << 20;    // 16 MB
  const size_t OFF_SQ    = (size_t)52 << 20;
  const size_t OFF_RIDX  = OFF_SQ + 65536;
  const size_t OFF_RCNT  = OFF_RIDX + 1572864;
  const size_t OFF_CCNT  = OFF_RCNT + 65536;
  const size_t OFF_CSTART = OFF_CCNT + 65536;
  const size_t OFF_CCUR  = OFF_CSTART + 65536;
  const size_t OFF_CLIST = OFF_CCUR + 65536;
  const size_t OFF_BNS   = OFF_CLIST + 1572864;
  const size_t OFF_BNQ   = OFF_BNS + 1024;
  const size_t OFF_SCALE = OFF_BNQ + 1024;
  const size_t OFF_SHIFT = OFF_SCALE + 1024;
  const size_t OFF_THRG  = OFF_SHIFT + 1024;    // 64 KB global per-row kNN threshold
  const size_t TOTAL = OFF_THRG + 65536;
  if (ws_size < TOTAL) return;

  unsigned* emb_hl = (unsigned*)(ws + OFF_EHL);
  float* xlin  = (float*)(ws + OFF_XLIN);
  float* yd    = (float*)(ws + OFF_YD);
  float* outf  = (float*)(ws + OFF_OUTF);
  unsigned long long* part = (unsigned long long*)(ws + OFF_YD);  // 25.2 MB overlay (yd+outf dead here)
  float* sq    = (float*)(ws + OFF_SQ);
  int* row_idx = (int*)(ws + OFF_RIDX);
  int* row_cnt = (int*)(ws + OFF_RCNT);
  int* col_cnt = (int*)(ws + OFF_CCNT);
  int* col_start = (int*)(ws + OFF_CSTART);
  int* col_cursor = (int*)(ws + OFF_CCUR);
  int* col_list = (int*)(ws + OFF_CLIST);
  float* bn_sum = (float*)(ws + OFF_BNS);
  float* bn_sumsq = (float*)(ws + OFF_BNQ);
  float* scale = (float*)(ws + OFF_SCALE);
  float* shift = (float*)(ws + OFF_SHIFT);
  unsigned* thr_g = (unsigned*)(ws + OFF_THRG);

  hipMemsetAsync(col_cnt, 0, 65536, stream);
  hipMemsetAsync(bn_sum, 0, 2048, stream);

  k_emb<<<256, 256, 0, stream>>>(x, dist_w, emb_hl, sq, thr_g);
  k_xlin<<<256, 256, 0, stream>>>(x, fc_w, fc_b, xlin);
  k_distp<<<2048, 512, 0, stream>>>(emb_hl, sq, thr_g, part);
  k_merge<<<64, 256, 0, stream>>>(part, row_idx, row_cnt, col_cnt);
  k_scan<<<1, 256, 0, stream>>>(col_cnt, col_start, col_cursor);
  k_fill<<<64, 256, 0, stream>>>(row_idx, row_cnt, col_cursor, col_list);
  k_yd<<<4096, 256, 0, stream>>>(xlin, col_cnt, col_start, col_list, yd);
  k_out2<<<1024, 256, 0, stream>>>(yd, row_idx, row_cnt, outf);
  k_res_bn<<<256, 256, 0, stream>>>(x, outf, bn_sum, bn_sumsq);
  k_bn<<<1, 256, 0, stream>>>(bn_sum, bn_sumsq, gamma, beta, scale, shift);
  k_write<<<256, 256, 0, stream>>>(outf, scale, shift, out);
}

// Round 7
// 527.726 us; speedup vs baseline: 1.3316x; 1.1558x over previous
//
#include <hip/hip_runtime.h>

#define NB 4096      // N = H*W
#define BATCH 4
#define CD 256       // channels
#define ED 64        // embedding dim
#define KNN 24

typedef __attribute__((ext_vector_type(8))) short bf16x8;
typedef __attribute__((ext_vector_type(4))) float f32x4;

__device__ __forceinline__ unsigned short f2bf(float x) {
  unsigned u = __float_as_uint(x);
  unsigned r = (u + 0x7fffu + ((u >> 16) & 1u)) >> 16;
  return (unsigned short)r;
}

// ---------------- K1: emb = x @ dist_w^T  -> emb_hl (bf16 hi/lo, XOR-swizzled chunks) + sq (fp32)
// Also inits thr_g (per-row global kNN threshold) to bits(100.0f).
__global__ __launch_bounds__(256) void k_emb(const float* __restrict__ x,
                                             const float* __restrict__ dist_w,
                                             unsigned* __restrict__ emb_hl,
                                             float* __restrict__ sq,
                                             unsigned* __restrict__ thr_g) {
  __shared__ float wds[ED * CD];   // 64 KB
  __shared__ float red[64 * 4];
  const int b = blockIdx.x >> 6;
  const int n0 = (blockIdx.x & 63) << 6;
  const int tid = threadIdx.x;
  const float4* wsrc = (const float4*)dist_w;
  float4* wdst = (float4*)wds;
#pragma unroll
  for (int k = 0; k < 16; ++k) wdst[tid + 256 * k] = wsrc[tid + 256 * k];
  __syncthreads();
  const int eg = tid >> 6;   // 0..3
  const int nl = tid & 63;
  const int n = n0 + nl;
  float acc[16];
#pragma unroll
  for (int t = 0; t < 16; ++t) acc[t] = 0.f;
  const float* xb = x + (size_t)b * CD * NB + n;
#pragma unroll 2
  for (int c4 = 0; c4 < CD; c4 += 4) {
    float x0 = xb[(size_t)(c4 + 0) * NB];
    float x1 = xb[(size_t)(c4 + 1) * NB];
    float x2 = xb[(size_t)(c4 + 2) * NB];
    float x3 = xb[(size_t)(c4 + 3) * NB];
#pragma unroll
    for (int t = 0; t < 16; ++t) {
      float4 wv = *(const float4*)&wds[(eg * 16 + t) * CD + c4];
      acc[t] = fmaf(x0, wv.x, acc[t]);
      acc[t] = fmaf(x1, wv.y, acc[t]);
      acc[t] = fmaf(x2, wv.z, acc[t]);
      acc[t] = fmaf(x3, wv.w, acc[t]);
    }
  }
  float s = 0.f;
#pragma unroll
  for (int t = 0; t < 16; ++t) s = fmaf(acc[t], acc[t], s);
  unsigned hw[8], lw[8];
#pragma unroll
  for (int i = 0; i < 8; ++i) {
    unsigned short h0 = f2bf(acc[2 * i]);
    unsigned short h1 = f2bf(acc[2 * i + 1]);
    float l0f = acc[2 * i] - __uint_as_float((unsigned)h0 << 16);
    float l1f = acc[2 * i + 1] - __uint_as_float((unsigned)h1 << 16);
    hw[i] = (unsigned)h0 | ((unsigned)h1 << 16);
    lw[i] = (unsigned)f2bf(l0f) | ((unsigned)f2bf(l1f) << 16);
  }
  uint4* g = (uint4*)emb_hl;
  const size_t gb = ((size_t)(b * NB + n)) * 16;
  const int k15 = n & 15;
  g[gb + ((2 * eg) ^ k15)]     = make_uint4(hw[0], hw[1], hw[2], hw[3]);
  g[gb + ((2 * eg + 1) ^ k15)] = make_uint4(hw[4], hw[5], hw[6], hw[7]);
  g[gb + ((8 + 2 * eg) ^ k15)]     = make_uint4(lw[0], lw[1], lw[2], lw[3]);
  g[gb + ((8 + 2 * eg + 1) ^ k15)] = make_uint4(lw[4], lw[5], lw[6], lw[7]);
  red[nl * 4 + eg] = s;
  __syncthreads();
  if (tid < 64) {
    sq[b * NB + n0 + tid] = red[tid * 4] + red[tid * 4 + 1] + red[tid * 4 + 2] + red[tid * 4 + 3];
    thr_g[(b << 12) + n0 + tid] = 0x42C80000u;  // bits(100.0f)
  }
}

// ---------------- K2: X_lin[b,n,c] = sum_k x[b,k,n]*fc_w[c,k] + fc_b[c]
__global__ __launch_bounds__(256) void k_xlin(const float* __restrict__ x,
                                              const float* __restrict__ fc_w,
                                              const float* __restrict__ fc_b,
                                              float* __restrict__ xlin) {
  __shared__ float xt[64 * 64];     // [k][n]
  __shared__ float wt[64 * 260];    // [k][c] padded
  const int b = blockIdx.x >> 6;
  const int n0 = (blockIdx.x & 63) << 6;
  const int tid = threadIdx.x;
  const int nl4 = tid & 15;
  const int cg = tid >> 4;
  float acc[4][16];
#pragma unroll
  for (int i = 0; i < 4; ++i)
#pragma unroll
    for (int j = 0; j < 16; ++j) acc[i][j] = 0.f;

  for (int kt = 0; kt < 4; ++kt) {
    __syncthreads();
#pragma unroll 4
    for (int i = 0; i < 16; ++i) {
      int idx = tid + 256 * i;
      int k = idx >> 6, n = idx & 63;
      xt[idx] = x[((size_t)(b * CD + kt * 64 + k)) * NB + n0 + n];
    }
#pragma unroll 4
    for (int i = 0; i < 16; ++i) {
      int q = tid + 256 * i;
      int c = q >> 4, k4 = (q & 15) * 4;
      float4 v = *(const float4*)&fc_w[(size_t)c * CD + kt * 64 + k4];
      wt[(k4 + 0) * 260 + c] = v.x;
      wt[(k4 + 1) * 260 + c] = v.y;
      wt[(k4 + 2) * 260 + c] = v.z;
      wt[(k4 + 3) * 260 + c] = v.w;
    }
    __syncthreads();
#pragma unroll 2
    for (int k = 0; k < 64; ++k) {
      float4 xv = *(const float4*)&xt[k * 64 + 4 * nl4];
#pragma unroll
      for (int j = 0; j < 4; ++j) {
        float4 wv = *(const float4*)&wt[k * 260 + 4 * cg + 64 * j];
        const float* wp = &wv.x;
#pragma unroll
        for (int l = 0; l < 4; ++l) {
          acc[0][4 * j + l] = fmaf(xv.x, wp[l], acc[0][4 * j + l]);
          acc[1][4 * j + l] = fmaf(xv.y, wp[l], acc[1][4 * j + l]);
          acc[2][4 * j + l] = fmaf(xv.z, wp[l], acc[2][4 * j + l]);
          acc[3][4 * j + l] = fmaf(xv.w, wp[l], acc[3][4 * j + l]);
        }
      }
    }
  }
#pragma unroll
  for (int i = 0; i < 4; ++i) {
    int n = n0 + 4 * nl4 + i;
    float* dst = xlin + ((size_t)(b * NB + n)) * CD;
#pragma unroll
    for (int j = 0; j < 4; ++j) {
      int c = 4 * cg + 64 * j;
      float4 bv = *(const float4*)&fc_b[c];
      float4 o;
      o.x = acc[i][4 * j + 0] + bv.x;
      o.y = acc[i][4 * j + 1] + bv.y;
      o.z = acc[i][4 * j + 2] + bv.z;
      o.w = acc[i][4 * j + 3] + bv.w;
      *(float4*)&dst[c] = o;
    }
  }
}

// ---------------- K3 v16 = v15 + filtered histogram adds.
// v15 PMC: SQ_LDS_BANK_CONFLICT 2.1M -> 32.6M because ~90% of d2 values exceed 100
// -> all clamp to bucket 63 -> 16 lanes/row hammer the SAME LDS address (16-way RMW
// serialization) every reg-iter. Fix: skip the atomicAdd when d2 > 100. EXACT: all
// >100 values live in bucket 63 only; cum_k for k<63 unchanged; if cum reached 24
// before bucket 63 kb is identical, else kb=63 in both versions (old: cum_63>=24
// trivially; new: falls through to kb=63 default). Pass-2 collect condition
// (bk<=kc && bits<=100) untouched -> selection bit-identical (absmax tripwire).
__global__ __launch_bounds__(512, 4) void k_distp(const unsigned* __restrict__ emb_hl,
                                                  const float* __restrict__ sq,
                                                  unsigned* __restrict__ thr_g,
                                                  unsigned long long* __restrict__ part) {
  __shared__ __align__(16) unsigned char smem[78592];
  unsigned* eN = (unsigned*)smem;                         // 16384 B
  unsigned* eM = (unsigned*)(smem + 16384);               // 16384 B
  float* sqN   = (float*)(smem + 32768);                  // 256 B
  float* sqMp  = (float*)(smem + 33024);                  // 2048 B
  int* hist    = (int*)(smem + 35072);                    // 16384 B [bucket][row] (transposed: extraction reads lane-consecutive)
  int* collectK= (int*)(smem + 51456);                    // 256 B
  int* cnt     = (int*)(smem + 51712);                    // 256 B
  unsigned long long* cand = (unsigned long long*)(smem + 51968);  // 64 x 52 x 8 = 26624 B

  const int bid = blockIdx.x;
  const int mp = bid & 7;
  const int nt = (bid >> 3) & 63;
  const int b  = bid >> 9;
  const int n0 = nt << 6;
  const int m00 = mp << 9;   // global m base of this part
  const int tid = threadIdx.x;
  const uint4* embg = (const uint4*)emb_hl;
  const size_t bbase = (size_t)b * NB;
  const int gbase = (b << 12) + n0;

#pragma unroll
  for (int k = 0; k < 2; ++k) {
    int q = tid + 512 * k;
    int r = q >> 4, ch = q & 15;
    *(uint4*)&eN[r * 64 + ch * 4] = embg[(bbase + n0 + r) * 16 + ch];
  }
  if (tid < 64) sqN[tid] = sq[b * NB + n0 + tid];
  sqMp[tid] = sq[b * NB + m00 + tid];
#pragma unroll
  for (int i = 0; i < 8; ++i) hist[tid + 512 * i] = 0;

  const int w = tid >> 6, lane = tid & 63;
  const int quad = lane >> 4, lr = lane & 15;
  const int rt = w >> 1;            // row tile 0..3
  const int ct0 = (w & 1) * 2;      // first of my 2 col tiles (of 4)
  const int rowA = rt * 16 + lr;
  const int rA = tid >> 4, chA = tid & 15;
  const int rB = rA + 32;

  uint4 pf0, pf1;

// MFMA chunk: d2 for 8 (row,col) pairs into acc0/acc1
#define CHUNK_MFMA(m0_)                                                            \
  f32x4 acc0 = {0.f, 0.f, 0.f, 0.f};                                               \
  f32x4 acc1 = {0.f, 0.f, 0.f, 0.f};                                               \
  _Pragma("unroll")                                                                \
  for (int kk = 0; kk < 2; ++kk) {                                                 \
    const int cb = quad + 4 * kk;                                                  \
    bf16x8 a_hi = *(const bf16x8*)&eN[rowA * 64 + ((cb) ^ lr) * 4];                \
    bf16x8 a_lo = *(const bf16x8*)&eN[rowA * 64 + ((cb + 8) ^ lr) * 4];            \
    int rowB0 = ct0 * 16 + lr, rowB1 = rowB0 + 16;                                 \
    bf16x8 b0_hi = *(const bf16x8*)&eM[rowB0 * 64 + ((cb) ^ lr) * 4];              \
    bf16x8 b0_lo = *(const bf16x8*)&eM[rowB0 * 64 + ((cb + 8) ^ lr) * 4];          \
    bf16x8 b1_hi = *(const bf16x8*)&eM[rowB1 * 64 + ((cb) ^ lr) * 4];              \
    bf16x8 b1_lo = *(const bf16x8*)&eM[rowB1 * 64 + ((cb + 8) ^ lr) * 4];          \
    acc0 = __builtin_amdgcn_mfma_f32_16x16x32_bf16(a_hi, b0_hi, acc0, 0, 0, 0);    \
    acc0 = __builtin_amdgcn_mfma_f32_16x16x32_bf16(a_hi, b0_lo, acc0, 0, 0, 0);    \
    acc0 = __builtin_amdgcn_mfma_f32_16x16x32_bf16(a_lo, b0_hi, acc0, 0, 0, 0);    \
    acc1 = __builtin_amdgcn_mfma_f32_16x16x32_bf16(a_hi, b1_hi, acc1, 0, 0, 0);    \
    acc1 = __builtin_amdgcn_mfma_f32_16x16x32_bf16(a_hi, b1_lo, acc1, 0, 0, 0);    \
    acc1 = __builtin_amdgcn_mfma_f32_16x16x32_bf16(a_lo, b1_hi, acc1, 0, 0, 0);    \
  }

#define STAGE_FIRST()                                                \
  pf0 = embg[(bbase + m00 + rA) * 16 + chA];                         \
  pf1 = embg[(bbase + m00 + rB) * 16 + chA];                         \
  *(uint4*)&eM[rA * 64 + chA * 4] = pf0;                             \
  *(uint4*)&eM[rB * 64 + chA * 4] = pf1;                             \
  pf0 = embg[(bbase + m00 + 64 + rA) * 16 + chA];                    \
  pf1 = embg[(bbase + m00 + 64 + rB) * 16 + chA];

#define RESTAGE(ci_, m0_)                                            \
  if ((ci_) < 7) {                                                   \
    *(uint4*)&eM[rA * 64 + chA * 4] = pf0;                           \
    *(uint4*)&eM[rB * 64 + chA * 4] = pf1;                           \
    if ((ci_) < 6) {                                                 \
      pf0 = embg[(bbase + m00 + (m0_) + 128 + rA) * 16 + chA];       \
      pf1 = embg[(bbase + m00 + (m0_) + 128 + rB) * 16 + chA];       \
    }                                                                \
  }

  // ================= PASS 1: histogram (only d2 <= 100 counted) =================
  STAGE_FIRST()
#pragma unroll 1
  for (int ci = 0; ci < 8; ++ci) {
    const int m0 = ci << 6;
    __syncthreads();  // B1: eM(ci) visible
    CHUNK_MFMA(m0)
#pragma unroll
    for (int reg = 0; reg < 4; ++reg) {
      int row = rt * 16 + quad * 4 + reg;
      int c0 = ct0 * 16 + lr, c1 = c0 + 16;
      float d20 = fmaxf(sqN[row] + sqMp[m0 + c0] - 2.f * acc0[reg], 0.f);
      float d21 = fmaxf(sqN[row] + sqMp[m0 + c1] - 2.f * acc1[reg], 0.f);
      // skip >100: those live only in bucket 63 -> kb provably unchanged (see header)
      if (__float_as_uint(d20) <= 0x42C80000u) {
        int bk0 = min(63, (int)(d20 * 0.64f));
        atomicAdd(&hist[bk0 * 64 + row], 1);
      }
      if (__float_as_uint(d21) <= 0x42C80000u) {
        int bk1 = min(63, (int)(d21 * 0.64f));
        atomicAdd(&hist[bk1 * 64 + row], 1);
      }
    }
    __syncthreads();  // B2: hist adds + eM frag reads done -> restage safe
    RESTAGE(ci, m0)
  }

  // ============ bound extraction + cross-part share ============
  if (tid < 64) {
    int cum = 0, kb = 63;
#pragma unroll 1
    for (int k2 = 0; k2 < 64; ++k2) {
      cum += hist[k2 * 64 + tid];
      if (cum >= 24) { kb = k2; break; }
    }
    // publish conservative upper edge (+1 bucket fp slack); certificate: >=24 part
    // values <= edge survive into this part's output (all bucket<=kb get collected)
    float edge = (float)(kb + 2) * 1.5625f;
    atomicMin(&thr_g[gbase + tid], __float_as_uint(edge));
    unsigned tg = thr_g[gbase + tid];  // import (stale-larger is safe)
    int kImp = min(63, (int)(__uint_as_float(tg) * 0.64f));  // v<=tg => bucket(v)<=kImp
    collectK[tid] = min(kb, kImp);
    cnt[tid] = 0;
  }
#pragma unroll
  for (int i = 0; i < 7; ++i) {  // cand sentinel init (64*52 = 3328)
    int q = tid + 512 * i;
    if (q < 64 * 52) cand[q] = ~0ULL;
  }
  __syncthreads();

  // ================= PASS 2: collect =================
  STAGE_FIRST()
#pragma unroll 1
  for (int ci = 0; ci < 8; ++ci) {
    const int m0 = ci << 6;
    __syncthreads();  // B1
    CHUNK_MFMA(m0)
#pragma unroll
    for (int reg = 0; reg < 4; ++reg) {
      int row = rt * 16 + quad * 4 + reg;
      int c0 = ct0 * 16 + lr, c1 = c0 + 16;
      float d20 = fmaxf(sqN[row] + sqMp[m0 + c0] - 2.f * acc0[reg], 0.f);
      float d21 = fmaxf(sqN[row] + sqMp[m0 + c1] - 2.f * acc1[reg], 0.f);
      int kc = collectK[row];
      unsigned bi0 = __float_as_uint(d20), bi1 = __float_as_uint(d21);
      int bk0 = min(63, (int)(d20 * 0.64f));
      int bk1 = min(63, (int)(d21 * 0.64f));
      if (bk0 <= kc && bi0 <= 0x42C80000u) {
        int pos = atomicAdd(&cnt[row], 1);
        if (pos < 52) cand[row * 52 + pos] = ((unsigned long long)bi0 << 32) | (unsigned)(m00 + m0 + c0);
      }
      if (bk1 <= kc && bi1 <= 0x42C80000u) {
        int pos = atomicAdd(&cnt[row], 1);
        if (pos < 52) cand[row * 52 + pos] = ((unsigned long long)bi1 << 32) | (unsigned)(m00 + m0 + c1);
      }
    }
    __syncthreads();  // B2
    RESTAGE(ci, m0)
  }
  __syncthreads();  // cand complete, visible to all

  // ====== sorted top-24 extraction: 8 lanes per row, shfl_xor min-reduce ======
  {
    const int row8 = tid >> 3, sub = tid & 7;
    unsigned long long last = 0;
    unsigned long long* op = part + ((size_t)bid * 64 + row8) * 24;
#pragma unroll 1
    for (int k = 0; k < 24; ++k) {
      unsigned long long lm = ~0ULL;
#pragma unroll
      for (int j2 = 0; j2 < 7; ++j2) {
        int p2 = sub + 8 * j2;
        if (p2 < 52) {
          unsigned long long v2 = cand[row8 * 52 + p2];
          if ((k == 0 || v2 > last) && v2 < lm) lm = v2;
        }
      }
#pragma unroll
      for (int s2 = 1; s2 < 8; s2 <<= 1) {
        unsigned long long o2 = __shfl_xor(lm, s2);
        if (o2 < lm) lm = o2;
      }
      if (sub == 0) op[k] = lm;  // sentinels ok; k_merge cuts
      last = lm;
    }
  }
}

// ---------------- K3b: merge 8 sorted partials per row -> row_idx/row_cnt/col_cnt
__global__ __launch_bounds__(256) void k_merge(const unsigned long long* __restrict__ part,
                                               int* __restrict__ row_idx,
                                               int* __restrict__ row_cnt,
                                               int* __restrict__ col_cnt) {
  const int row = blockIdx.x * 256 + threadIdx.x;  // b*4096 + n
  const int b = row >> 12;
  const int n = row & 4095;
  const int nt = n >> 6, r = n & 63;
  const size_t gb = (size_t)(((b << 6) | nt) << 3);  // block base (b,nt,mp=0)
  unsigned long long h[8];
  int pp[8];
#pragma unroll
  for (int t = 0; t < 8; ++t) {
    h[t] = part[((gb + t) * 64 + r) * 24];
    pp[t] = 0;
  }
  int cnt = 0;
  const int base = row * KNN;
  for (int k = 0; k < 24; ++k) {
    int bs = 0;
    unsigned long long mv = h[0];
#pragma unroll
    for (int t = 1; t < 8; ++t)
      if (h[t] < mv) { mv = h[t]; bs = t; }
    if ((unsigned)(mv >> 32) > 0x42C80000u) break;  // sentinel / beyond threshold
    int mi = (int)(mv & 0xFFFFFFFFu);
    row_idx[base + cnt] = mi;
    atomicAdd(&col_cnt[(b << 12) + mi], 1);
    ++cnt;
    int np = ++pp[bs];
    h[bs] = (np < 24) ? part[((gb + bs) * 64 + r) * 24 + np] : ~0ULL;
  }
  row_cnt[row] = cnt;
#pragma unroll 4
  for (int j = cnt; j < 24; ++j) row_idx[base + j] = n;  // pad with self (valid gather idx)
}

// ---------------- K4: exclusive scan of col_cnt (16384 entries), 1 block
__global__ __launch_bounds__(256) void k_scan(const int* __restrict__ col_cnt,
                                              int* __restrict__ col_start,
                                              int* __restrict__ col_cursor) {
  __shared__ int part[256];
  const int tid = threadIdx.x;
  const int base = tid * 64;
  int s = 0;
  for (int j = 0; j < 64; ++j) s += col_cnt[base + j];
  part[tid] = s;
  __syncthreads();
  for (int off = 1; off < 256; off <<= 1) {
    int v = (tid >= off) ? part[tid - off] : 0;
    __syncthreads();
    part[tid] += v;
    __syncthreads();
  }
  int run = part[tid] - s;
  for (int j = 0; j < 64; ++j) {
    col_start[base + j] = run;
    col_cursor[base + j] = run;
    run += col_cnt[base + j];
  }
}

// ---------------- K5: fill CSC column lists
__global__ __launch_bounds__(256) void k_fill(const int* __restrict__ row_idx,
                                              const int* __restrict__ row_cnt,
                                              int* __restrict__ col_cursor,
                                              int* __restrict__ col_list) {
  const int row = blockIdx.x * 256 + threadIdx.x;
  const int b = row >> 12;
  const int cnt = row_cnt[row];
  for (int j = 0; j < cnt; ++j) {
    int m = row_idx[row * KNN + j];
    int pos = atomicAdd(&col_cursor[(b << 12) + m], 1);
    col_list[pos] = row & 4095;
  }
}

// ---------------- K6: Yd[e,c] = (sum_{m in col(e)} X_lin[m,c]) / De[e]
__global__ __launch_bounds__(256) void k_yd(const float* __restrict__ xlin,
                                            const int* __restrict__ col_cnt,
                                            const int* __restrict__ col_start,
                                            const int* __restrict__ col_list,
                                            float* __restrict__ yd) {
  const int le = threadIdx.x >> 6;
  const int c4 = threadIdx.x & 63;
  const int be = blockIdx.x * 4 + le;
  const int b = be >> 12;
  const int deg = col_cnt[be];
  const int start = col_start[be];
  float4 acc = make_float4(0.f, 0.f, 0.f, 0.f);
  int j = 0;
  for (; j + 3 < deg; j += 4) {
    int ma = col_list[start + j], mb2 = col_list[start + j + 1];
    int mc = col_list[start + j + 2], md = col_list[start + j + 3];
    float4 va = *(const float4*)&xlin[(((size_t)(b << 12) + ma) << 8) + c4 * 4];
    float4 vb = *(const float4*)&xlin[(((size_t)(b << 12) + mb2) << 8) + c4 * 4];
    float4 vc = *(const float4*)&xlin[(((size_t)(b << 12) + mc) << 8) + c4 * 4];
    float4 vd = *(const float4*)&xlin[(((size_t)(b << 12) + md) << 8) + c4 * 4];
    acc.x += (va.x + vb.x) + (vc.x + vd.x);
    acc.y += (va.y + vb.y) + (vc.y + vd.y);
    acc.z += (va.z + vb.z) + (vc.z + vd.z);
    acc.w += (va.w + vb.w) + (vc.w + vd.w);
  }
  for (; j < deg; ++j) {
    int m = col_list[start + j];
    float4 v = *(const float4*)&xlin[(((size_t)(b << 12) + m) << 8) + c4 * 4];
    acc.x += v.x; acc.y += v.y; acc.z += v.z; acc.w += v.w;
  }
  float inv = 1.f / (float)deg;
  acc.x *= inv; acc.y *= inv; acc.z *= inv; acc.w *= inv;
  *(float4*)&yd[((size_t)be << 8) + c4 * 4] = acc;
}

// ---------------- K7: g[n,c] = (sum_{e in row(n)} Yd[e,c]) / Dv[n]
__global__ __launch_bounds__(256) void k_out2(const float* __restrict__ yd,
                                              const int* __restrict__ row_idx,
                                              const int* __restrict__ row_cnt,
                                              float* __restrict__ outf) {
  const int b = blockIdx.x >> 8;
  const int nt = blockIdx.x & 255;
  const int le = threadIdx.x >> 6;
  const int c4 = threadIdx.x & 63;
  for (int ii = 0; ii < 4; ++ii) {
    int n = nt * 16 + le * 4 + ii;
    int row = (b << 12) + n;
    int cnt = row_cnt[row];
    int idx[24];
    const int4* ip = (const int4*)(row_idx + (size_t)row * KNN);
#pragma unroll
    for (int t = 0; t < 6; ++t) {
      int4 v = ip[t];
      idx[4 * t] = v.x; idx[4 * t + 1] = v.y; idx[4 * t + 2] = v.z; idx[4 * t + 3] = v.w;
    }
    float4 acc = make_float4(0.f, 0.f, 0.f, 0.f);
#pragma unroll
    for (int j = 0; j < 24; ++j) {
      float wgt = (j < cnt) ? 1.f : 0.f;
      float4 v = *(const float4*)&yd[(((size_t)(b << 12) + idx[j]) << 8) + c4 * 4];
      acc.x = fmaf(wgt, v.x, acc.x);
      acc.y = fmaf(wgt, v.y, acc.y);
      acc.z = fmaf(wgt, v.z, acc.z);
      acc.w = fmaf(wgt, v.w, acc.w);
    }
    float inv = 1.f / (float)cnt;
    acc.x *= inv; acc.y *= inv; acc.z *= inv; acc.w *= inv;
    *(float4*)&outf[((size_t)row << 8) + c4 * 4] = acc;
  }
}

// ---------------- K8: outf += x (residual, via LDS transpose); accumulate BN sums
__global__ __launch_bounds__(256) void k_res_bn(const float* __restrict__ x,
                                                float* __restrict__ outf,
                                                float* __restrict__ bn_sum,
                                                float* __restrict__ bn_sumsq) {
  __shared__ float xt[256 * 69];
  const int b = blockIdx.x >> 6;
  const int n0 = (blockIdx.x & 63) << 6;
  const int tid = threadIdx.x;
#pragma unroll 4
  for (int k = 0; k < 16; ++k) {
    int q = tid + 256 * k;
    int c = q >> 4, f = q & 15;
    float4 v = *(const float4*)&x[((size_t)(b * CD + c)) * NB + n0 + 4 * f];
    xt[c * 69 + 4 * f + 0] = v.x;
    xt[c * 69 + 4 * f + 1] = v.y;
    xt[c * 69 + 4 * f + 2] = v.z;
    xt[c * 69 + 4 * f + 3] = v.w;
  }
  __syncthreads();
  float s = 0.f, q = 0.f;
  const size_t rbase = ((size_t)((b << 12) + n0)) << 8;
#pragma unroll 4
  for (int i = 0; i < 64; ++i) {
    float v = outf[rbase + (size_t)i * 256 + tid] + xt[tid * 69 + i];
    outf[rbase + (size_t)i * 256 + tid] = v;
    s += v;
    q = fmaf(v, v, q);
  }
  atomicAdd(&bn_sum[tid], s);
  atomicAdd(&bn_sumsq[tid], q);
}

// ---------------- K9: BN scale/shift per channel
__global__ __launch_bounds__(256) void k_bn(const float* __restrict__ bn_sum,
                                            const float* __restrict__ bn_sumsq,
                                            const float* __restrict__ gamma,
                                            const float* __restrict__ beta,
                                            float* __restrict__ scale,
                                            float* __restrict__ shift) {
  const int c = threadIdx.x;
  const float inv = 1.f / 16384.f;
  float mean = bn_sum[c] * inv;
  float var = bn_sumsq[c] * inv - mean * mean;
  float sc = gamma[c] * rsqrtf(var + 1e-5f);
  scale[c] = sc;
  shift[c] = beta[c] - mean * sc;
}

// ---------------- K10: normalize + SiLU + transpose to [B,C,N]
__global__ __launch_bounds__(256) void k_write(const float* __restrict__ outf,
                                               const float* __restrict__ scale,
                                               const float* __restrict__ shift,
                                               float* __restrict__ out) {
  __shared__ float tile[64 * 257];
  __shared__ float sc[256], sh[256];
  const int b = blockIdx.x >> 6;
  const int n0 = (blockIdx.x & 63) << 6;
  const int tid = threadIdx.x;
  sc[tid] = scale[tid];
  sh[tid] = shift[tid];
  __syncthreads();
#pragma unroll 4
  for (int i = 0; i < 64; ++i) {
    int idx = tid + 256 * i;
    int n = idx >> 8, c = idx & 255;
    float v = outf[(((size_t)(b << 12) + n0 + n) << 8) + c];
    v = fmaf(v, sc[c], sh[c]);
    float w = v / (1.f + expf(-v));  // SiLU
    tile[n * 257 + c] = w;
  }
  __syncthreads();
  const int nl = tid & 63;
  const int cg = tid >> 6;
#pragma unroll 4
  for (int j = 0; j < 64; ++j) {
    int c = cg * 64 + j;
    out[((size_t)(b * CD + c)) * NB + n0 + nl] = tile[nl * 257 + c];
  }
}

extern "C" void kernel_launch(void* const* d_in, const int* in_sizes, int n_in,
                              void* d_out, int out_size, void* d_ws, size_t ws_size,
                              hipStream_t stream) {
  const float* x      = (const float*)d_in[0];
  const float* fc_w   = (const float*)d_in[1];
  const float* fc_b   = (const float*)d_in[2];
  const float* dist_w = (const float*)d_in[3];
  const float* gamma  = (const float*)d_in[4];
  const float* beta   = (const float*)d_in[5];
  float* out = (float*)d_out;
  char* ws = (char*)d_ws;

  const size_t OFF_EHL   = 0;                   // 4 MB
  const size_t OFF_XLIN  = (size_t)4 << 20;     // 16 MB
  const size_t OFF_YD    = (size_t)20 << 20;    // 16 MB (part buffer overlays yd+outf: both dead then)
  const size_t OFF_OUTF  = (size_t)36 << 20;    // 16 MB
  const size_t OFF_SQ    = (size_t)52 << 20;
  const size_t OFF_RIDX  = OFF_SQ + 65536;
  const size_t OFF_RCNT  = OFF_RIDX + 1572864;
  const size_t OFF_CCNT  = OFF_RCNT + 65536;
  const size_t OFF_CSTART = OFF_CCNT + 65536;
  const size_t OFF_CCUR  = OFF_CSTART + 65536;
  const size_t OFF_CLIST = OFF_CCUR + 65536;
  const size_t OFF_BNS   = OFF_CLIST + 1572864;
  const size_t OFF_BNQ   = OFF_BNS + 1024;
  const size_t OFF_SCALE = OFF_BNQ + 1024;
  const size_t OFF_SHIFT = OFF_SCALE + 1024;
  const size_t OFF_THRG  = OFF_SHIFT + 1024;    // 64 KB global per-row kNN threshold
  const size_t TOTAL = OFF_THRG + 65536;
  if (ws_size < TOTAL) return;

  unsigned* emb_hl = (unsigned*)(ws + OFF_EHL);
  float* xlin  = (float*)(ws + OFF_XLIN);
  float* yd    = (float*)(ws + OFF_YD);
  float* outf  = (float*)(ws + OFF_OUTF);
  unsigned long long* part = (unsigned long long*)(ws + OFF_YD);  // 25.2 MB overlay (yd+outf dead here)
  float* sq    = (float*)(ws + OFF_SQ);
  int* row_idx = (int*)(ws + OFF_RIDX);
  int* row_cnt = (int*)(ws + OFF_RCNT);
  int* col_cnt = (int*)(ws + OFF_CCNT);
  int* col_start = (int*)(ws + OFF_CSTART);
  int* col_cursor = (int*)(ws + OFF_CCUR);
  int* col_list = (int*)(ws + OFF_CLIST);
  float* bn_sum = (float*)(ws + OFF_BNS);
  float* bn_sumsq = (float*)(ws + OFF_BNQ);
  float* scale = (float*)(ws + OFF_SCALE);
  float* shift = (float*)(ws + OFF_SHIFT);
  unsigned* thr_g = (unsigned*)(ws + OFF_THRG);

  hipMemsetAsync(col_cnt, 0, 65536, stream);
  hipMemsetAsync(bn_sum, 0, 2048, stream);

  k_emb<<<256, 256, 0, stream>>>(x, dist_w, emb_hl, sq, thr_g);
  k_xlin<<<256, 256, 0, stream>>>(x, fc_w, fc_b, xlin);
  k_distp<<<2048, 512, 0, stream>>>(emb_hl, sq, thr_g, part);
  k_merge<<<64, 256, 0, stream>>>(part, row_idx, row_cnt, col_cnt);
  k_scan<<<1, 256, 0, stream>>>(col_cnt, col_start, col_cursor);
  k_fill<<<64, 256, 0, stream>>>(row_idx, row_cnt, col_cursor, col_list);
  k_yd<<<4096, 256, 0, stream>>>(xlin, col_cnt, col_start, col_list, yd);
  k_out2<<<1024, 256, 0, stream>>>(yd, row_idx, row_cnt, outf);
  k_res_bn<<<256, 256, 0, stream>>>(x, outf, bn_sum, bn_sumsq);
  k_bn<<<1, 256, 0, stream>>>(bn_sum, bn_sumsq, gamma, beta, scale, shift);
  k_write<<<256, 256, 0, stream>>>(outf, scale, shift, out);
}

// Round 8
// 497.511 us; speedup vs baseline: 1.4125x; 1.0607x over previous
//
#include <hip/hip_runtime.h>

#define NB 4096      // N = H*W
#define BATCH 4
#define CD 256       // channels
#define ED 64        // embedding dim
#define KNN 24

typedef __attribute__((ext_vector_type(8))) short bf16x8;
typedef __attribute__((ext_vector_type(4))) float f32x4;

__device__ __forceinline__ unsigned short f2bf(float x) {
  unsigned u = __float_as_uint(x);
  unsigned r = (u + 0x7fffu + ((u >> 16) & 1u)) >> 16;
  return (unsigned short)r;
}

// ---------------- K1: emb = x @ dist_w^T  -> emb_hl (bf16 hi/lo, XOR-swizzled chunks) + sq (fp32)
// Also inits thr_g (per-row global kNN threshold) to bits(100.0f).
__global__ __launch_bounds__(256) void k_emb(const float* __restrict__ x,
                                             const float* __restrict__ dist_w,
                                             unsigned* __restrict__ emb_hl,
                                             float* __restrict__ sq,
                                             unsigned* __restrict__ thr_g) {
  __shared__ float wds[ED * CD];   // 64 KB
  __shared__ float red[64 * 4];
  const int b = blockIdx.x >> 6;
  const int n0 = (blockIdx.x & 63) << 6;
  const int tid = threadIdx.x;
  const float4* wsrc = (const float4*)dist_w;
  float4* wdst = (float4*)wds;
#pragma unroll
  for (int k = 0; k < 16; ++k) wdst[tid + 256 * k] = wsrc[tid + 256 * k];
  __syncthreads();
  const int eg = tid >> 6;   // 0..3
  const int nl = tid & 63;
  const int n = n0 + nl;
  float acc[16];
#pragma unroll
  for (int t = 0; t < 16; ++t) acc[t] = 0.f;
  const float* xb = x + (size_t)b * CD * NB + n;
#pragma unroll 2
  for (int c4 = 0; c4 < CD; c4 += 4) {
    float x0 = xb[(size_t)(c4 + 0) * NB];
    float x1 = xb[(size_t)(c4 + 1) * NB];
    float x2 = xb[(size_t)(c4 + 2) * NB];
    float x3 = xb[(size_t)(c4 + 3) * NB];
#pragma unroll
    for (int t = 0; t < 16; ++t) {
      float4 wv = *(const float4*)&wds[(eg * 16 + t) * CD + c4];
      acc[t] = fmaf(x0, wv.x, acc[t]);
      acc[t] = fmaf(x1, wv.y, acc[t]);
      acc[t] = fmaf(x2, wv.z, acc[t]);
      acc[t] = fmaf(x3, wv.w, acc[t]);
    }
  }
  float s = 0.f;
#pragma unroll
  for (int t = 0; t < 16; ++t) s = fmaf(acc[t], acc[t], s);
  unsigned hw[8], lw[8];
#pragma unroll
  for (int i = 0; i < 8; ++i) {
    unsigned short h0 = f2bf(acc[2 * i]);
    unsigned short h1 = f2bf(acc[2 * i + 1]);
    float l0f = acc[2 * i] - __uint_as_float((unsigned)h0 << 16);
    float l1f = acc[2 * i + 1] - __uint_as_float((unsigned)h1 << 16);
    hw[i] = (unsigned)h0 | ((unsigned)h1 << 16);
    lw[i] = (unsigned)f2bf(l0f) | ((unsigned)f2bf(l1f) << 16);
  }
  uint4* g = (uint4*)emb_hl;
  const size_t gb = ((size_t)(b * NB + n)) * 16;
  const int k15 = n & 15;
  g[gb + ((2 * eg) ^ k15)]     = make_uint4(hw[0], hw[1], hw[2], hw[3]);
  g[gb + ((2 * eg + 1) ^ k15)] = make_uint4(hw[4], hw[5], hw[6], hw[7]);
  g[gb + ((8 + 2 * eg) ^ k15)]     = make_uint4(lw[0], lw[1], lw[2], lw[3]);
  g[gb + ((8 + 2 * eg + 1) ^ k15)] = make_uint4(lw[4], lw[5], lw[6], lw[7]);
  red[nl * 4 + eg] = s;
  __syncthreads();
  if (tid < 64) {
    sq[b * NB + n0 + tid] = red[tid * 4] + red[tid * 4 + 1] + red[tid * 4 + 2] + red[tid * 4 + 3];
    thr_g[(b << 12) + n0 + tid] = 0x42C80000u;  // bits(100.0f)
  }
}

// ---------------- K2a: split fc_w into bf16 hi/lo chunks, distp-compatible layout.
// w_hl[(c*4+kt)*16 + (chl ^ (c&15))] = hi chunk (8 bf16), [+8^...] = lo chunk.
__global__ __launch_bounds__(256) void k_wsplit(const float* __restrict__ fc_w,
                                                unsigned* __restrict__ w_hl) {
  const int u = blockIdx.x * 256 + threadIdx.x;  // 8192 units = 256c x 32 chunk8
  const int c = u >> 5, cg = u & 31;
  const int kt = cg >> 3, chl = cg & 7;
  const float* src = fc_w + (size_t)c * CD + kt * 64 + chl * 8;
  unsigned hi[4], lo[4];
#pragma unroll
  for (int j = 0; j < 4; ++j) {
    float a0 = src[2 * j], a1 = src[2 * j + 1];
    unsigned short h0 = f2bf(a0), h1 = f2bf(a1);
    float l0 = a0 - __uint_as_float((unsigned)h0 << 16);
    float l1 = a1 - __uint_as_float((unsigned)h1 << 16);
    hi[j] = (unsigned)h0 | ((unsigned)h1 << 16);
    lo[j] = (unsigned)f2bf(l0) | ((unsigned)f2bf(l1) << 16);
  }
  uint4* dst = (uint4*)w_hl;
  const int base = (c * 4 + kt) * 16;
  const int k15 = c & 15;
  dst[base + (chl ^ k15)] = make_uint4(hi[0], hi[1], hi[2], hi[3]);
  dst[base + ((chl + 8) ^ k15)] = make_uint4(lo[0], lo[1], lo[2], lo[3]);
}

// ---------------- K2 v17: X_lin via MFMA bf16 hi/lo (3-product scheme, ~2e-4 abs err;
// selection depends only on emb -> unaffected; final absmax drift <= ~1e-3).
// Clone of k_distp's proven fragment geometry: 512 thr, 8 waves, 64n x 64c out-tile,
// K-loop 4 chunks of 64; x staged fp32 -> split in-LDS with the same XOR-swizzle.
__global__ __launch_bounds__(512) void k_xlin(const float* __restrict__ x,
                                              const unsigned* __restrict__ w_hl,
                                              const float* __restrict__ fc_b,
                                              float* __restrict__ xlin) {
  __shared__ __align__(16) unsigned char smem[49152];
  float* xt = (float*)smem;                     // 16KB [64k][64n]
  unsigned* xhl = (unsigned*)(smem + 16384);    // 16KB [64n][64 uints]
  unsigned* whl = (unsigned*)(smem + 32768);    // 16KB [64c][64 uints]
  const int bid = blockIdx.x;
  const int ct = bid & 3;
  const int nt = (bid >> 2) & 63;
  const int b = bid >> 8;
  const int n0 = nt << 6;
  const int tid = threadIdx.x;
  const int w = tid >> 6, lane = tid & 63;
  const int quad = lane >> 4, lr = lane & 15;
  const int rt = w >> 1;            // n row-tile 0..3
  const int ct0 = (w & 1) * 2;      // first of 2 c col-tiles
  const int rowA = rt * 16 + lr;
  const int cvt_n = tid & 63, cvt_k8 = tid >> 6;
  uint4* whl4 = (uint4*)whl;
  uint4* xhl4 = (uint4*)xhl;
  const uint4* wg = (const uint4*)w_hl;
  f32x4 acc0 = {0.f, 0.f, 0.f, 0.f};
  f32x4 acc1 = {0.f, 0.f, 0.f, 0.f};

#pragma unroll 1
  for (int kt = 0; kt < 4; ++kt) {
    __syncthreads();  // B0: buffers free (prev chunk's MFMA done)
#pragma unroll
    for (int i = 0; i < 8; ++i) {
      int idx = tid + 512 * i;
      int k = idx >> 6, n = idx & 63;
      xt[k * 64 + n] = x[((size_t)(b * CD + kt * 64 + k)) * NB + n0 + n];
    }
#pragma unroll
    for (int i = 0; i < 2; ++i) {
      int idx = tid + 512 * i;
      int r = idx >> 4, ch = idx & 15;
      whl4[r * 16 + ch] = wg[(size_t)((ct * 64 + r) * 4 + kt) * 16 + ch];
    }
    __syncthreads();  // B1: xt ready
    {
      unsigned hi[4], lo[4];
#pragma unroll
      for (int j = 0; j < 4; ++j) {
        float a0 = xt[(cvt_k8 * 8 + 2 * j) * 64 + cvt_n];
        float a1 = xt[(cvt_k8 * 8 + 2 * j + 1) * 64 + cvt_n];
        unsigned short h0 = f2bf(a0), h1 = f2bf(a1);
        float l0 = a0 - __uint_as_float((unsigned)h0 << 16);
        float l1 = a1 - __uint_as_float((unsigned)h1 << 16);
        hi[j] = (unsigned)h0 | ((unsigned)h1 << 16);
        lo[j] = (unsigned)f2bf(l0) | ((unsigned)f2bf(l1) << 16);
      }
      const int k15 = cvt_n & 15;
      xhl4[cvt_n * 16 + (cvt_k8 ^ k15)] = make_uint4(hi[0], hi[1], hi[2], hi[3]);
      xhl4[cvt_n * 16 + ((cvt_k8 + 8) ^ k15)] = make_uint4(lo[0], lo[1], lo[2], lo[3]);
    }
    __syncthreads();  // B2: xhl + whl ready
#pragma unroll
    for (int kk = 0; kk < 2; ++kk) {
      const int cb = quad + 4 * kk;
      bf16x8 a_hi = *(const bf16x8*)&xhl[rowA * 64 + ((cb) ^ lr) * 4];
      bf16x8 a_lo = *(const bf16x8*)&xhl[rowA * 64 + ((cb + 8) ^ lr) * 4];
      int rowB0 = ct0 * 16 + lr, rowB1 = rowB0 + 16;
      bf16x8 b0_hi = *(const bf16x8*)&whl[rowB0 * 64 + ((cb) ^ lr) * 4];
      bf16x8 b0_lo = *(const bf16x8*)&whl[rowB0 * 64 + ((cb + 8) ^ lr) * 4];
      bf16x8 b1_hi = *(const bf16x8*)&whl[rowB1 * 64 + ((cb) ^ lr) * 4];
      bf16x8 b1_lo = *(const bf16x8*)&whl[rowB1 * 64 + ((cb + 8) ^ lr) * 4];
      acc0 = __builtin_amdgcn_mfma_f32_16x16x32_bf16(a_hi, b0_hi, acc0, 0, 0, 0);
      acc0 = __builtin_amdgcn_mfma_f32_16x16x32_bf16(a_hi, b0_lo, acc0, 0, 0, 0);
      acc0 = __builtin_amdgcn_mfma_f32_16x16x32_bf16(a_lo, b0_hi, acc0, 0, 0, 0);
      acc1 = __builtin_amdgcn_mfma_f32_16x16x32_bf16(a_hi, b1_hi, acc1, 0, 0, 0);
      acc1 = __builtin_amdgcn_mfma_f32_16x16x32_bf16(a_hi, b1_lo, acc1, 0, 0, 0);
      acc1 = __builtin_amdgcn_mfma_f32_16x16x32_bf16(a_lo, b1_hi, acc1, 0, 0, 0);
    }
  }
#pragma unroll
  for (int reg = 0; reg < 4; ++reg) {
    int n = n0 + rt * 16 + quad * 4 + reg;
    float* dst = xlin + ((size_t)(b * NB + n)) * CD + ct * 64;
    int c0 = ct0 * 16 + lr;
    dst[c0] = acc0[reg] + fc_b[ct * 64 + c0];
    dst[c0 + 16] = acc1[reg] + fc_b[ct * 64 + c0 + 16];
  }
}

// ---------------- K3 v16 (unchanged): two-pass histogram select, filtered adds.
__global__ __launch_bounds__(512, 4) void k_distp(const unsigned* __restrict__ emb_hl,
                                                  const float* __restrict__ sq,
                                                  unsigned* __restrict__ thr_g,
                                                  unsigned long long* __restrict__ part) {
  __shared__ __align__(16) unsigned char smem[78592];
  unsigned* eN = (unsigned*)smem;                         // 16384 B
  unsigned* eM = (unsigned*)(smem + 16384);               // 16384 B
  float* sqN   = (float*)(smem + 32768);                  // 256 B
  float* sqMp  = (float*)(smem + 33024);                  // 2048 B
  int* hist    = (int*)(smem + 35072);                    // 16384 B [bucket][row]
  int* collectK= (int*)(smem + 51456);                    // 256 B
  int* cnt     = (int*)(smem + 51712);                    // 256 B
  unsigned long long* cand = (unsigned long long*)(smem + 51968);  // 64 x 52 x 8 = 26624 B

  const int bid = blockIdx.x;
  const int mp = bid & 7;
  const int nt = (bid >> 3) & 63;
  const int b  = bid >> 9;
  const int n0 = nt << 6;
  const int m00 = mp << 9;   // global m base of this part
  const int tid = threadIdx.x;
  const uint4* embg = (const uint4*)emb_hl;
  const size_t bbase = (size_t)b * NB;
  const int gbase = (b << 12) + n0;

#pragma unroll
  for (int k = 0; k < 2; ++k) {
    int q = tid + 512 * k;
    int r = q >> 4, ch = q & 15;
    *(uint4*)&eN[r * 64 + ch * 4] = embg[(bbase + n0 + r) * 16 + ch];
  }
  if (tid < 64) sqN[tid] = sq[b * NB + n0 + tid];
  sqMp[tid] = sq[b * NB + m00 + tid];
#pragma unroll
  for (int i = 0; i < 8; ++i) hist[tid + 512 * i] = 0;

  const int w = tid >> 6, lane = tid & 63;
  const int quad = lane >> 4, lr = lane & 15;
  const int rt = w >> 1;            // row tile 0..3
  const int ct0 = (w & 1) * 2;      // first of my 2 col tiles (of 4)
  const int rowA = rt * 16 + lr;
  const int rA = tid >> 4, chA = tid & 15;
  const int rB = rA + 32;

  uint4 pf0, pf1;

#define CHUNK_MFMA(m0_)                                                            \
  f32x4 acc0 = {0.f, 0.f, 0.f, 0.f};                                               \
  f32x4 acc1 = {0.f, 0.f, 0.f, 0.f};                                               \
  _Pragma("unroll")                                                                \
  for (int kk = 0; kk < 2; ++kk) {                                                 \
    const int cb = quad + 4 * kk;                                                  \
    bf16x8 a_hi = *(const bf16x8*)&eN[rowA * 64 + ((cb) ^ lr) * 4];                \
    bf16x8 a_lo = *(const bf16x8*)&eN[rowA * 64 + ((cb + 8) ^ lr) * 4];            \
    int rowB0 = ct0 * 16 + lr, rowB1 = rowB0 + 16;                                 \
    bf16x8 b0_hi = *(const bf16x8*)&eM[rowB0 * 64 + ((cb) ^ lr) * 4];              \
    bf16x8 b0_lo = *(const bf16x8*)&eM[rowB0 * 64 + ((cb + 8) ^ lr) * 4];          \
    bf16x8 b1_hi = *(const bf16x8*)&eM[rowB1 * 64 + ((cb) ^ lr) * 4];              \
    bf16x8 b1_lo = *(const bf16x8*)&eM[rowB1 * 64 + ((cb + 8) ^ lr) * 4];          \
    acc0 = __builtin_amdgcn_mfma_f32_16x16x32_bf16(a_hi, b0_hi, acc0, 0, 0, 0);    \
    acc0 = __builtin_amdgcn_mfma_f32_16x16x32_bf16(a_hi, b0_lo, acc0, 0, 0, 0);    \
    acc0 = __builtin_amdgcn_mfma_f32_16x16x32_bf16(a_lo, b0_hi, acc0, 0, 0, 0);    \
    acc1 = __builtin_amdgcn_mfma_f32_16x16x32_bf16(a_hi, b1_hi, acc1, 0, 0, 0);    \
    acc1 = __builtin_amdgcn_mfma_f32_16x16x32_bf16(a_hi, b1_lo, acc1, 0, 0, 0);    \
    acc1 = __builtin_amdgcn_mfma_f32_16x16x32_bf16(a_lo, b1_hi, acc1, 0, 0, 0);    \
  }

#define STAGE_FIRST()                                                \
  pf0 = embg[(bbase + m00 + rA) * 16 + chA];                         \
  pf1 = embg[(bbase + m00 + rB) * 16 + chA];                         \
  *(uint4*)&eM[rA * 64 + chA * 4] = pf0;                             \
  *(uint4*)&eM[rB * 64 + chA * 4] = pf1;                             \
  pf0 = embg[(bbase + m00 + 64 + rA) * 16 + chA];                    \
  pf1 = embg[(bbase + m00 + 64 + rB) * 16 + chA];

#define RESTAGE(ci_, m0_)                                            \
  if ((ci_) < 7) {                                                   \
    *(uint4*)&eM[rA * 64 + chA * 4] = pf0;                           \
    *(uint4*)&eM[rB * 64 + chA * 4] = pf1;                           \
    if ((ci_) < 6) {                                                 \
      pf0 = embg[(bbase + m00 + (m0_) + 128 + rA) * 16 + chA];       \
      pf1 = embg[(bbase + m00 + (m0_) + 128 + rB) * 16 + chA];       \
    }                                                                \
  }

  // ================= PASS 1: histogram (only d2 <= 100 counted) =================
  STAGE_FIRST()
#pragma unroll 1
  for (int ci = 0; ci < 8; ++ci) {
    const int m0 = ci << 6;
    __syncthreads();  // B1: eM(ci) visible
    CHUNK_MFMA(m0)
#pragma unroll
    for (int reg = 0; reg < 4; ++reg) {
      int row = rt * 16 + quad * 4 + reg;
      int c0 = ct0 * 16 + lr, c1 = c0 + 16;
      float d20 = fmaxf(sqN[row] + sqMp[m0 + c0] - 2.f * acc0[reg], 0.f);
      float d21 = fmaxf(sqN[row] + sqMp[m0 + c1] - 2.f * acc1[reg], 0.f);
      if (__float_as_uint(d20) <= 0x42C80000u) {
        int bk0 = min(63, (int)(d20 * 0.64f));
        atomicAdd(&hist[bk0 * 64 + row], 1);
      }
      if (__float_as_uint(d21) <= 0x42C80000u) {
        int bk1 = min(63, (int)(d21 * 0.64f));
        atomicAdd(&hist[bk1 * 64 + row], 1);
      }
    }
    __syncthreads();  // B2: hist adds + eM frag reads done -> restage safe
    RESTAGE(ci, m0)
  }

  // ============ bound extraction + cross-part share ============
  if (tid < 64) {
    int cum = 0, kb = 63;
#pragma unroll 1
    for (int k2 = 0; k2 < 64; ++k2) {
      cum += hist[k2 * 64 + tid];
      if (cum >= 24) { kb = k2; break; }
    }
    float edge = (float)(kb + 2) * 1.5625f;
    atomicMin(&thr_g[gbase + tid], __float_as_uint(edge));
    unsigned tg = thr_g[gbase + tid];  // import (stale-larger is safe)
    int kImp = min(63, (int)(__uint_as_float(tg) * 0.64f));
    collectK[tid] = min(kb, kImp);
    cnt[tid] = 0;
  }
#pragma unroll
  for (int i = 0; i < 7; ++i) {  // cand sentinel init (64*52 = 3328)
    int q = tid + 512 * i;
    if (q < 64 * 52) cand[q] = ~0ULL;
  }
  __syncthreads();

  // ================= PASS 2: collect =================
  STAGE_FIRST()
#pragma unroll 1
  for (int ci = 0; ci < 8; ++ci) {
    const int m0 = ci << 6;
    __syncthreads();  // B1
    CHUNK_MFMA(m0)
#pragma unroll
    for (int reg = 0; reg < 4; ++reg) {
      int row = rt * 16 + quad * 4 + reg;
      int c0 = ct0 * 16 + lr, c1 = c0 + 16;
      float d20 = fmaxf(sqN[row] + sqMp[m0 + c0] - 2.f * acc0[reg], 0.f);
      float d21 = fmaxf(sqN[row] + sqMp[m0 + c1] - 2.f * acc1[reg], 0.f);
      int kc = collectK[row];
      unsigned bi0 = __float_as_uint(d20), bi1 = __float_as_uint(d21);
      int bk0 = min(63, (int)(d20 * 0.64f));
      int bk1 = min(63, (int)(d21 * 0.64f));
      if (bk0 <= kc && bi0 <= 0x42C80000u) {
        int pos = atomicAdd(&cnt[row], 1);
        if (pos < 52) cand[row * 52 + pos] = ((unsigned long long)bi0 << 32) | (unsigned)(m00 + m0 + c0);
      }
      if (bk1 <= kc && bi1 <= 0x42C80000u) {
        int pos = atomicAdd(&cnt[row], 1);
        if (pos < 52) cand[row * 52 + pos] = ((unsigned long long)bi1 << 32) | (unsigned)(m00 + m0 + c1);
      }
    }
    __syncthreads();  // B2
    RESTAGE(ci, m0)
  }
  __syncthreads();  // cand complete, visible to all

  // ====== sorted top-24 extraction: 8 lanes per row, shfl_xor min-reduce ======
  {
    const int row8 = tid >> 3, sub = tid & 7;
    unsigned long long last = 0;
    unsigned long long* op = part + ((size_t)bid * 64 + row8) * 24;
#pragma unroll 1
    for (int k = 0; k < 24; ++k) {
      unsigned long long lm = ~0ULL;
#pragma unroll
      for (int j2 = 0; j2 < 7; ++j2) {
        int p2 = sub + 8 * j2;
        if (p2 < 52) {
          unsigned long long v2 = cand[row8 * 52 + p2];
          if ((k == 0 || v2 > last) && v2 < lm) lm = v2;
        }
      }
#pragma unroll
      for (int s2 = 1; s2 < 8; s2 <<= 1) {
        unsigned long long o2 = __shfl_xor(lm, s2);
        if (o2 < lm) lm = o2;
      }
      if (sub == 0) op[k] = lm;  // sentinels ok; k_merge cuts
      last = lm;
    }
  }
}

// ---------------- K3b: merge 8 sorted partials per row (v17: 256 blocks x 64 thr)
__global__ __launch_bounds__(64) void k_merge(const unsigned long long* __restrict__ part,
                                              int* __restrict__ row_idx,
                                              int* __restrict__ row_cnt,
                                              int* __restrict__ col_cnt) {
  const int row = blockIdx.x * 64 + threadIdx.x;  // b*4096 + n
  const int b = row >> 12;
  const int n = row & 4095;
  const int nt = n >> 6, r = n & 63;
  const size_t gb = (size_t)(((b << 6) | nt) << 3);  // block base (b,nt,mp=0)
  unsigned long long h[8];
  int pp[8];
#pragma unroll
  for (int t = 0; t < 8; ++t) {
    h[t] = part[((gb + t) * 64 + r) * 24];
    pp[t] = 0;
  }
  int cnt = 0;
  const int base = row * KNN;
  for (int k = 0; k < 24; ++k) {
    int bs = 0;
    unsigned long long mv = h[0];
#pragma unroll
    for (int t = 1; t < 8; ++t)
      if (h[t] < mv) { mv = h[t]; bs = t; }
    if ((unsigned)(mv >> 32) > 0x42C80000u) break;  // sentinel / beyond threshold
    int mi = (int)(mv & 0xFFFFFFFFu);
    row_idx[base + cnt] = mi;
    atomicAdd(&col_cnt[(b << 12) + mi], 1);
    ++cnt;
    int np = ++pp[bs];
    h[bs] = (np < 24) ? part[((gb + bs) * 64 + r) * 24 + np] : ~0ULL;
  }
  row_cnt[row] = cnt;
#pragma unroll 4
  for (int j = cnt; j < 24; ++j) row_idx[base + j] = n;  // pad with self (valid gather idx)
}

// ---------------- K4: exclusive scan of col_cnt (16384 entries), 1 block
__global__ __launch_bounds__(256) void k_scan(const int* __restrict__ col_cnt,
                                              int* __restrict__ col_start,
                                              int* __restrict__ col_cursor) {
  __shared__ int part[256];
  const int tid = threadIdx.x;
  const int base = tid * 64;
  int s = 0;
  for (int j = 0; j < 64; ++j) s += col_cnt[base + j];
  part[tid] = s;
  __syncthreads();
  for (int off = 1; off < 256; off <<= 1) {
    int v = (tid >= off) ? part[tid - off] : 0;
    __syncthreads();
    part[tid] += v;
    __syncthreads();
  }
  int run = part[tid] - s;
  for (int j = 0; j < 64; ++j) {
    col_start[base + j] = run;
    col_cursor[base + j] = run;
    run += col_cnt[base + j];
  }
}

// ---------------- K5: fill CSC column lists (v17: 256 blocks x 64 thr)
__global__ __launch_bounds__(64) void k_fill(const int* __restrict__ row_idx,
                                             const int* __restrict__ row_cnt,
                                             int* __restrict__ col_cursor,
                                             int* __restrict__ col_list) {
  const int row = blockIdx.x * 64 + threadIdx.x;
  const int b = row >> 12;
  const int cnt = row_cnt[row];
  for (int j = 0; j < cnt; ++j) {
    int m = row_idx[row * KNN + j];
    int pos = atomicAdd(&col_cursor[(b << 12) + m], 1);
    col_list[pos] = row & 4095;
  }
}

// ---------------- K6: Yd[e,c] = (sum_{m in col(e)} X_lin[m,c]) / De[e]
__global__ __launch_bounds__(256) void k_yd(const float* __restrict__ xlin,
                                            const int* __restrict__ col_cnt,
                                            const int* __restrict__ col_start,
                                            const int* __restrict__ col_list,
                                            float* __restrict__ yd) {
  const int le = threadIdx.x >> 6;
  const int c4 = threadIdx.x & 63;
  const int be = blockIdx.x * 4 + le;
  const int b = be >> 12;
  const int deg = col_cnt[be];
  const int start = col_start[be];
  float4 acc = make_float4(0.f, 0.f, 0.f, 0.f);
  int j = 0;
  for (; j + 3 < deg; j += 4) {
    int ma = col_list[start + j], mb2 = col_list[start + j + 1];
    int mc = col_list[start + j + 2], md = col_list[start + j + 3];
    float4 va = *(const float4*)&xlin[(((size_t)(b << 12) + ma) << 8) + c4 * 4];
    float4 vb = *(const float4*)&xlin[(((size_t)(b << 12) + mb2) << 8) + c4 * 4];
    float4 vc = *(const float4*)&xlin[(((size_t)(b << 12) + mc) << 8) + c4 * 4];
    float4 vd = *(const float4*)&xlin[(((size_t)(b << 12) + md) << 8) + c4 * 4];
    acc.x += (va.x + vb.x) + (vc.x + vd.x);
    acc.y += (va.y + vb.y) + (vc.y + vd.y);
    acc.z += (va.z + vb.z) + (vc.z + vd.z);
    acc.w += (va.w + vb.w) + (vc.w + vd.w);
  }
  for (; j < deg; ++j) {
    int m = col_list[start + j];
    float4 v = *(const float4*)&xlin[(((size_t)(b << 12) + m) << 8) + c4 * 4];
    acc.x += v.x; acc.y += v.y; acc.z += v.z; acc.w += v.w;
  }
  float inv = 1.f / (float)deg;
  acc.x *= inv; acc.y *= inv; acc.z *= inv; acc.w *= inv;
  *(float4*)&yd[((size_t)be << 8) + c4 * 4] = acc;
}

// ---------------- K7: g[n,c] = (sum_{e in row(n)} Yd[e,c]) / Dv[n]
__global__ __launch_bounds__(256) void k_out2(const float* __restrict__ yd,
                                              const int* __restrict__ row_idx,
                                              const int* __restrict__ row_cnt,
                                              float* __restrict__ outf) {
  const int b = blockIdx.x >> 8;
  const int nt = blockIdx.x & 255;
  const int le = threadIdx.x >> 6;
  const int c4 = threadIdx.x & 63;
  for (int ii = 0; ii < 4; ++ii) {
    int n = nt * 16 + le * 4 + ii;
    int row = (b << 12) + n;
    int cnt = row_cnt[row];
    int idx[24];
    const int4* ip = (const int4*)(row_idx + (size_t)row * KNN);
#pragma unroll
    for (int t = 0; t < 6; ++t) {
      int4 v = ip[t];
      idx[4 * t] = v.x; idx[4 * t + 1] = v.y; idx[4 * t + 2] = v.z; idx[4 * t + 3] = v.w;
    }
    float4 acc = make_float4(0.f, 0.f, 0.f, 0.f);
#pragma unroll
    for (int j = 0; j < 24; ++j) {
      float wgt = (j < cnt) ? 1.f : 0.f;
      float4 v = *(const float4*)&yd[(((size_t)(b << 12) + idx[j]) << 8) + c4 * 4];
      acc.x = fmaf(wgt, v.x, acc.x);
      acc.y = fmaf(wgt, v.y, acc.y);
      acc.z = fmaf(wgt, v.z, acc.z);
      acc.w = fmaf(wgt, v.w, acc.w);
    }
    float inv = 1.f / (float)cnt;
    acc.x *= inv; acc.y *= inv; acc.z *= inv; acc.w *= inv;
    *(float4*)&outf[((size_t)row << 8) + c4 * 4] = acc;
  }
}

// ---------------- K8: outf += x (residual, via LDS transpose); accumulate BN sums
__global__ __launch_bounds__(256) void k_res_bn(const float* __restrict__ x,
                                                float* __restrict__ outf,
                                                float* __restrict__ bn_sum,
                                                float* __restrict__ bn_sumsq) {
  __shared__ float xt[256 * 69];
  const int b = blockIdx.x >> 6;
  const int n0 = (blockIdx.x & 63) << 6;
  const int tid = threadIdx.x;
#pragma unroll 4
  for (int k = 0; k < 16; ++k) {
    int q = tid + 256 * k;
    int c = q >> 4, f = q & 15;
    float4 v = *(const float4*)&x[((size_t)(b * CD + c)) * NB + n0 + 4 * f];
    xt[c * 69 + 4 * f + 0] = v.x;
    xt[c * 69 + 4 * f + 1] = v.y;
    xt[c * 69 + 4 * f + 2] = v.z;
    xt[c * 69 + 4 * f + 3] = v.w;
  }
  __syncthreads();
  float s = 0.f, q = 0.f;
  const size_t rbase = ((size_t)((b << 12) + n0)) << 8;
#pragma unroll 4
  for (int i = 0; i < 64; ++i) {
    float v = outf[rbase + (size_t)i * 256 + tid] + xt[tid * 69 + i];
    outf[rbase + (size_t)i * 256 + tid] = v;
    s += v;
    q = fmaf(v, v, q);
  }
  atomicAdd(&bn_sum[tid], s);
  atomicAdd(&bn_sumsq[tid], q);
}

// ---------------- K10 v17: BN (per-block recompute, bit-identical to old k_bn) + SiLU + transpose
__global__ __launch_bounds__(256) void k_write(const float* __restrict__ outf,
                                               const float* __restrict__ bn_sum,
                                               const float* __restrict__ bn_sumsq,
                                               const float* __restrict__ gamma,
                                               const float* __restrict__ beta,
                                               float* __restrict__ out) {
  __shared__ float tile[64 * 257];
  __shared__ float sc[256], sh[256];
  const int b = blockIdx.x >> 6;
  const int n0 = (blockIdx.x & 63) << 6;
  const int tid = threadIdx.x;
  {
    const float inv = 1.f / 16384.f;
    float mean = bn_sum[tid] * inv;
    float var = bn_sumsq[tid] * inv - mean * mean;
    float scf = gamma[tid] * rsqrtf(var + 1e-5f);
    sc[tid] = scf;
    sh[tid] = beta[tid] - mean * scf;
  }
  __syncthreads();
#pragma unroll 4
  for (int i = 0; i < 64; ++i) {
    int idx = tid + 256 * i;
    int n = idx >> 8, c = idx & 255;
    float v = outf[(((size_t)(b << 12) + n0 + n) << 8) + c];
    v = fmaf(v, sc[c], sh[c]);
    float w = v / (1.f + expf(-v));  // SiLU
    tile[n * 257 + c] = w;
  }
  __syncthreads();
  const int nl = tid & 63;
  const int cg = tid >> 6;
#pragma unroll 4
  for (int j = 0; j < 64; ++j) {
    int c = cg * 64 + j;
    out[((size_t)(b * CD + c)) * NB + n0 + nl] = tile[nl * 257 + c];
  }
}

extern "C" void kernel_launch(void* const* d_in, const int* in_sizes, int n_in,
                              void* d_out, int out_size, void* d_ws, size_t ws_size,
                              hipStream_t stream) {
  const float* x      = (const float*)d_in[0];
  const float* fc_w   = (const float*)d_in[1];
  const float* fc_b   = (const float*)d_in[2];
  const float* dist_w = (const float*)d_in[3];
  const float* gamma  = (const float*)d_in[4];
  const float* beta   = (const float*)d_in[5];
  float* out = (float*)d_out;
  char* ws = (char*)d_ws;

  const size_t OFF_EHL   = 0;                   // 4 MB
  const size_t OFF_XLIN  = (size_t)4 << 20;     // 16 MB
  const size_t OFF_YD    = (size_t)20 << 20;    // 16 MB (part buffer overlays yd+outf: both dead then)
  const size_t OFF_OUTF  = (size_t)36 << 20;    // 16 MB
  const size_t OFF_SQ    = (size_t)52 << 20;
  const size_t OFF_RIDX  = OFF_SQ + 65536;
  const size_t OFF_RCNT  = OFF_RIDX + 1572864;
  const size_t OFF_CCNT  = OFF_RCNT + 65536;
  const size_t OFF_CSTART = OFF_CCNT + 65536;
  const size_t OFF_CCUR  = OFF_CSTART + 65536;
  const size_t OFF_CLIST = OFF_CCUR + 65536;
  const size_t OFF_BNS   = OFF_CLIST + 1572864;
  const size_t OFF_BNQ   = OFF_BNS + 1024;
  const size_t OFF_THRG  = OFF_BNQ + 1024;      // 64 KB global per-row kNN threshold
  const size_t OFF_WHL   = OFF_THRG + 65536;    // 256 KB fc_w bf16 hi/lo split
  const size_t TOTAL = OFF_WHL + 262144;
  if (ws_size < TOTAL) return;

  unsigned* emb_hl = (unsigned*)(ws + OFF_EHL);
  float* xlin  = (float*)(ws + OFF_XLIN);
  float* yd    = (float*)(ws + OFF_YD);
  float* outf  = (float*)(ws + OFF_OUTF);
  unsigned long long* part = (unsigned long long*)(ws + OFF_YD);  // 25.2 MB overlay (yd+outf dead here)
  float* sq    = (float*)(ws + OFF_SQ);
  int* row_idx = (int*)(ws + OFF_RIDX);
  int* row_cnt = (int*)(ws + OFF_RCNT);
  int* col_cnt = (int*)(ws + OFF_CCNT);
  int* col_start = (int*)(ws + OFF_CSTART);
  int* col_cursor = (int*)(ws + OFF_CCUR);
  int* col_list = (int*)(ws + OFF_CLIST);
  float* bn_sum = (float*)(ws + OFF_BNS);
  float* bn_sumsq = (float*)(ws + OFF_BNQ);
  unsigned* thr_g = (unsigned*)(ws + OFF_THRG);
  unsigned* w_hl = (unsigned*)(ws + OFF_WHL);

  hipMemsetAsync(col_cnt, 0, 65536, stream);
  hipMemsetAsync(bn_sum, 0, 2048, stream);

  k_emb<<<256, 256, 0, stream>>>(x, dist_w, emb_hl, sq, thr_g);
  k_wsplit<<<32, 256, 0, stream>>>(fc_w, w_hl);
  k_xlin<<<1024, 512, 0, stream>>>(x, w_hl, fc_b, xlin);
  k_distp<<<2048, 512, 0, stream>>>(emb_hl, sq, thr_g, part);
  k_merge<<<256, 64, 0, stream>>>(part, row_idx, row_cnt, col_cnt);
  k_scan<<<1, 256, 0, stream>>>(col_cnt, col_start, col_cursor);
  k_fill<<<256, 64, 0, stream>>>(row_idx, row_cnt, col_cursor, col_list);
  k_yd<<<4096, 256, 0, stream>>>(xlin, col_cnt, col_start, col_list, yd);
  k_out2<<<1024, 256, 0, stream>>>(yd, row_idx, row_cnt, outf);
  k_res_bn<<<256, 256, 0, stream>>>(x, outf, bn_sum, bn_sumsq);
  k_write<<<256, 256, 0, stream>>>(outf, bn_sum, bn_sumsq, gamma, beta, out);
}

// Round 9
// 491.062 us; speedup vs baseline: 1.4310x; 1.0131x over previous
//
#include <hip/hip_runtime.h>

#define NB 4096      // N = H*W
#define BATCH 4
#define CD 256       // channels
#define ED 64        // embedding dim
#define KNN 24

typedef __attribute__((ext_vector_type(8))) short bf16x8;
typedef __attribute__((ext_vector_type(4))) float f32x4;

__device__ __forceinline__ unsigned short f2bf(float x) {
  unsigned u = __float_as_uint(x);
  unsigned r = (u + 0x7fffu + ((u >> 16) & 1u)) >> 16;
  return (unsigned short)r;
}

// ---------------- K1: emb = x @ dist_w^T  -> emb_hl (bf16 hi/lo, XOR-swizzled chunks) + sq (fp32)
// Also inits thr_g (per-row global kNN threshold) to bits(100.0f).
__global__ __launch_bounds__(256) void k_emb(const float* __restrict__ x,
                                             const float* __restrict__ dist_w,
                                             unsigned* __restrict__ emb_hl,
                                             float* __restrict__ sq,
                                             unsigned* __restrict__ thr_g) {
  __shared__ float wds[ED * CD];   // 64 KB
  __shared__ float red[64 * 4];
  const int b = blockIdx.x >> 6;
  const int n0 = (blockIdx.x & 63) << 6;
  const int tid = threadIdx.x;
  const float4* wsrc = (const float4*)dist_w;
  float4* wdst = (float4*)wds;
#pragma unroll
  for (int k = 0; k < 16; ++k) wdst[tid + 256 * k] = wsrc[tid + 256 * k];
  __syncthreads();
  const int eg = tid >> 6;   // 0..3
  const int nl = tid & 63;
  const int n = n0 + nl;
  float acc[16];
#pragma unroll
  for (int t = 0; t < 16; ++t) acc[t] = 0.f;
  const float* xb = x + (size_t)b * CD * NB + n;
#pragma unroll 2
  for (int c4 = 0; c4 < CD; c4 += 4) {
    float x0 = xb[(size_t)(c4 + 0) * NB];
    float x1 = xb[(size_t)(c4 + 1) * NB];
    float x2 = xb[(size_t)(c4 + 2) * NB];
    float x3 = xb[(size_t)(c4 + 3) * NB];
#pragma unroll
    for (int t = 0; t < 16; ++t) {
      float4 wv = *(const float4*)&wds[(eg * 16 + t) * CD + c4];
      acc[t] = fmaf(x0, wv.x, acc[t]);
      acc[t] = fmaf(x1, wv.y, acc[t]);
      acc[t] = fmaf(x2, wv.z, acc[t]);
      acc[t] = fmaf(x3, wv.w, acc[t]);
    }
  }
  float s = 0.f;
#pragma unroll
  for (int t = 0; t < 16; ++t) s = fmaf(acc[t], acc[t], s);
  unsigned hw[8], lw[8];
#pragma unroll
  for (int i = 0; i < 8; ++i) {
    unsigned short h0 = f2bf(acc[2 * i]);
    unsigned short h1 = f2bf(acc[2 * i + 1]);
    float l0f = acc[2 * i] - __uint_as_float((unsigned)h0 << 16);
    float l1f = acc[2 * i + 1] - __uint_as_float((unsigned)h1 << 16);
    hw[i] = (unsigned)h0 | ((unsigned)h1 << 16);
    lw[i] = (unsigned)f2bf(l0f) | ((unsigned)f2bf(l1f) << 16);
  }
  uint4* g = (uint4*)emb_hl;
  const size_t gb = ((size_t)(b * NB + n)) * 16;
  const int k15 = n & 15;
  g[gb + ((2 * eg) ^ k15)]     = make_uint4(hw[0], hw[1], hw[2], hw[3]);
  g[gb + ((2 * eg + 1) ^ k15)] = make_uint4(hw[4], hw[5], hw[6], hw[7]);
  g[gb + ((8 + 2 * eg) ^ k15)]     = make_uint4(lw[0], lw[1], lw[2], lw[3]);
  g[gb + ((8 + 2 * eg + 1) ^ k15)] = make_uint4(lw[4], lw[5], lw[6], lw[7]);
  red[nl * 4 + eg] = s;
  __syncthreads();
  if (tid < 64) {
    sq[b * NB + n0 + tid] = red[tid * 4] + red[tid * 4 + 1] + red[tid * 4 + 2] + red[tid * 4 + 3];
    thr_g[(b << 12) + n0 + tid] = 0x42C80000u;  // bits(100.0f)
  }
}

// ---------------- K2a: split fc_w into bf16 hi/lo chunks, distp-compatible layout.
__global__ __launch_bounds__(256) void k_wsplit(const float* __restrict__ fc_w,
                                                unsigned* __restrict__ w_hl) {
  const int u = blockIdx.x * 256 + threadIdx.x;  // 8192 units = 256c x 32 chunk8
  const int c = u >> 5, cg = u & 31;
  const int kt = cg >> 3, chl = cg & 7;
  const float* src = fc_w + (size_t)c * CD + kt * 64 + chl * 8;
  unsigned hi[4], lo[4];
#pragma unroll
  for (int j = 0; j < 4; ++j) {
    float a0 = src[2 * j], a1 = src[2 * j + 1];
    unsigned short h0 = f2bf(a0), h1 = f2bf(a1);
    float l0 = a0 - __uint_as_float((unsigned)h0 << 16);
    float l1 = a1 - __uint_as_float((unsigned)h1 << 16);
    hi[j] = (unsigned)h0 | ((unsigned)h1 << 16);
    lo[j] = (unsigned)f2bf(l0) | ((unsigned)f2bf(l1) << 16);
  }
  uint4* dst = (uint4*)w_hl;
  const int base = (c * 4 + kt) * 16;
  const int k15 = c & 15;
  dst[base + (chl ^ k15)] = make_uint4(hi[0], hi[1], hi[2], hi[3]);
  dst[base + ((chl + 8) ^ k15)] = make_uint4(lo[0], lo[1], lo[2], lo[3]);
}

// ---------------- K2 v17: X_lin via MFMA bf16 hi/lo (unchanged)
__global__ __launch_bounds__(512) void k_xlin(const float* __restrict__ x,
                                              const unsigned* __restrict__ w_hl,
                                              const float* __restrict__ fc_b,
                                              float* __restrict__ xlin) {
  __shared__ __align__(16) unsigned char smem[49152];
  float* xt = (float*)smem;                     // 16KB [64k][64n]
  unsigned* xhl = (unsigned*)(smem + 16384);    // 16KB [64n][64 uints]
  unsigned* whl = (unsigned*)(smem + 32768);    // 16KB [64c][64 uints]
  const int bid = blockIdx.x;
  const int ct = bid & 3;
  const int nt = (bid >> 2) & 63;
  const int b = bid >> 8;
  const int n0 = nt << 6;
  const int tid = threadIdx.x;
  const int w = tid >> 6, lane = tid & 63;
  const int quad = lane >> 4, lr = lane & 15;
  const int rt = w >> 1;            // n row-tile 0..3
  const int ct0 = (w & 1) * 2;      // first of 2 c col-tiles
  const int rowA = rt * 16 + lr;
  const int cvt_n = tid & 63, cvt_k8 = tid >> 6;
  uint4* whl4 = (uint4*)whl;
  uint4* xhl4 = (uint4*)xhl;
  const uint4* wg = (const uint4*)w_hl;
  f32x4 acc0 = {0.f, 0.f, 0.f, 0.f};
  f32x4 acc1 = {0.f, 0.f, 0.f, 0.f};

#pragma unroll 1
  for (int kt = 0; kt < 4; ++kt) {
    __syncthreads();  // B0: buffers free (prev chunk's MFMA done)
#pragma unroll
    for (int i = 0; i < 8; ++i) {
      int idx = tid + 512 * i;
      int k = idx >> 6, n = idx & 63;
      xt[k * 64 + n] = x[((size_t)(b * CD + kt * 64 + k)) * NB + n0 + n];
    }
#pragma unroll
    for (int i = 0; i < 2; ++i) {
      int idx = tid + 512 * i;
      int r = idx >> 4, ch = idx & 15;
      whl4[r * 16 + ch] = wg[(size_t)((ct * 64 + r) * 4 + kt) * 16 + ch];
    }
    __syncthreads();  // B1: xt ready
    {
      unsigned hi[4], lo[4];
#pragma unroll
      for (int j = 0; j < 4; ++j) {
        float a0 = xt[(cvt_k8 * 8 + 2 * j) * 64 + cvt_n];
        float a1 = xt[(cvt_k8 * 8 + 2 * j + 1) * 64 + cvt_n];
        unsigned short h0 = f2bf(a0), h1 = f2bf(a1);
        float l0 = a0 - __uint_as_float((unsigned)h0 << 16);
        float l1 = a1 - __uint_as_float((unsigned)h1 << 16);
        hi[j] = (unsigned)h0 | ((unsigned)h1 << 16);
        lo[j] = (unsigned)f2bf(l0) | ((unsigned)f2bf(l1) << 16);
      }
      const int k15 = cvt_n & 15;
      xhl4[cvt_n * 16 + (cvt_k8 ^ k15)] = make_uint4(hi[0], hi[1], hi[2], hi[3]);
      xhl4[cvt_n * 16 + ((cvt_k8 + 8) ^ k15)] = make_uint4(lo[0], lo[1], lo[2], lo[3]);
    }
    __syncthreads();  // B2: xhl + whl ready
#pragma unroll
    for (int kk = 0; kk < 2; ++kk) {
      const int cb = quad + 4 * kk;
      bf16x8 a_hi = *(const bf16x8*)&xhl[rowA * 64 + ((cb) ^ lr) * 4];
      bf16x8 a_lo = *(const bf16x8*)&xhl[rowA * 64 + ((cb + 8) ^ lr) * 4];
      int rowB0 = ct0 * 16 + lr, rowB1 = rowB0 + 16;
      bf16x8 b0_hi = *(const bf16x8*)&whl[rowB0 * 64 + ((cb) ^ lr) * 4];
      bf16x8 b0_lo = *(const bf16x8*)&whl[rowB0 * 64 + ((cb + 8) ^ lr) * 4];
      bf16x8 b1_hi = *(const bf16x8*)&whl[rowB1 * 64 + ((cb) ^ lr) * 4];
      bf16x8 b1_lo = *(const bf16x8*)&whl[rowB1 * 64 + ((cb + 8) ^ lr) * 4];
      acc0 = __builtin_amdgcn_mfma_f32_16x16x32_bf16(a_hi, b0_hi, acc0, 0, 0, 0);
      acc0 = __builtin_amdgcn_mfma_f32_16x16x32_bf16(a_hi, b0_lo, acc0, 0, 0, 0);
      acc0 = __builtin_amdgcn_mfma_f32_16x16x32_bf16(a_lo, b0_hi, acc0, 0, 0, 0);
      acc1 = __builtin_amdgcn_mfma_f32_16x16x32_bf16(a_hi, b1_hi, acc1, 0, 0, 0);
      acc1 = __builtin_amdgcn_mfma_f32_16x16x32_bf16(a_hi, b1_lo, acc1, 0, 0, 0);
      acc1 = __builtin_amdgcn_mfma_f32_16x16x32_bf16(a_lo, b1_hi, acc1, 0, 0, 0);
    }
  }
#pragma unroll
  for (int reg = 0; reg < 4; ++reg) {
    int n = n0 + rt * 16 + quad * 4 + reg;
    float* dst = xlin + ((size_t)(b * NB + n)) * CD + ct * 64;
    int c0 = ct0 * 16 + lr;
    dst[c0] = acc0[reg] + fc_b[ct * 64 + c0];
    dst[c0 + 16] = acc1[reg] + fc_b[ct * 64 + c0 + 16];
  }
}

// ---------------- K3 v18: barrier-lean histogram select.
// v16 analysis: fundamental work in k_distp is ~25 us; the 176 us is dominated by
// 34 full barrier-drains/block + LDS round-trips at 2 blocks/CU. Changes (selection
// math IDENTICAL -> absmax tripwire 0.0546875):
//  (1) A-fragments (eN) live in 16 VGPRs, loaded once per block straight from emb_hl
//      (global layout already matches the fragment layout); reused by both passes.
//  (2) eM double-buffered (2x16KB): 1 barrier/chunk instead of 2. Schedule per ci:
//      {barrier; MFMA+drain from buf[ci&1]; write pf regs -> buf[(ci+1)&1]; load ci+2}.
//      The barrier proves buf[ci&1] visible AND chunk ci-1 reads (buf[(ci+1)&1]) done.
//  (3) hist u16-packed (2 rows/word; counts <=512 so no cross-carry; concurrent rows
//      within a wave differ by 4 -> distinct words). LDS total 70400 B, 2 blocks/CU.
__global__ __launch_bounds__(512, 4) void k_distp(const unsigned* __restrict__ emb_hl,
                                                  const float* __restrict__ sq,
                                                  unsigned* __restrict__ thr_g,
                                                  unsigned long long* __restrict__ part) {
  __shared__ __align__(16) unsigned char smem[70400];
  unsigned* eM   = (unsigned*)smem;                     // 32768 B (2 bufs x 16KB)
  float* sqN     = (float*)(smem + 32768);              // 256 B
  float* sqMp    = (float*)(smem + 33024);              // 2048 B
  unsigned* hist = (unsigned*)(smem + 35072);           // 8192 B u16-packed [bucket][row/2]
  int* collectK  = (int*)(smem + 43264);                // 256 B
  int* cnt       = (int*)(smem + 43520);                // 256 B
  unsigned long long* cand = (unsigned long long*)(smem + 43776);  // 64 x 52 x 8 = 26624 B

  const int bid = blockIdx.x;
  const int mp = bid & 7;
  const int nt = (bid >> 3) & 63;
  const int b  = bid >> 9;
  const int n0 = nt << 6;
  const int m00 = mp << 9;   // global m base of this part
  const int tid = threadIdx.x;
  const uint4* embg = (const uint4*)emb_hl;
  const size_t bbase = (size_t)b * NB;
  const int gbase = (b << 12) + n0;

  if (tid < 64) sqN[tid] = sq[b * NB + n0 + tid];
  sqMp[tid] = sq[b * NB + m00 + tid];
#pragma unroll
  for (int i = 0; i < 4; ++i) hist[tid + 512 * i] = 0;

  const int w = tid >> 6, lane = tid & 63;
  const int quad = lane >> 4, lr = lane & 15;
  const int rt = w >> 1;            // row tile 0..3
  const int ct0 = (w & 1) * 2;      // first of my 2 col tiles (of 4)
  const int rowA = rt * 16 + lr;
  const int rA = tid >> 4, chA = tid & 15;
  const int rB = rA + 32;

  // A-fragments in registers: loaded once, reused by all 16 chunks of both passes
  bf16x8 aHi0 = *(const bf16x8*)&emb_hl[((bbase + n0 + rowA) * 16 + ((quad) ^ lr)) * 4];
  bf16x8 aLo0 = *(const bf16x8*)&emb_hl[((bbase + n0 + rowA) * 16 + ((quad + 8) ^ lr)) * 4];
  bf16x8 aHi1 = *(const bf16x8*)&emb_hl[((bbase + n0 + rowA) * 16 + ((quad + 4) ^ lr)) * 4];
  bf16x8 aLo1 = *(const bf16x8*)&emb_hl[((bbase + n0 + rowA) * 16 + ((quad + 12) ^ lr)) * 4];

  uint4* eM4 = (uint4*)eM;
  uint4 pf0, pf1;

// MFMA from buffer eMc (A from regs); same product order as v16 -> bit-identical acc
#define CHUNK_MFMA_R(eMc)                                                          \
  f32x4 acc0 = {0.f, 0.f, 0.f, 0.f};                                               \
  f32x4 acc1 = {0.f, 0.f, 0.f, 0.f};                                               \
  _Pragma("unroll")                                                                \
  for (int kk = 0; kk < 2; ++kk) {                                                 \
    const int cb = quad + 4 * kk;                                                  \
    bf16x8 a_hi = kk ? aHi1 : aHi0;                                                \
    bf16x8 a_lo = kk ? aLo1 : aLo0;                                                \
    int rowB0 = ct0 * 16 + lr, rowB1 = rowB0 + 16;                                 \
    bf16x8 b0_hi = *(const bf16x8*)&(eMc)[rowB0 * 64 + ((cb) ^ lr) * 4];           \
    bf16x8 b0_lo = *(const bf16x8*)&(eMc)[rowB0 * 64 + ((cb + 8) ^ lr) * 4];       \
    bf16x8 b1_hi = *(const bf16x8*)&(eMc)[rowB1 * 64 + ((cb) ^ lr) * 4];           \
    bf16x8 b1_lo = *(const bf16x8*)&(eMc)[rowB1 * 64 + ((cb + 8) ^ lr) * 4];       \
    acc0 = __builtin_amdgcn_mfma_f32_16x16x32_bf16(a_hi, b0_hi, acc0, 0, 0, 0);    \
    acc0 = __builtin_amdgcn_mfma_f32_16x16x32_bf16(a_hi, b0_lo, acc0, 0, 0, 0);    \
    acc0 = __builtin_amdgcn_mfma_f32_16x16x32_bf16(a_lo, b0_hi, acc0, 0, 0, 0);    \
    acc1 = __builtin_amdgcn_mfma_f32_16x16x32_bf16(a_hi, b1_hi, acc1, 0, 0, 0);    \
    acc1 = __builtin_amdgcn_mfma_f32_16x16x32_bf16(a_hi, b1_lo, acc1, 0, 0, 0);    \
    acc1 = __builtin_amdgcn_mfma_f32_16x16x32_bf16(a_lo, b1_hi, acc1, 0, 0, 0);    \
  }

// prologue: chunk0 -> buf0; chunk1 -> pf regs
#define STAGE_PROLOGUE()                                             \
  pf0 = embg[(bbase + m00 + rA) * 16 + chA];                         \
  pf1 = embg[(bbase + m00 + rB) * 16 + chA];                         \
  eM4[rA * 16 + chA] = pf0;                                          \
  eM4[rB * 16 + chA] = pf1;                                          \
  pf0 = embg[(bbase + m00 + 64 + rA) * 16 + chA];                    \
  pf1 = embg[(bbase + m00 + 64 + rB) * 16 + chA];

// after compute of chunk ci: write pf (chunk ci+1) into buf[(ci+1)&1]; load chunk ci+2
#define RESTAGE_DB(ci_)                                              \
  if ((ci_) < 7) {                                                   \
    uint4* dst = eM4 + (((ci_) + 1) & 1) * 1024;                     \
    dst[rA * 16 + chA] = pf0;                                        \
    dst[rB * 16 + chA] = pf1;                                        \
    if ((ci_) < 6) {                                                 \
      pf0 = embg[(bbase + m00 + ((ci_) + 2) * 64 + rA) * 16 + chA];  \
      pf1 = embg[(bbase + m00 + ((ci_) + 2) * 64 + rB) * 16 + chA];  \
    }                                                                \
  }

  // ================= PASS 1: histogram (only d2 <= 100 counted) =================
  STAGE_PROLOGUE()
#pragma unroll 1
  for (int ci = 0; ci < 8; ++ci) {
    const int m0 = ci << 6;
    __syncthreads();  // buf[ci&1] visible; chunk ci-1 reads of buf[(ci+1)&1] done
    const unsigned* eMc = eM + (ci & 1) * 4096;
    CHUNK_MFMA_R(eMc)
#pragma unroll
    for (int reg = 0; reg < 4; ++reg) {
      int row = rt * 16 + quad * 4 + reg;
      int c0 = ct0 * 16 + lr, c1 = c0 + 16;
      float d20 = fmaxf(sqN[row] + sqMp[m0 + c0] - 2.f * acc0[reg], 0.f);
      float d21 = fmaxf(sqN[row] + sqMp[m0 + c1] - 2.f * acc1[reg], 0.f);
      if (__float_as_uint(d20) <= 0x42C80000u) {
        int bk0 = min(63, (int)(d20 * 0.64f));
        atomicAdd(&hist[bk0 * 32 + (row >> 1)], 1u << (16 * (row & 1)));
      }
      if (__float_as_uint(d21) <= 0x42C80000u) {
        int bk1 = min(63, (int)(d21 * 0.64f));
        atomicAdd(&hist[bk1 * 32 + (row >> 1)], 1u << (16 * (row & 1)));
      }
    }
    RESTAGE_DB(ci)
  }
  __syncthreads();  // hist complete

  // ============ bound extraction + cross-part share ============
  if (tid < 64) {
    int cum = 0, kb = 63;
    const int sh = 16 * (tid & 1);
#pragma unroll 1
    for (int k2 = 0; k2 < 64; ++k2) {
      cum += (hist[k2 * 32 + (tid >> 1)] >> sh) & 0xFFFFu;
      if (cum >= 24) { kb = k2; break; }
    }
    float edge = (float)(kb + 2) * 1.5625f;
    atomicMin(&thr_g[gbase + tid], __float_as_uint(edge));
    unsigned tg = thr_g[gbase + tid];  // import (stale-larger is safe)
    int kImp = min(63, (int)(__uint_as_float(tg) * 0.64f));
    collectK[tid] = min(kb, kImp);
    cnt[tid] = 0;
  }
#pragma unroll
  for (int i = 0; i < 7; ++i) {  // cand sentinel init (64*52 = 3328)
    int q = tid + 512 * i;
    if (q < 64 * 52) cand[q] = ~0ULL;
  }
  __syncthreads();  // collectK/cnt/cand ready; pass-1 buffer reads all done

  // ================= PASS 2: collect =================
  STAGE_PROLOGUE()
#pragma unroll 1
  for (int ci = 0; ci < 8; ++ci) {
    const int m0 = ci << 6;
    __syncthreads();
    const unsigned* eMc = eM + (ci & 1) * 4096;
    CHUNK_MFMA_R(eMc)
#pragma unroll
    for (int reg = 0; reg < 4; ++reg) {
      int row = rt * 16 + quad * 4 + reg;
      int c0 = ct0 * 16 + lr, c1 = c0 + 16;
      float d20 = fmaxf(sqN[row] + sqMp[m0 + c0] - 2.f * acc0[reg], 0.f);
      float d21 = fmaxf(sqN[row] + sqMp[m0 + c1] - 2.f * acc1[reg], 0.f);
      int kc = collectK[row];
      unsigned bi0 = __float_as_uint(d20), bi1 = __float_as_uint(d21);
      int bk0 = min(63, (int)(d20 * 0.64f));
      int bk1 = min(63, (int)(d21 * 0.64f));
      if (bk0 <= kc && bi0 <= 0x42C80000u) {
        int pos = atomicAdd(&cnt[row], 1);
        if (pos < 52) cand[row * 52 + pos] = ((unsigned long long)bi0 << 32) | (unsigned)(m00 + m0 + c0);
      }
      if (bk1 <= kc && bi1 <= 0x42C80000u) {
        int pos = atomicAdd(&cnt[row], 1);
        if (pos < 52) cand[row * 52 + pos] = ((unsigned long long)bi1 << 32) | (unsigned)(m00 + m0 + c1);
      }
    }
    RESTAGE_DB(ci)
  }
  __syncthreads();  // cand complete, visible to all

  // ====== sorted top-24 extraction: 8 lanes per row, shfl_xor min-reduce ======
  {
    const int row8 = tid >> 3, sub = tid & 7;
    unsigned long long last = 0;
    unsigned long long* op = part + ((size_t)bid * 64 + row8) * 24;
#pragma unroll 1
    for (int k = 0; k < 24; ++k) {
      unsigned long long lm = ~0ULL;
#pragma unroll
      for (int j2 = 0; j2 < 7; ++j2) {
        int p2 = sub + 8 * j2;
        if (p2 < 52) {
          unsigned long long v2 = cand[row8 * 52 + p2];
          if ((k == 0 || v2 > last) && v2 < lm) lm = v2;
        }
      }
#pragma unroll
      for (int s2 = 1; s2 < 8; s2 <<= 1) {
        unsigned long long o2 = __shfl_xor(lm, s2);
        if (o2 < lm) lm = o2;
      }
      if (sub == 0) op[k] = lm;  // sentinels ok; k_merge cuts
      last = lm;
    }
  }
}

// ---------------- K3b: merge 8 sorted partials per row (256 blocks x 64 thr)
__global__ __launch_bounds__(64) void k_merge(const unsigned long long* __restrict__ part,
                                              int* __restrict__ row_idx,
                                              int* __restrict__ row_cnt,
                                              int* __restrict__ col_cnt) {
  const int row = blockIdx.x * 64 + threadIdx.x;  // b*4096 + n
  const int b = row >> 12;
  const int n = row & 4095;
  const int nt = n >> 6, r = n & 63;
  const size_t gb = (size_t)(((b << 6) | nt) << 3);  // block base (b,nt,mp=0)
  unsigned long long h[8];
  int pp[8];
#pragma unroll
  for (int t = 0; t < 8; ++t) {
    h[t] = part[((gb + t) * 64 + r) * 24];
    pp[t] = 0;
  }
  int cnt = 0;
  const int base = row * KNN;
  for (int k = 0; k < 24; ++k) {
    int bs = 0;
    unsigned long long mv = h[0];
#pragma unroll
    for (int t = 1; t < 8; ++t)
      if (h[t] < mv) { mv = h[t]; bs = t; }
    if ((unsigned)(mv >> 32) > 0x42C80000u) break;  // sentinel / beyond threshold
    int mi = (int)(mv & 0xFFFFFFFFu);
    row_idx[base + cnt] = mi;
    atomicAdd(&col_cnt[(b << 12) + mi], 1);
    ++cnt;
    int np = ++pp[bs];
    h[bs] = (np < 24) ? part[((gb + bs) * 64 + r) * 24 + np] : ~0ULL;
  }
  row_cnt[row] = cnt;
#pragma unroll 4
  for (int j = cnt; j < 24; ++j) row_idx[base + j] = n;  // pad with self (valid gather idx)
}

// ---------------- K4: exclusive scan of col_cnt (16384 entries), 1 block
__global__ __launch_bounds__(256) void k_scan(const int* __restrict__ col_cnt,
                                              int* __restrict__ col_start,
                                              int* __restrict__ col_cursor) {
  __shared__ int part[256];
  const int tid = threadIdx.x;
  const int base = tid * 64;
  int s = 0;
  for (int j = 0; j < 64; ++j) s += col_cnt[base + j];
  part[tid] = s;
  __syncthreads();
  for (int off = 1; off < 256; off <<= 1) {
    int v = (tid >= off) ? part[tid - off] : 0;
    __syncthreads();
    part[tid] += v;
    __syncthreads();
  }
  int run = part[tid] - s;
  for (int j = 0; j < 64; ++j) {
    col_start[base + j] = run;
    col_cursor[base + j] = run;
    run += col_cnt[base + j];
  }
}

// ---------------- K5: fill CSC column lists (256 blocks x 64 thr)
__global__ __launch_bounds__(64) void k_fill(const int* __restrict__ row_idx,
                                             const int* __restrict__ row_cnt,
                                             int* __restrict__ col_cursor,
                                             int* __restrict__ col_list) {
  const int row = blockIdx.x * 64 + threadIdx.x;
  const int b = row >> 12;
  const int cnt = row_cnt[row];
  for (int j = 0; j < cnt; ++j) {
    int m = row_idx[row * KNN + j];
    int pos = atomicAdd(&col_cursor[(b << 12) + m], 1);
    col_list[pos] = row & 4095;
  }
}

// ---------------- K6: Yd[e,c] = (sum_{m in col(e)} X_lin[m,c]) / De[e]
__global__ __launch_bounds__(256) void k_yd(const float* __restrict__ xlin,
                                            const int* __restrict__ col_cnt,
                                            const int* __restrict__ col_start,
                                            const int* __restrict__ col_list,
                                            float* __restrict__ yd) {
  const int le = threadIdx.x >> 6;
  const int c4 = threadIdx.x & 63;
  const int be = blockIdx.x * 4 + le;
  const int b = be >> 12;
  const int deg = col_cnt[be];
  const int start = col_start[be];
  float4 acc = make_float4(0.f, 0.f, 0.f, 0.f);
  int j = 0;
  for (; j + 3 < deg; j += 4) {
    int ma = col_list[start + j], mb2 = col_list[start + j + 1];
    int mc = col_list[start + j + 2], md = col_list[start + j + 3];
    float4 va = *(const float4*)&xlin[(((size_t)(b << 12) + ma) << 8) + c4 * 4];
    float4 vb = *(const float4*)&xlin[(((size_t)(b << 12) + mb2) << 8) + c4 * 4];
    float4 vc = *(const float4*)&xlin[(((size_t)(b << 12) + mc) << 8) + c4 * 4];
    float4 vd = *(const float4*)&xlin[(((size_t)(b << 12) + md) << 8) + c4 * 4];
    acc.x += (va.x + vb.x) + (vc.x + vd.x);
    acc.y += (va.y + vb.y) + (vc.y + vd.y);
    acc.z += (va.z + vb.z) + (vc.z + vd.z);
    acc.w += (va.w + vb.w) + (vc.w + vd.w);
  }
  for (; j < deg; ++j) {
    int m = col_list[start + j];
    float4 v = *(const float4*)&xlin[(((size_t)(b << 12) + m) << 8) + c4 * 4];
    acc.x += v.x; acc.y += v.y; acc.z += v.z; acc.w += v.w;
  }
  float inv = 1.f / (float)deg;
  acc.x *= inv; acc.y *= inv; acc.z *= inv; acc.w *= inv;
  *(float4*)&yd[((size_t)be << 8) + c4 * 4] = acc;
}

// ---------------- K7: g[n,c] = (sum_{e in row(n)} Yd[e,c]) / Dv[n]
__global__ __launch_bounds__(256) void k_out2(const float* __restrict__ yd,
                                              const int* __restrict__ row_idx,
                                              const int* __restrict__ row_cnt,
                                              float* __restrict__ outf) {
  const int b = blockIdx.x >> 8;
  const int nt = blockIdx.x & 255;
  const int le = threadIdx.x >> 6;
  const int c4 = threadIdx.x & 63;
  for (int ii = 0; ii < 4; ++ii) {
    int n = nt * 16 + le * 4 + ii;
    int row = (b << 12) + n;
    int cnt = row_cnt[row];
    int idx[24];
    const int4* ip = (const int4*)(row_idx + (size_t)row * KNN);
#pragma unroll
    for (int t = 0; t < 6; ++t) {
      int4 v = ip[t];
      idx[4 * t] = v.x; idx[4 * t + 1] = v.y; idx[4 * t + 2] = v.z; idx[4 * t + 3] = v.w;
    }
    float4 acc = make_float4(0.f, 0.f, 0.f, 0.f);
#pragma unroll
    for (int j = 0; j < 24; ++j) {
      float wgt = (j < cnt) ? 1.f : 0.f;
      float4 v = *(const float4*)&yd[(((size_t)(b << 12) + idx[j]) << 8) + c4 * 4];
      acc.x = fmaf(wgt, v.x, acc.x);
      acc.y = fmaf(wgt, v.y, acc.y);
      acc.z = fmaf(wgt, v.z, acc.z);
      acc.w = fmaf(wgt, v.w, acc.w);
    }
    float inv = 1.f / (float)cnt;
    acc.x *= inv; acc.y *= inv; acc.z *= inv; acc.w *= inv;
    *(float4*)&outf[((size_t)row << 8) + c4 * 4] = acc;
  }
}

// ---------------- K8: outf += x (residual, via LDS transpose); accumulate BN sums
__global__ __launch_bounds__(256) void k_res_bn(const float* __restrict__ x,
                                                float* __restrict__ outf,
                                                float* __restrict__ bn_sum,
                                                float* __restrict__ bn_sumsq) {
  __shared__ float xt[256 * 69];
  const int b = blockIdx.x >> 6;
  const int n0 = (blockIdx.x & 63) << 6;
  const int tid = threadIdx.x;
#pragma unroll 4
  for (int k = 0; k < 16; ++k) {
    int q = tid + 256 * k;
    int c = q >> 4, f = q & 15;
    float4 v = *(const float4*)&x[((size_t)(b * CD + c)) * NB + n0 + 4 * f];
    xt[c * 69 + 4 * f + 0] = v.x;
    xt[c * 69 + 4 * f + 1] = v.y;
    xt[c * 69 + 4 * f + 2] = v.z;
    xt[c * 69 + 4 * f + 3] = v.w;
  }
  __syncthreads();
  float s = 0.f, q = 0.f;
  const size_t rbase = ((size_t)((b << 12) + n0)) << 8;
#pragma unroll 4
  for (int i = 0; i < 64; ++i) {
    float v = outf[rbase + (size_t)i * 256 + tid] + xt[tid * 69 + i];
    outf[rbase + (size_t)i * 256 + tid] = v;
    s += v;
    q = fmaf(v, v, q);
  }
  atomicAdd(&bn_sum[tid], s);
  atomicAdd(&bn_sumsq[tid], q);
}

// ---------------- K10: BN (per-block recompute) + SiLU + transpose
__global__ __launch_bounds__(256) void k_write(const float* __restrict__ outf,
                                               const float* __restrict__ bn_sum,
                                               const float* __restrict__ bn_sumsq,
                                               const float* __restrict__ gamma,
                                               const float* __restrict__ beta,
                                               float* __restrict__ out) {
  __shared__ float tile[64 * 257];
  __shared__ float sc[256], sh[256];
  const int b = blockIdx.x >> 6;
  const int n0 = (blockIdx.x & 63) << 6;
  const int tid = threadIdx.x;
  {
    const float inv = 1.f / 16384.f;
    float mean = bn_sum[tid] * inv;
    float var = bn_sumsq[tid] * inv - mean * mean;
    float scf = gamma[tid] * rsqrtf(var + 1e-5f);
    sc[tid] = scf;
    sh[tid] = beta[tid] - mean * scf;
  }
  __syncthreads();
#pragma unroll 4
  for (int i = 0; i < 64; ++i) {
    int idx = tid + 256 * i;
    int n = idx >> 8, c = idx & 255;
    float v = outf[(((size_t)(b << 12) + n0 + n) << 8) + c];
    v = fmaf(v, sc[c], sh[c]);
    float w = v / (1.f + expf(-v));  // SiLU
    tile[n * 257 + c] = w;
  }
  __syncthreads();
  const int nl = tid & 63;
  const int cg = tid >> 6;
#pragma unroll 4
  for (int j = 0; j < 64; ++j) {
    int c = cg * 64 + j;
    out[((size_t)(b * CD + c)) * NB + n0 + nl] = tile[nl * 257 + c];
  }
}

extern "C" void kernel_launch(void* const* d_in, const int* in_sizes, int n_in,
                              void* d_out, int out_size, void* d_ws, size_t ws_size,
                              hipStream_t stream) {
  const float* x      = (const float*)d_in[0];
  const float* fc_w   = (const float*)d_in[1];
  const float* fc_b   = (const float*)d_in[2];
  const float* dist_w = (const float*)d_in[3];
  const float* gamma  = (const float*)d_in[4];
  const float* beta   = (const float*)d_in[5];
  float* out = (float*)d_out;
  char* ws = (char*)d_ws;

  const size_t OFF_EHL   = 0;                   // 4 MB
  const size_t OFF_XLIN  = (size_t)4 << 20;     // 16 MB
  const size_t OFF_YD    = (size_t)20 << 20;    // 16 MB (part buffer overlays yd+outf: both dead then)
  const size_t OFF_OUTF  = (size_t)36 << 20;    // 16 MB
  const size_t OFF_SQ    = (size_t)52 << 20;
  const size_t OFF_RIDX  = OFF_SQ + 65536;
  const size_t OFF_RCNT  = OFF_RIDX + 1572864;
  const size_t OFF_CCNT  = OFF_RCNT + 65536;
  const size_t OFF_CSTART = OFF_CCNT + 65536;
  const size_t OFF_CCUR  = OFF_CSTART + 65536;
  const size_t OFF_CLIST = OFF_CCUR + 65536;
  const size_t OFF_BNS   = OFF_CLIST + 1572864;
  const size_t OFF_BNQ   = OFF_BNS + 1024;
  const size_t OFF_THRG  = OFF_BNQ + 1024;      // 64 KB global per-row kNN threshold
  const size_t OFF_WHL   = OFF_THRG + 65536;    // 256 KB fc_w bf16 hi/lo split
  const size_t TOTAL = OFF_WHL + 262144;
  if (ws_size < TOTAL) return;

  unsigned* emb_hl = (unsigned*)(ws + OFF_EHL);
  float* xlin  = (float*)(ws + OFF_XLIN);
  float* yd    = (float*)(ws + OFF_YD);
  float* outf  = (float*)(ws + OFF_OUTF);
  unsigned long long* part = (unsigned long long*)(ws + OFF_YD);  // 25.2 MB overlay (yd+outf dead here)
  float* sq    = (float*)(ws + OFF_SQ);
  int* row_idx = (int*)(ws + OFF_RIDX);
  int* row_cnt = (int*)(ws + OFF_RCNT);
  int* col_cnt = (int*)(ws + OFF_CCNT);
  int* col_start = (int*)(ws + OFF_CSTART);
  int* col_cursor = (int*)(ws + OFF_CCUR);
  int* col_list = (int*)(ws + OFF_CLIST);
  float* bn_sum = (float*)(ws + OFF_BNS);
  float* bn_sumsq = (float*)(ws + OFF_BNQ);
  unsigned* thr_g = (unsigned*)(ws + OFF_THRG);
  unsigned* w_hl = (unsigned*)(ws + OFF_WHL);

  hipMemsetAsync(col_cnt, 0, 65536, stream);
  hipMemsetAsync(bn_sum, 0, 2048, stream);

  k_emb<<<256, 256, 0, stream>>>(x, dist_w, emb_hl, sq, thr_g);
  k_wsplit<<<32, 256, 0, stream>>>(fc_w, w_hl);
  k_xlin<<<1024, 512, 0, stream>>>(x, w_hl, fc_b, xlin);
  k_distp<<<2048, 512, 0, stream>>>(emb_hl, sq, thr_g, part);
  k_merge<<<256, 64, 0, stream>>>(part, row_idx, row_cnt, col_cnt);
  k_scan<<<1, 256, 0, stream>>>(col_cnt, col_start, col_cursor);
  k_fill<<<256, 64, 0, stream>>>(row_idx, row_cnt, col_cursor, col_list);
  k_yd<<<4096, 256, 0, stream>>>(xlin, col_cnt, col_start, col_list, yd);
  k_out2<<<1024, 256, 0, stream>>>(yd, row_idx, row_cnt, outf);
  k_res_bn<<<256, 256, 0, stream>>>(x, outf, bn_sum, bn_sumsq);
  k_write<<<256, 256, 0, stream>>>(outf, bn_sum, bn_sumsq, gamma, beta, out);
}

// Round 10
// 450.385 us; speedup vs baseline: 1.5603x; 1.0903x over previous
//
#include <hip/hip_runtime.h>

#define NB 4096      // N = H*W
#define BATCH 4
#define CD 256       // channels
#define ED 64        // embedding dim
#define KNN 24

typedef __attribute__((ext_vector_type(8))) short bf16x8;
typedef __attribute__((ext_vector_type(4))) float f32x4;

__device__ __forceinline__ unsigned short f2bf(float x) {
  unsigned u = __float_as_uint(x);
  unsigned r = (u + 0x7fffu + ((u >> 16) & 1u)) >> 16;
  return (unsigned short)r;
}

// ---------------- K1: emb = x @ dist_w^T  -> emb_hl (bf16 hi/lo, XOR-swizzled chunks) + sq (fp32)
// Also inits thr_g (per-row global kNN threshold) to bits(100.0f).
__global__ __launch_bounds__(256) void k_emb(const float* __restrict__ x,
                                             const float* __restrict__ dist_w,
                                             unsigned* __restrict__ emb_hl,
                                             float* __restrict__ sq,
                                             unsigned* __restrict__ thr_g) {
  __shared__ float wds[ED * CD];   // 64 KB
  __shared__ float red[64 * 4];
  const int b = blockIdx.x >> 6;
  const int n0 = (blockIdx.x & 63) << 6;
  const int tid = threadIdx.x;
  const float4* wsrc = (const float4*)dist_w;
  float4* wdst = (float4*)wds;
#pragma unroll
  for (int k = 0; k < 16; ++k) wdst[tid + 256 * k] = wsrc[tid + 256 * k];
  __syncthreads();
  const int eg = tid >> 6;   // 0..3
  const int nl = tid & 63;
  const int n = n0 + nl;
  float acc[16];
#pragma unroll
  for (int t = 0; t < 16; ++t) acc[t] = 0.f;
  const float* xb = x + (size_t)b * CD * NB + n;
#pragma unroll 2
  for (int c4 = 0; c4 < CD; c4 += 4) {
    float x0 = xb[(size_t)(c4 + 0) * NB];
    float x1 = xb[(size_t)(c4 + 1) * NB];
    float x2 = xb[(size_t)(c4 + 2) * NB];
    float x3 = xb[(size_t)(c4 + 3) * NB];
#pragma unroll
    for (int t = 0; t < 16; ++t) {
      float4 wv = *(const float4*)&wds[(eg * 16 + t) * CD + c4];
      acc[t] = fmaf(x0, wv.x, acc[t]);
      acc[t] = fmaf(x1, wv.y, acc[t]);
      acc[t] = fmaf(x2, wv.z, acc[t]);
      acc[t] = fmaf(x3, wv.w, acc[t]);
    }
  }
  float s = 0.f;
#pragma unroll
  for (int t = 0; t < 16; ++t) s = fmaf(acc[t], acc[t], s);
  unsigned hw[8], lw[8];
#pragma unroll
  for (int i = 0; i < 8; ++i) {
    unsigned short h0 = f2bf(acc[2 * i]);
    unsigned short h1 = f2bf(acc[2 * i + 1]);
    float l0f = acc[2 * i] - __uint_as_float((unsigned)h0 << 16);
    float l1f = acc[2 * i + 1] - __uint_as_float((unsigned)h1 << 16);
    hw[i] = (unsigned)h0 | ((unsigned)h1 << 16);
    lw[i] = (unsigned)f2bf(l0f) | ((unsigned)f2bf(l1f) << 16);
  }
  uint4* g = (uint4*)emb_hl;
  const size_t gb = ((size_t)(b * NB + n)) * 16;
  const int k15 = n & 15;
  g[gb + ((2 * eg) ^ k15)]     = make_uint4(hw[0], hw[1], hw[2], hw[3]);
  g[gb + ((2 * eg + 1) ^ k15)] = make_uint4(hw[4], hw[5], hw[6], hw[7]);
  g[gb + ((8 + 2 * eg) ^ k15)]     = make_uint4(lw[0], lw[1], lw[2], lw[3]);
  g[gb + ((8 + 2 * eg + 1) ^ k15)] = make_uint4(lw[4], lw[5], lw[6], lw[7]);
  red[nl * 4 + eg] = s;
  __syncthreads();
  if (tid < 64) {
    sq[b * NB + n0 + tid] = red[tid * 4] + red[tid * 4 + 1] + red[tid * 4 + 2] + red[tid * 4 + 3];
    thr_g[(b << 12) + n0 + tid] = 0x42C80000u;  // bits(100.0f)
  }
}

// ---------------- K2a: split fc_w into bf16 hi/lo chunks, distp-compatible layout.
__global__ __launch_bounds__(256) void k_wsplit(const float* __restrict__ fc_w,
                                                unsigned* __restrict__ w_hl) {
  const int u = blockIdx.x * 256 + threadIdx.x;  // 8192 units = 256c x 32 chunk8
  const int c = u >> 5, cg = u & 31;
  const int kt = cg >> 3, chl = cg & 7;
  const float* src = fc_w + (size_t)c * CD + kt * 64 + chl * 8;
  unsigned hi[4], lo[4];
#pragma unroll
  for (int j = 0; j < 4; ++j) {
    float a0 = src[2 * j], a1 = src[2 * j + 1];
    unsigned short h0 = f2bf(a0), h1 = f2bf(a1);
    float l0 = a0 - __uint_as_float((unsigned)h0 << 16);
    float l1 = a1 - __uint_as_float((unsigned)h1 << 16);
    hi[j] = (unsigned)h0 | ((unsigned)h1 << 16);
    lo[j] = (unsigned)f2bf(l0) | ((unsigned)f2bf(l1) << 16);
  }
  uint4* dst = (uint4*)w_hl;
  const int base = (c * 4 + kt) * 16;
  const int k15 = c & 15;
  dst[base + (chl ^ k15)] = make_uint4(hi[0], hi[1], hi[2], hi[3]);
  dst[base + ((chl + 8) ^ k15)] = make_uint4(lo[0], lo[1], lo[2], lo[3]);
}

// ---------------- K2 v19: X_lin via MFMA bf16 hi/lo; OUTPUT packed bf16 (u16/channel).
// xlin is only consumed by k_yd's gather -> bf16 storage halves that ~400 MB stream.
// Single extra rounding step (~0.4% rel); absmax is tie-dominated -> expect unchanged.
__global__ __launch_bounds__(512) void k_xlin(const float* __restrict__ x,
                                              const unsigned* __restrict__ w_hl,
                                              const float* __restrict__ fc_b,
                                              unsigned short* __restrict__ xlin_h) {
  __shared__ __align__(16) unsigned char smem[49152];
  float* xt = (float*)smem;                     // 16KB [64k][64n]
  unsigned* xhl = (unsigned*)(smem + 16384);    // 16KB [64n][64 uints]
  unsigned* whl = (unsigned*)(smem + 32768);    // 16KB [64c][64 uints]
  const int bid = blockIdx.x;
  const int ct = bid & 3;
  const int nt = (bid >> 2) & 63;
  const int b = bid >> 8;
  const int n0 = nt << 6;
  const int tid = threadIdx.x;
  const int w = tid >> 6, lane = tid & 63;
  const int quad = lane >> 4, lr = lane & 15;
  const int rt = w >> 1;            // n row-tile 0..3
  const int ct0 = (w & 1) * 2;      // first of 2 c col-tiles
  const int rowA = rt * 16 + lr;
  const int cvt_n = tid & 63, cvt_k8 = tid >> 6;
  uint4* whl4 = (uint4*)whl;
  uint4* xhl4 = (uint4*)xhl;
  const uint4* wg = (const uint4*)w_hl;
  f32x4 acc0 = {0.f, 0.f, 0.f, 0.f};
  f32x4 acc1 = {0.f, 0.f, 0.f, 0.f};

#pragma unroll 1
  for (int kt = 0; kt < 4; ++kt) {
    __syncthreads();  // B0: buffers free (prev chunk's MFMA done)
#pragma unroll
    for (int i = 0; i < 8; ++i) {
      int idx = tid + 512 * i;
      int k = idx >> 6, n = idx & 63;
      xt[k * 64 + n] = x[((size_t)(b * CD + kt * 64 + k)) * NB + n0 + n];
    }
#pragma unroll
    for (int i = 0; i < 2; ++i) {
      int idx = tid + 512 * i;
      int r = idx >> 4, ch = idx & 15;
      whl4[r * 16 + ch] = wg[(size_t)((ct * 64 + r) * 4 + kt) * 16 + ch];
    }
    __syncthreads();  // B1: xt ready
    {
      unsigned hi[4], lo[4];
#pragma unroll
      for (int j = 0; j < 4; ++j) {
        float a0 = xt[(cvt_k8 * 8 + 2 * j) * 64 + cvt_n];
        float a1 = xt[(cvt_k8 * 8 + 2 * j + 1) * 64 + cvt_n];
        unsigned short h0 = f2bf(a0), h1 = f2bf(a1);
        float l0 = a0 - __uint_as_float((unsigned)h0 << 16);
        float l1 = a1 - __uint_as_float((unsigned)h1 << 16);
        hi[j] = (unsigned)h0 | ((unsigned)h1 << 16);
        lo[j] = (unsigned)f2bf(l0) | ((unsigned)f2bf(l1) << 16);
      }
      const int k15 = cvt_n & 15;
      xhl4[cvt_n * 16 + (cvt_k8 ^ k15)] = make_uint4(hi[0], hi[1], hi[2], hi[3]);
      xhl4[cvt_n * 16 + ((cvt_k8 + 8) ^ k15)] = make_uint4(lo[0], lo[1], lo[2], lo[3]);
    }
    __syncthreads();  // B2: xhl + whl ready
#pragma unroll
    for (int kk = 0; kk < 2; ++kk) {
      const int cb = quad + 4 * kk;
      bf16x8 a_hi = *(const bf16x8*)&xhl[rowA * 64 + ((cb) ^ lr) * 4];
      bf16x8 a_lo = *(const bf16x8*)&xhl[rowA * 64 + ((cb + 8) ^ lr) * 4];
      int rowB0 = ct0 * 16 + lr, rowB1 = rowB0 + 16;
      bf16x8 b0_hi = *(const bf16x8*)&whl[rowB0 * 64 + ((cb) ^ lr) * 4];
      bf16x8 b0_lo = *(const bf16x8*)&whl[rowB0 * 64 + ((cb + 8) ^ lr) * 4];
      bf16x8 b1_hi = *(const bf16x8*)&whl[rowB1 * 64 + ((cb) ^ lr) * 4];
      bf16x8 b1_lo = *(const bf16x8*)&whl[rowB1 * 64 + ((cb + 8) ^ lr) * 4];
      acc0 = __builtin_amdgcn_mfma_f32_16x16x32_bf16(a_hi, b0_hi, acc0, 0, 0, 0);
      acc0 = __builtin_amdgcn_mfma_f32_16x16x32_bf16(a_hi, b0_lo, acc0, 0, 0, 0);
      acc0 = __builtin_amdgcn_mfma_f32_16x16x32_bf16(a_lo, b0_hi, acc0, 0, 0, 0);
      acc1 = __builtin_amdgcn_mfma_f32_16x16x32_bf16(a_hi, b1_hi, acc1, 0, 0, 0);
      acc1 = __builtin_amdgcn_mfma_f32_16x16x32_bf16(a_hi, b1_lo, acc1, 0, 0, 0);
      acc1 = __builtin_amdgcn_mfma_f32_16x16x32_bf16(a_lo, b1_hi, acc1, 0, 0, 0);
    }
  }
#pragma unroll
  for (int reg = 0; reg < 4; ++reg) {
    int n = n0 + rt * 16 + quad * 4 + reg;
    unsigned short* dst = xlin_h + (((size_t)(b * NB + n)) << 8) + ct * 64;
    int c0 = ct0 * 16 + lr;
    dst[c0] = f2bf(acc0[reg] + fc_b[ct * 64 + c0]);
    dst[c0 + 16] = f2bf(acc1[reg] + fc_b[ct * 64 + c0 + 16]);
  }
}

// ---------------- K3 v19: occupancy-focused histogram select.
// v18 lesson: removing 17 barriers bought only 6 us -> not barrier-bound. At 70.6 KB
// LDS we sit at 2 blocks/CU (~4 waves/SIMD): latency-bound hypothesis. Changes
// (selection math IDENTICAL -> absmax tripwire 0.0546875):
//  - single eM buffer (v16's proven 2-barrier schedule; costs back the ~6 us)
//  - keep v18's A-frags-in-VGPR + u16-packed hist
//  - cand cap 52->48 (certified collect <= 23+bucket-pop ~ 29; v15-v18 never tripped 52)
//  LDS = 51,968 <= 53.3 KB -> 3 blocks/CU, 6 waves/SIMD (+50% TLP).
__global__ __launch_bounds__(512, 6) void k_distp(const unsigned* __restrict__ emb_hl,
                                                  const float* __restrict__ sq,
                                                  unsigned* __restrict__ thr_g,
                                                  unsigned long long* __restrict__ part) {
  __shared__ __align__(16) unsigned char smem[51968];
  unsigned* eM   = (unsigned*)smem;                     // 16384 B
  float* sqN     = (float*)(smem + 16384);              // 256 B
  float* sqMp    = (float*)(smem + 16640);              // 2048 B
  unsigned* hist = (unsigned*)(smem + 18688);           // 8192 B u16-packed [bucket][row/2]
  int* collectK  = (int*)(smem + 26880);                // 256 B
  int* cnt       = (int*)(smem + 27136);                // 256 B
  unsigned long long* cand = (unsigned long long*)(smem + 27392);  // 64 x 48 x 8 = 24576 B

  const int bid = blockIdx.x;
  const int mp = bid & 7;
  const int nt = (bid >> 3) & 63;
  const int b  = bid >> 9;
  const int n0 = nt << 6;
  const int m00 = mp << 9;   // global m base of this part
  const int tid = threadIdx.x;
  const uint4* embg = (const uint4*)emb_hl;
  const size_t bbase = (size_t)b * NB;
  const int gbase = (b << 12) + n0;

  if (tid < 64) sqN[tid] = sq[b * NB + n0 + tid];
  sqMp[tid] = sq[b * NB + m00 + tid];
#pragma unroll
  for (int i = 0; i < 4; ++i) hist[tid + 512 * i] = 0;

  const int w = tid >> 6, lane = tid & 63;
  const int quad = lane >> 4, lr = lane & 15;
  const int rt = w >> 1;            // row tile 0..3
  const int ct0 = (w & 1) * 2;      // first of my 2 col tiles (of 4)
  const int rowA = rt * 16 + lr;
  const int rA = tid >> 4, chA = tid & 15;
  const int rB = rA + 32;

  // A-fragments in registers: loaded once, reused by all 16 chunks of both passes
  bf16x8 aHi0 = *(const bf16x8*)&emb_hl[((bbase + n0 + rowA) * 16 + ((quad) ^ lr)) * 4];
  bf16x8 aLo0 = *(const bf16x8*)&emb_hl[((bbase + n0 + rowA) * 16 + ((quad + 8) ^ lr)) * 4];
  bf16x8 aHi1 = *(const bf16x8*)&emb_hl[((bbase + n0 + rowA) * 16 + ((quad + 4) ^ lr)) * 4];
  bf16x8 aLo1 = *(const bf16x8*)&emb_hl[((bbase + n0 + rowA) * 16 + ((quad + 12) ^ lr)) * 4];

  uint4* eM4 = (uint4*)eM;
  uint4 pf0, pf1;

// MFMA from single eM buffer (A from regs); same product order -> bit-identical acc
#define CHUNK_MFMA_R()                                                             \
  f32x4 acc0 = {0.f, 0.f, 0.f, 0.f};                                               \
  f32x4 acc1 = {0.f, 0.f, 0.f, 0.f};                                               \
  _Pragma("unroll")                                                                \
  for (int kk = 0; kk < 2; ++kk) {                                                 \
    const int cb = quad + 4 * kk;                                                  \
    bf16x8 a_hi = kk ? aHi1 : aHi0;                                                \
    bf16x8 a_lo = kk ? aLo1 : aLo0;                                                \
    int rowB0 = ct0 * 16 + lr, rowB1 = rowB0 + 16;                                 \
    bf16x8 b0_hi = *(const bf16x8*)&eM[rowB0 * 64 + ((cb) ^ lr) * 4];              \
    bf16x8 b0_lo = *(const bf16x8*)&eM[rowB0 * 64 + ((cb + 8) ^ lr) * 4];          \
    bf16x8 b1_hi = *(const bf16x8*)&eM[rowB1 * 64 + ((cb) ^ lr) * 4];              \
    bf16x8 b1_lo = *(const bf16x8*)&eM[rowB1 * 64 + ((cb + 8) ^ lr) * 4];          \
    acc0 = __builtin_amdgcn_mfma_f32_16x16x32_bf16(a_hi, b0_hi, acc0, 0, 0, 0);    \
    acc0 = __builtin_amdgcn_mfma_f32_16x16x32_bf16(a_hi, b0_lo, acc0, 0, 0, 0);    \
    acc0 = __builtin_amdgcn_mfma_f32_16x16x32_bf16(a_lo, b0_hi, acc0, 0, 0, 0);    \
    acc1 = __builtin_amdgcn_mfma_f32_16x16x32_bf16(a_hi, b1_hi, acc1, 0, 0, 0);    \
    acc1 = __builtin_amdgcn_mfma_f32_16x16x32_bf16(a_hi, b1_lo, acc1, 0, 0, 0);    \
    acc1 = __builtin_amdgcn_mfma_f32_16x16x32_bf16(a_lo, b1_hi, acc1, 0, 0, 0);    \
  }

#define STAGE_FIRST()                                                \
  pf0 = embg[(bbase + m00 + rA) * 16 + chA];                         \
  pf1 = embg[(bbase + m00 + rB) * 16 + chA];                         \
  eM4[rA * 16 + chA] = pf0;                                          \
  eM4[rB * 16 + chA] = pf1;                                          \
  pf0 = embg[(bbase + m00 + 64 + rA) * 16 + chA];                    \
  pf1 = embg[(bbase + m00 + 64 + rB) * 16 + chA];

#define RESTAGE(ci_)                                                 \
  if ((ci_) < 7) {                                                   \
    eM4[rA * 16 + chA] = pf0;                                        \
    eM4[rB * 16 + chA] = pf1;                                        \
    if ((ci_) < 6) {                                                 \
      pf0 = embg[(bbase + m00 + ((ci_) + 2) * 64 + rA) * 16 + chA];  \
      pf1 = embg[(bbase + m00 + ((ci_) + 2) * 64 + rB) * 16 + chA];  \
    }                                                                \
  }

  // ================= PASS 1: histogram (only d2 <= 100 counted) =================
  STAGE_FIRST()
#pragma unroll 1
  for (int ci = 0; ci < 8; ++ci) {
    const int m0 = ci << 6;
    __syncthreads();  // B1: eM(ci) visible
    CHUNK_MFMA_R()
#pragma unroll
    for (int reg = 0; reg < 4; ++reg) {
      int row = rt * 16 + quad * 4 + reg;
      int c0 = ct0 * 16 + lr, c1 = c0 + 16;
      float d20 = fmaxf(sqN[row] + sqMp[m0 + c0] - 2.f * acc0[reg], 0.f);
      float d21 = fmaxf(sqN[row] + sqMp[m0 + c1] - 2.f * acc1[reg], 0.f);
      if (__float_as_uint(d20) <= 0x42C80000u) {
        int bk0 = min(63, (int)(d20 * 0.64f));
        atomicAdd(&hist[bk0 * 32 + (row >> 1)], 1u << (16 * (row & 1)));
      }
      if (__float_as_uint(d21) <= 0x42C80000u) {
        int bk1 = min(63, (int)(d21 * 0.64f));
        atomicAdd(&hist[bk1 * 32 + (row >> 1)], 1u << (16 * (row & 1)));
      }
    }
    __syncthreads();  // B2: eM frag reads done -> restage safe
    RESTAGE(ci)
  }
  __syncthreads();  // hist complete

  // ============ bound extraction + cross-part share ============
  if (tid < 64) {
    int cum = 0, kb = 63;
    const int sh = 16 * (tid & 1);
#pragma unroll 1
    for (int k2 = 0; k2 < 64; ++k2) {
      cum += (hist[k2 * 32 + (tid >> 1)] >> sh) & 0xFFFFu;
      if (cum >= 24) { kb = k2; break; }
    }
    float edge = (float)(kb + 2) * 1.5625f;
    atomicMin(&thr_g[gbase + tid], __float_as_uint(edge));
    unsigned tg = thr_g[gbase + tid];  // import (stale-larger is safe)
    int kImp = min(63, (int)(__uint_as_float(tg) * 0.64f));
    collectK[tid] = min(kb, kImp);
    cnt[tid] = 0;
  }
#pragma unroll
  for (int i = 0; i < 6; ++i) {  // cand sentinel init (64*48 = 3072)
    cand[tid + 512 * i] = ~0ULL;
  }
  __syncthreads();  // collectK/cnt/cand ready; pass-1 eM reads done

  // ================= PASS 2: collect =================
  STAGE_FIRST()
#pragma unroll 1
  for (int ci = 0; ci < 8; ++ci) {
    const int m0 = ci << 6;
    __syncthreads();  // B1
    CHUNK_MFMA_R()
#pragma unroll
    for (int reg = 0; reg < 4; ++reg) {
      int row = rt * 16 + quad * 4 + reg;
      int c0 = ct0 * 16 + lr, c1 = c0 + 16;
      float d20 = fmaxf(sqN[row] + sqMp[m0 + c0] - 2.f * acc0[reg], 0.f);
      float d21 = fmaxf(sqN[row] + sqMp[m0 + c1] - 2.f * acc1[reg], 0.f);
      int kc = collectK[row];
      unsigned bi0 = __float_as_uint(d20), bi1 = __float_as_uint(d21);
      int bk0 = min(63, (int)(d20 * 0.64f));
      int bk1 = min(63, (int)(d21 * 0.64f));
      if (bk0 <= kc && bi0 <= 0x42C80000u) {
        int pos = atomicAdd(&cnt[row], 1);
        if (pos < 48) cand[row * 48 + pos] = ((unsigned long long)bi0 << 32) | (unsigned)(m00 + m0 + c0);
      }
      if (bk1 <= kc && bi1 <= 0x42C80000u) {
        int pos = atomicAdd(&cnt[row], 1);
        if (pos < 48) cand[row * 48 + pos] = ((unsigned long long)bi1 << 32) | (unsigned)(m00 + m0 + c1);
      }
    }
    __syncthreads();  // B2
    RESTAGE(ci)
  }
  __syncthreads();  // cand complete, visible to all

  // ====== sorted top-24 extraction: 8 lanes per row, shfl_xor min-reduce ======
  {
    const int row8 = tid >> 3, sub = tid & 7;
    unsigned long long last = 0;
    unsigned long long* op = part + ((size_t)bid * 64 + row8) * 24;
#pragma unroll 1
    for (int k = 0; k < 24; ++k) {
      unsigned long long lm = ~0ULL;
#pragma unroll
      for (int j2 = 0; j2 < 6; ++j2) {
        int p2 = sub + 8 * j2;
        unsigned long long v2 = cand[row8 * 48 + p2];
        if ((k == 0 || v2 > last) && v2 < lm) lm = v2;
      }
#pragma unroll
      for (int s2 = 1; s2 < 8; s2 <<= 1) {
        unsigned long long o2 = __shfl_xor(lm, s2);
        if (o2 < lm) lm = o2;
      }
      if (sub == 0) op[k] = lm;  // sentinels ok; k_merge cuts
      last = lm;
    }
  }
}

// ---------------- K3b: merge 8 sorted partials per row (256 blocks x 64 thr)
__global__ __launch_bounds__(64) void k_merge(const unsigned long long* __restrict__ part,
                                              int* __restrict__ row_idx,
                                              int* __restrict__ row_cnt,
                                              int* __restrict__ col_cnt) {
  const int row = blockIdx.x * 64 + threadIdx.x;  // b*4096 + n
  const int b = row >> 12;
  const int n = row & 4095;
  const int nt = n >> 6, r = n & 63;
  const size_t gb = (size_t)(((b << 6) | nt) << 3);  // block base (b,nt,mp=0)
  unsigned long long h[8];
  int pp[8];
#pragma unroll
  for (int t = 0; t < 8; ++t) {
    h[t] = part[((gb + t) * 64 + r) * 24];
    pp[t] = 0;
  }
  int cnt = 0;
  const int base = row * KNN;
  for (int k = 0; k < 24; ++k) {
    int bs = 0;
    unsigned long long mv = h[0];
#pragma unroll
    for (int t = 1; t < 8; ++t)
      if (h[t] < mv) { mv = h[t]; bs = t; }
    if ((unsigned)(mv >> 32) > 0x42C80000u) break;  // sentinel / beyond threshold
    int mi = (int)(mv & 0xFFFFFFFFu);
    row_idx[base + cnt] = mi;
    atomicAdd(&col_cnt[(b << 12) + mi], 1);
    ++cnt;
    int np = ++pp[bs];
    h[bs] = (np < 24) ? part[((gb + bs) * 64 + r) * 24 + np] : ~0ULL;
  }
  row_cnt[row] = cnt;
#pragma unroll 4
  for (int j = cnt; j < 24; ++j) row_idx[base + j] = n;  // pad with self (valid gather idx)
}

// ---------------- K4: exclusive scan of col_cnt (16384 entries), 1 block
__global__ __launch_bounds__(256) void k_scan(const int* __restrict__ col_cnt,
                                              int* __restrict__ col_start,
                                              int* __restrict__ col_cursor) {
  __shared__ int part[256];
  const int tid = threadIdx.x;
  const int base = tid * 64;
  int s = 0;
  for (int j = 0; j < 64; ++j) s += col_cnt[base + j];
  part[tid] = s;
  __syncthreads();
  for (int off = 1; off < 256; off <<= 1) {
    int v = (tid >= off) ? part[tid - off] : 0;
    __syncthreads();
    part[tid] += v;
    __syncthreads();
  }
  int run = part[tid] - s;
  for (int j = 0; j < 64; ++j) {
    col_start[base + j] = run;
    col_cursor[base + j] = run;
    run += col_cnt[base + j];
  }
}

// ---------------- K5: fill CSC column lists (256 blocks x 64 thr)
__global__ __launch_bounds__(64) void k_fill(const int* __restrict__ row_idx,
                                             const int* __restrict__ row_cnt,
                                             int* __restrict__ col_cursor,
                                             int* __restrict__ col_list) {
  const int row = blockIdx.x * 64 + threadIdx.x;
  const int b = row >> 12;
  const int cnt = row_cnt[row];
  for (int j = 0; j < cnt; ++j) {
    int m = row_idx[row * KNN + j];
    int pos = atomicAdd(&col_cursor[(b << 12) + m], 1);
    col_list[pos] = row & 4095;
  }
}

// ---------------- K6 v19: Yd[e,c] from bf16 xlin (half the gather bytes), fp32 accum/out
__global__ __launch_bounds__(256) void k_yd(const unsigned short* __restrict__ xlin_h,
                                            const int* __restrict__ col_cnt,
                                            const int* __restrict__ col_start,
                                            const int* __restrict__ col_list,
                                            float* __restrict__ yd) {
  const int le = threadIdx.x >> 6;
  const int c4 = threadIdx.x & 63;
  const int be = blockIdx.x * 4 + le;
  const int b = be >> 12;
  const int deg = col_cnt[be];
  const int start = col_start[be];
  float4 acc = make_float4(0.f, 0.f, 0.f, 0.f);
#define BF2F_LO(u) __uint_as_float(((u) & 0xFFFFu) << 16)
#define BF2F_HI(u) __uint_as_float((u) & 0xFFFF0000u)
  int j = 0;
  for (; j + 3 < deg; j += 4) {
    int ma = col_list[start + j], mb2 = col_list[start + j + 1];
    int mc = col_list[start + j + 2], md = col_list[start + j + 3];
    uint2 va = *(const uint2*)&xlin_h[(((size_t)(b << 12) + ma) << 8) + c4 * 4];
    uint2 vb = *(const uint2*)&xlin_h[(((size_t)(b << 12) + mb2) << 8) + c4 * 4];
    uint2 vc = *(const uint2*)&xlin_h[(((size_t)(b << 12) + mc) << 8) + c4 * 4];
    uint2 vd = *(const uint2*)&xlin_h[(((size_t)(b << 12) + md) << 8) + c4 * 4];
    acc.x += (BF2F_LO(va.x) + BF2F_LO(vb.x)) + (BF2F_LO(vc.x) + BF2F_LO(vd.x));
    acc.y += (BF2F_HI(va.x) + BF2F_HI(vb.x)) + (BF2F_HI(vc.x) + BF2F_HI(vd.x));
    acc.z += (BF2F_LO(va.y) + BF2F_LO(vb.y)) + (BF2F_LO(vc.y) + BF2F_LO(vd.y));
    acc.w += (BF2F_HI(va.y) + BF2F_HI(vb.y)) + (BF2F_HI(vc.y) + BF2F_HI(vd.y));
  }
  for (; j < deg; ++j) {
    int m = col_list[start + j];
    uint2 v = *(const uint2*)&xlin_h[(((size_t)(b << 12) + m) << 8) + c4 * 4];
    acc.x += BF2F_LO(v.x); acc.y += BF2F_HI(v.x);
    acc.z += BF2F_LO(v.y); acc.w += BF2F_HI(v.y);
  }
  float inv = 1.f / (float)deg;
  acc.x *= inv; acc.y *= inv; acc.z *= inv; acc.w *= inv;
  *(float4*)&yd[((size_t)be << 8) + c4 * 4] = acc;
}

// ---------------- K7: g[n,c] = (sum_{e in row(n)} Yd[e,c]) / Dv[n]
__global__ __launch_bounds__(256) void k_out2(const float* __restrict__ yd,
                                              const int* __restrict__ row_idx,
                                              const int* __restrict__ row_cnt,
                                              float* __restrict__ outf) {
  const int b = blockIdx.x >> 8;
  const int nt = blockIdx.x & 255;
  const int le = threadIdx.x >> 6;
  const int c4 = threadIdx.x & 63;
  for (int ii = 0; ii < 4; ++ii) {
    int n = nt * 16 + le * 4 + ii;
    int row = (b << 12) + n;
    int cnt = row_cnt[row];
    int idx[24];
    const int4* ip = (const int4*)(row_idx + (size_t)row * KNN);
#pragma unroll
    for (int t = 0; t < 6; ++t) {
      int4 v = ip[t];
      idx[4 * t] = v.x; idx[4 * t + 1] = v.y; idx[4 * t + 2] = v.z; idx[4 * t + 3] = v.w;
    }
    float4 acc = make_float4(0.f, 0.f, 0.f, 0.f);
#pragma unroll
    for (int j = 0; j < 24; ++j) {
      float wgt = (j < cnt) ? 1.f : 0.f;
      float4 v = *(const float4*)&yd[(((size_t)(b << 12) + idx[j]) << 8) + c4 * 4];
      acc.x = fmaf(wgt, v.x, acc.x);
      acc.y = fmaf(wgt, v.y, acc.y);
      acc.z = fmaf(wgt, v.z, acc.z);
      acc.w = fmaf(wgt, v.w, acc.w);
    }
    float inv = 1.f / (float)cnt;
    acc.x *= inv; acc.y *= inv; acc.z *= inv; acc.w *= inv;
    *(float4*)&outf[((size_t)row << 8) + c4 * 4] = acc;
  }
}

// ---------------- K8: outf += x (residual, via LDS transpose); accumulate BN sums
__global__ __launch_bounds__(256) void k_res_bn(const float* __restrict__ x,
                                                float* __restrict__ outf,
                                                float* __restrict__ bn_sum,
                                                float* __restrict__ bn_sumsq) {
  __shared__ float xt[256 * 69];
  const int b = blockIdx.x >> 6;
  const int n0 = (blockIdx.x & 63) << 6;
  const int tid = threadIdx.x;
#pragma unroll 4
  for (int k = 0; k < 16; ++k) {
    int q = tid + 256 * k;
    int c = q >> 4, f = q & 15;
    float4 v = *(const float4*)&x[((size_t)(b * CD + c)) * NB + n0 + 4 * f];
    xt[c * 69 + 4 * f + 0] = v.x;
    xt[c * 69 + 4 * f + 1] = v.y;
    xt[c * 69 + 4 * f + 2] = v.z;
    xt[c * 69 + 4 * f + 3] = v.w;
  }
  __syncthreads();
  float s = 0.f, q = 0.f;
  const size_t rbase = ((size_t)((b << 12) + n0)) << 8;
#pragma unroll 4
  for (int i = 0; i < 64; ++i) {
    float v = outf[rbase + (size_t)i * 256 + tid] + xt[tid * 69 + i];
    outf[rbase + (size_t)i * 256 + tid] = v;
    s += v;
    q = fmaf(v, v, q);
  }
  atomicAdd(&bn_sum[tid], s);
  atomicAdd(&bn_sumsq[tid], q);
}

// ---------------- K10: BN (per-block recompute) + SiLU + transpose
__global__ __launch_bounds__(256) void k_write(const float* __restrict__ outf,
                                               const float* __restrict__ bn_sum,
                                               const float* __restrict__ bn_sumsq,
                                               const float* __restrict__ gamma,
                                               const float* __restrict__ beta,
                                               float* __restrict__ out) {
  __shared__ float tile[64 * 257];
  __shared__ float sc[256], sh[256];
  const int b = blockIdx.x >> 6;
  const int n0 = (blockIdx.x & 63) << 6;
  const int tid = threadIdx.x;
  {
    const float inv = 1.f / 16384.f;
    float mean = bn_sum[tid] * inv;
    float var = bn_sumsq[tid] * inv - mean * mean;
    float scf = gamma[tid] * rsqrtf(var + 1e-5f);
    sc[tid] = scf;
    sh[tid] = beta[tid] - mean * scf;
  }
  __syncthreads();
#pragma unroll 4
  for (int i = 0; i < 64; ++i) {
    int idx = tid + 256 * i;
    int n = idx >> 8, c = idx & 255;
    float v = outf[(((size_t)(b << 12) + n0 + n) << 8) + c];
    v = fmaf(v, sc[c], sh[c]);
    float w = v / (1.f + expf(-v));  // SiLU
    tile[n * 257 + c] = w;
  }
  __syncthreads();
  const int nl = tid & 63;
  const int cg = tid >> 6;
#pragma unroll 4
  for (int j = 0; j < 64; ++j) {
    int c = cg * 64 + j;
    out[((size_t)(b * CD + c)) * NB + n0 + nl] = tile[nl * 257 + c];
  }
}

extern "C" void kernel_launch(void* const* d_in, const int* in_sizes, int n_in,
                              void* d_out, int out_size, void* d_ws, size_t ws_size,
                              hipStream_t stream) {
  const float* x      = (const float*)d_in[0];
  const float* fc_w   = (const float*)d_in[1];
  const float* fc_b   = (const float*)d_in[2];
  const float* dist_w = (const float*)d_in[3];
  const float* gamma  = (const float*)d_in[4];
  const float* beta   = (const float*)d_in[5];
  float* out = (float*)d_out;
  char* ws = (char*)d_ws;

  const size_t OFF_EHL   = 0;                   // 4 MB
  const size_t OFF_XLIN  = (size_t)4 << 20;     // 8 MB used (bf16); slot kept 16 MB
  const size_t OFF_YD    = (size_t)20 << 20;    // 16 MB (part buffer overlays yd+outf: both dead then)
  const size_t OFF_OUTF  = (size_t)36 << 20;    // 16 MB
  const size_t OFF_SQ    = (size_t)52 << 20;
  const size_t OFF_RIDX  = OFF_SQ + 65536;
  const size_t OFF_RCNT  = OFF_RIDX + 1572864;
  const size_t OFF_CCNT  = OFF_RCNT + 65536;
  const size_t OFF_CSTART = OFF_CCNT + 65536;
  const size_t OFF_CCUR  = OFF_CSTART + 65536;
  const size_t OFF_CLIST = OFF_CCUR + 65536;
  const size_t OFF_BNS   = OFF_CLIST + 1572864;
  const size_t OFF_BNQ   = OFF_BNS + 1024;
  const size_t OFF_THRG  = OFF_BNQ + 1024;      // 64 KB global per-row kNN threshold
  const size_t OFF_WHL   = OFF_THRG + 65536;    // 256 KB fc_w bf16 hi/lo split
  const size_t TOTAL = OFF_WHL + 262144;
  if (ws_size < TOTAL) return;

  unsigned* emb_hl = (unsigned*)(ws + OFF_EHL);
  unsigned short* xlin_h = (unsigned short*)(ws + OFF_XLIN);
  float* yd    = (float*)(ws + OFF_YD);
  float* outf  = (float*)(ws + OFF_OUTF);
  unsigned long long* part = (unsigned long long*)(ws + OFF_YD);  // 25.2 MB overlay (yd+outf dead here)
  float* sq    = (float*)(ws + OFF_SQ);
  int* row_idx = (int*)(ws + OFF_RIDX);
  int* row_cnt = (int*)(ws + OFF_RCNT);
  int* col_cnt = (int*)(ws + OFF_CCNT);
  int* col_start = (int*)(ws + OFF_CSTART);
  int* col_cursor = (int*)(ws + OFF_CCUR);
  int* col_list = (int*)(ws + OFF_CLIST);
  float* bn_sum = (float*)(ws + OFF_BNS);
  float* bn_sumsq = (float*)(ws + OFF_BNQ);
  unsigned* thr_g = (unsigned*)(ws + OFF_THRG);
  unsigned* w_hl = (unsigned*)(ws + OFF_WHL);

  hipMemsetAsync(col_cnt, 0, 65536, stream);
  hipMemsetAsync(bn_sum, 0, 2048, stream);

  k_emb<<<256, 256, 0, stream>>>(x, dist_w, emb_hl, sq, thr_g);
  k_wsplit<<<32, 256, 0, stream>>>(fc_w, w_hl);
  k_xlin<<<1024, 512, 0, stream>>>(x, w_hl, fc_b, xlin_h);
  k_distp<<<2048, 512, 0, stream>>>(emb_hl, sq, thr_g, part);
  k_merge<<<256, 64, 0, stream>>>(part, row_idx, row_cnt, col_cnt);
  k_scan<<<1, 256, 0, stream>>>(col_cnt, col_start, col_cursor);
  k_fill<<<256, 64, 0, stream>>>(row_idx, row_cnt, col_cursor, col_list);
  k_yd<<<4096, 256, 0, stream>>>(xlin_h, col_cnt, col_start, col_list, yd);
  k_out2<<<1024, 256, 0, stream>>>(yd, row_idx, row_cnt, outf);
  k_res_bn<<<256, 256, 0, stream>>>(x, outf, bn_sum, bn_sumsq);
  k_write<<<256, 256, 0, stream>>>(outf, bn_sum, bn_sumsq, gamma, beta, out);
}

// Round 11
// 448.147 us; speedup vs baseline: 1.5680x; 1.0050x over previous
//
#include <hip/hip_runtime.h>

#define NB 4096      // N = H*W
#define BATCH 4
#define CD 256       // channels
#define ED 64        // embedding dim
#define KNN 24

typedef __attribute__((ext_vector_type(8))) short bf16x8;
typedef __attribute__((ext_vector_type(4))) float f32x4;

__device__ __forceinline__ unsigned short f2bf(float x) {
  unsigned u = __float_as_uint(x);
  unsigned r = (u + 0x7fffu + ((u >> 16) & 1u)) >> 16;
  return (unsigned short)r;
}

// ---------------- K1: emb = x @ dist_w^T  -> emb_hl (bf16 hi/lo, XOR-swizzled chunks) + sq (fp32)
// Also inits thr_g (per-row global kNN threshold) to bits(100.0f).
__global__ __launch_bounds__(256) void k_emb(const float* __restrict__ x,
                                             const float* __restrict__ dist_w,
                                             unsigned* __restrict__ emb_hl,
                                             float* __restrict__ sq,
                                             unsigned* __restrict__ thr_g) {
  __shared__ float wds[ED * CD];   // 64 KB
  __shared__ float red[64 * 4];
  const int b = blockIdx.x >> 6;
  const int n0 = (blockIdx.x & 63) << 6;
  const int tid = threadIdx.x;
  const float4* wsrc = (const float4*)dist_w;
  float4* wdst = (float4*)wds;
#pragma unroll
  for (int k = 0; k < 16; ++k) wdst[tid + 256 * k] = wsrc[tid + 256 * k];
  __syncthreads();
  const int eg = tid >> 6;   // 0..3
  const int nl = tid & 63;
  const int n = n0 + nl;
  float acc[16];
#pragma unroll
  for (int t = 0; t < 16; ++t) acc[t] = 0.f;
  const float* xb = x + (size_t)b * CD * NB + n;
#pragma unroll 2
  for (int c4 = 0; c4 < CD; c4 += 4) {
    float x0 = xb[(size_t)(c4 + 0) * NB];
    float x1 = xb[(size_t)(c4 + 1) * NB];
    float x2 = xb[(size_t)(c4 + 2) * NB];
    float x3 = xb[(size_t)(c4 + 3) * NB];
#pragma unroll
    for (int t = 0; t < 16; ++t) {
      float4 wv = *(const float4*)&wds[(eg * 16 + t) * CD + c4];
      acc[t] = fmaf(x0, wv.x, acc[t]);
      acc[t] = fmaf(x1, wv.y, acc[t]);
      acc[t] = fmaf(x2, wv.z, acc[t]);
      acc[t] = fmaf(x3, wv.w, acc[t]);
    }
  }
  float s = 0.f;
#pragma unroll
  for (int t = 0; t < 16; ++t) s = fmaf(acc[t], acc[t], s);
  unsigned hw[8], lw[8];
#pragma unroll
  for (int i = 0; i < 8; ++i) {
    unsigned short h0 = f2bf(acc[2 * i]);
    unsigned short h1 = f2bf(acc[2 * i + 1]);
    float l0f = acc[2 * i] - __uint_as_float((unsigned)h0 << 16);
    float l1f = acc[2 * i + 1] - __uint_as_float((unsigned)h1 << 16);
    hw[i] = (unsigned)h0 | ((unsigned)h1 << 16);
    lw[i] = (unsigned)f2bf(l0f) | ((unsigned)f2bf(l1f) << 16);
  }
  uint4* g = (uint4*)emb_hl;
  const size_t gb = ((size_t)(b * NB + n)) * 16;
  const int k15 = n & 15;
  g[gb + ((2 * eg) ^ k15)]     = make_uint4(hw[0], hw[1], hw[2], hw[3]);
  g[gb + ((2 * eg + 1) ^ k15)] = make_uint4(hw[4], hw[5], hw[6], hw[7]);
  g[gb + ((8 + 2 * eg) ^ k15)]     = make_uint4(lw[0], lw[1], lw[2], lw[3]);
  g[gb + ((8 + 2 * eg + 1) ^ k15)] = make_uint4(lw[4], lw[5], lw[6], lw[7]);
  red[nl * 4 + eg] = s;
  __syncthreads();
  if (tid < 64) {
    sq[b * NB + n0 + tid] = red[tid * 4] + red[tid * 4 + 1] + red[tid * 4 + 2] + red[tid * 4 + 3];
    thr_g[(b << 12) + n0 + tid] = 0x42C80000u;  // bits(100.0f)
  }
}

// ---------------- K2a: split fc_w into bf16 hi/lo chunks, distp-compatible layout.
__global__ __launch_bounds__(256) void k_wsplit(const float* __restrict__ fc_w,
                                                unsigned* __restrict__ w_hl) {
  const int u = blockIdx.x * 256 + threadIdx.x;  // 8192 units = 256c x 32 chunk8
  const int c = u >> 5, cg = u & 31;
  const int kt = cg >> 3, chl = cg & 7;
  const float* src = fc_w + (size_t)c * CD + kt * 64 + chl * 8;
  unsigned hi[4], lo[4];
#pragma unroll
  for (int j = 0; j < 4; ++j) {
    float a0 = src[2 * j], a1 = src[2 * j + 1];
    unsigned short h0 = f2bf(a0), h1 = f2bf(a1);
    float l0 = a0 - __uint_as_float((unsigned)h0 << 16);
    float l1 = a1 - __uint_as_float((unsigned)h1 << 16);
    hi[j] = (unsigned)h0 | ((unsigned)h1 << 16);
    lo[j] = (unsigned)f2bf(l0) | ((unsigned)f2bf(l1) << 16);
  }
  uint4* dst = (uint4*)w_hl;
  const int base = (c * 4 + kt) * 16;
  const int k15 = c & 15;
  dst[base + (chl ^ k15)] = make_uint4(hi[0], hi[1], hi[2], hi[3]);
  dst[base + ((chl + 8) ^ k15)] = make_uint4(lo[0], lo[1], lo[2], lo[3]);
}

// ---------------- K2: X_lin via MFMA bf16 hi/lo; output packed bf16 (unchanged from v19)
__global__ __launch_bounds__(512) void k_xlin(const float* __restrict__ x,
                                              const unsigned* __restrict__ w_hl,
                                              const float* __restrict__ fc_b,
                                              unsigned short* __restrict__ xlin_h) {
  __shared__ __align__(16) unsigned char smem[49152];
  float* xt = (float*)smem;                     // 16KB [64k][64n]
  unsigned* xhl = (unsigned*)(smem + 16384);    // 16KB [64n][64 uints]
  unsigned* whl = (unsigned*)(smem + 32768);    // 16KB [64c][64 uints]
  const int bid = blockIdx.x;
  const int ct = bid & 3;
  const int nt = (bid >> 2) & 63;
  const int b = bid >> 8;
  const int n0 = nt << 6;
  const int tid = threadIdx.x;
  const int w = tid >> 6, lane = tid & 63;
  const int quad = lane >> 4, lr = lane & 15;
  const int rt = w >> 1;            // n row-tile 0..3
  const int ct0 = (w & 1) * 2;      // first of 2 c col-tiles
  const int rowA = rt * 16 + lr;
  const int cvt_n = tid & 63, cvt_k8 = tid >> 6;
  uint4* whl4 = (uint4*)whl;
  uint4* xhl4 = (uint4*)xhl;
  const uint4* wg = (const uint4*)w_hl;
  f32x4 acc0 = {0.f, 0.f, 0.f, 0.f};
  f32x4 acc1 = {0.f, 0.f, 0.f, 0.f};

#pragma unroll 1
  for (int kt = 0; kt < 4; ++kt) {
    __syncthreads();  // B0: buffers free (prev chunk's MFMA done)
#pragma unroll
    for (int i = 0; i < 8; ++i) {
      int idx = tid + 512 * i;
      int k = idx >> 6, n = idx & 63;
      xt[k * 64 + n] = x[((size_t)(b * CD + kt * 64 + k)) * NB + n0 + n];
    }
#pragma unroll
    for (int i = 0; i < 2; ++i) {
      int idx = tid + 512 * i;
      int r = idx >> 4, ch = idx & 15;
      whl4[r * 16 + ch] = wg[(size_t)((ct * 64 + r) * 4 + kt) * 16 + ch];
    }
    __syncthreads();  // B1: xt ready
    {
      unsigned hi[4], lo[4];
#pragma unroll
      for (int j = 0; j < 4; ++j) {
        float a0 = xt[(cvt_k8 * 8 + 2 * j) * 64 + cvt_n];
        float a1 = xt[(cvt_k8 * 8 + 2 * j + 1) * 64 + cvt_n];
        unsigned short h0 = f2bf(a0), h1 = f2bf(a1);
        float l0 = a0 - __uint_as_float((unsigned)h0 << 16);
        float l1 = a1 - __uint_as_float((unsigned)h1 << 16);
        hi[j] = (unsigned)h0 | ((unsigned)h1 << 16);
        lo[j] = (unsigned)f2bf(l0) | ((unsigned)f2bf(l1) << 16);
      }
      const int k15 = cvt_n & 15;
      xhl4[cvt_n * 16 + (cvt_k8 ^ k15)] = make_uint4(hi[0], hi[1], hi[2], hi[3]);
      xhl4[cvt_n * 16 + ((cvt_k8 + 8) ^ k15)] = make_uint4(lo[0], lo[1], lo[2], lo[3]);
    }
    __syncthreads();  // B2: xhl + whl ready
#pragma unroll
    for (int kk = 0; kk < 2; ++kk) {
      const int cb = quad + 4 * kk;
      bf16x8 a_hi = *(const bf16x8*)&xhl[rowA * 64 + ((cb) ^ lr) * 4];
      bf16x8 a_lo = *(const bf16x8*)&xhl[rowA * 64 + ((cb + 8) ^ lr) * 4];
      int rowB0 = ct0 * 16 + lr, rowB1 = rowB0 + 16;
      bf16x8 b0_hi = *(const bf16x8*)&whl[rowB0 * 64 + ((cb) ^ lr) * 4];
      bf16x8 b0_lo = *(const bf16x8*)&whl[rowB0 * 64 + ((cb + 8) ^ lr) * 4];
      bf16x8 b1_hi = *(const bf16x8*)&whl[rowB1 * 64 + ((cb) ^ lr) * 4];
      bf16x8 b1_lo = *(const bf16x8*)&whl[rowB1 * 64 + ((cb + 8) ^ lr) * 4];
      acc0 = __builtin_amdgcn_mfma_f32_16x16x32_bf16(a_hi, b0_hi, acc0, 0, 0, 0);
      acc0 = __builtin_amdgcn_mfma_f32_16x16x32_bf16(a_hi, b0_lo, acc0, 0, 0, 0);
      acc0 = __builtin_amdgcn_mfma_f32_16x16x32_bf16(a_lo, b0_hi, acc0, 0, 0, 0);
      acc1 = __builtin_amdgcn_mfma_f32_16x16x32_bf16(a_hi, b1_hi, acc1, 0, 0, 0);
      acc1 = __builtin_amdgcn_mfma_f32_16x16x32_bf16(a_hi, b1_lo, acc1, 0, 0, 0);
      acc1 = __builtin_amdgcn_mfma_f32_16x16x32_bf16(a_lo, b1_hi, acc1, 0, 0, 0);
    }
  }
#pragma unroll
  for (int reg = 0; reg < 4; ++reg) {
    int n = n0 + rt * 16 + quad * 4 + reg;
    unsigned short* dst = xlin_h + (((size_t)(b * NB + n)) << 8) + ct * 64;
    int c0 = ct0 * 16 + lr;
    dst[c0] = f2bf(acc0[reg] + fc_b[ct * 64 + c0]);
    dst[c0 + 16] = f2bf(acc1[reg] + fc_b[ct * 64 + c0 + 16]);
  }
}

// ---------------- K3 v19 (unchanged): occupancy-focused histogram select.
__global__ __launch_bounds__(512, 6) void k_distp(const unsigned* __restrict__ emb_hl,
                                                  const float* __restrict__ sq,
                                                  unsigned* __restrict__ thr_g,
                                                  unsigned long long* __restrict__ part) {
  __shared__ __align__(16) unsigned char smem[51968];
  unsigned* eM   = (unsigned*)smem;                     // 16384 B
  float* sqN     = (float*)(smem + 16384);              // 256 B
  float* sqMp    = (float*)(smem + 16640);              // 2048 B
  unsigned* hist = (unsigned*)(smem + 18688);           // 8192 B u16-packed [bucket][row/2]
  int* collectK  = (int*)(smem + 26880);                // 256 B
  int* cnt       = (int*)(smem + 27136);                // 256 B
  unsigned long long* cand = (unsigned long long*)(smem + 27392);  // 64 x 48 x 8 = 24576 B

  const int bid = blockIdx.x;
  const int mp = bid & 7;
  const int nt = (bid >> 3) & 63;
  const int b  = bid >> 9;
  const int n0 = nt << 6;
  const int m00 = mp << 9;   // global m base of this part
  const int tid = threadIdx.x;
  const uint4* embg = (const uint4*)emb_hl;
  const size_t bbase = (size_t)b * NB;
  const int gbase = (b << 12) + n0;

  if (tid < 64) sqN[tid] = sq[b * NB + n0 + tid];
  sqMp[tid] = sq[b * NB + m00 + tid];
#pragma unroll
  for (int i = 0; i < 4; ++i) hist[tid + 512 * i] = 0;

  const int w = tid >> 6, lane = tid & 63;
  const int quad = lane >> 4, lr = lane & 15;
  const int rt = w >> 1;            // row tile 0..3
  const int ct0 = (w & 1) * 2;      // first of my 2 col tiles (of 4)
  const int rowA = rt * 16 + lr;
  const int rA = tid >> 4, chA = tid & 15;
  const int rB = rA + 32;

  // A-fragments in registers: loaded once, reused by all 16 chunks of both passes
  bf16x8 aHi0 = *(const bf16x8*)&emb_hl[((bbase + n0 + rowA) * 16 + ((quad) ^ lr)) * 4];
  bf16x8 aLo0 = *(const bf16x8*)&emb_hl[((bbase + n0 + rowA) * 16 + ((quad + 8) ^ lr)) * 4];
  bf16x8 aHi1 = *(const bf16x8*)&emb_hl[((bbase + n0 + rowA) * 16 + ((quad + 4) ^ lr)) * 4];
  bf16x8 aLo1 = *(const bf16x8*)&emb_hl[((bbase + n0 + rowA) * 16 + ((quad + 12) ^ lr)) * 4];

  uint4* eM4 = (uint4*)eM;
  uint4 pf0, pf1;

#define CHUNK_MFMA_R()                                                             \
  f32x4 acc0 = {0.f, 0.f, 0.f, 0.f};                                               \
  f32x4 acc1 = {0.f, 0.f, 0.f, 0.f};                                               \
  _Pragma("unroll")                                                                \
  for (int kk = 0; kk < 2; ++kk) {                                                 \
    const int cb = quad + 4 * kk;                                                  \
    bf16x8 a_hi = kk ? aHi1 : aHi0;                                                \
    bf16x8 a_lo = kk ? aLo1 : aLo0;                                                \
    int rowB0 = ct0 * 16 + lr, rowB1 = rowB0 + 16;                                 \
    bf16x8 b0_hi = *(const bf16x8*)&eM[rowB0 * 64 + ((cb) ^ lr) * 4];              \
    bf16x8 b0_lo = *(const bf16x8*)&eM[rowB0 * 64 + ((cb + 8) ^ lr) * 4];          \
    bf16x8 b1_hi = *(const bf16x8*)&eM[rowB1 * 64 + ((cb) ^ lr) * 4];              \
    bf16x8 b1_lo = *(const bf16x8*)&eM[rowB1 * 64 + ((cb + 8) ^ lr) * 4];          \
    acc0 = __builtin_amdgcn_mfma_f32_16x16x32_bf16(a_hi, b0_hi, acc0, 0, 0, 0);    \
    acc0 = __builtin_amdgcn_mfma_f32_16x16x32_bf16(a_hi, b0_lo, acc0, 0, 0, 0);    \
    acc0 = __builtin_amdgcn_mfma_f32_16x16x32_bf16(a_lo, b0_hi, acc0, 0, 0, 0);    \
    acc1 = __builtin_amdgcn_mfma_f32_16x16x32_bf16(a_hi, b1_hi, acc1, 0, 0, 0);    \
    acc1 = __builtin_amdgcn_mfma_f32_16x16x32_bf16(a_hi, b1_lo, acc1, 0, 0, 0);    \
    acc1 = __builtin_amdgcn_mfma_f32_16x16x32_bf16(a_lo, b1_hi, acc1, 0, 0, 0);    \
  }

#define STAGE_FIRST()                                                \
  pf0 = embg[(bbase + m00 + rA) * 16 + chA];                         \
  pf1 = embg[(bbase + m00 + rB) * 16 + chA];                         \
  eM4[rA * 16 + chA] = pf0;                                          \
  eM4[rB * 16 + chA] = pf1;                                          \
  pf0 = embg[(bbase + m00 + 64 + rA) * 16 + chA];                    \
  pf1 = embg[(bbase + m00 + 64 + rB) * 16 + chA];

#define RESTAGE(ci_)                                                 \
  if ((ci_) < 7) {                                                   \
    eM4[rA * 16 + chA] = pf0;                                        \
    eM4[rB * 16 + chA] = pf1;                                        \
    if ((ci_) < 6) {                                                 \
      pf0 = embg[(bbase + m00 + ((ci_) + 2) * 64 + rA) * 16 + chA];  \
      pf1 = embg[(bbase + m00 + ((ci_) + 2) * 64 + rB) * 16 + chA];  \
    }                                                                \
  }

  // ================= PASS 1: histogram (only d2 <= 100 counted) =================
  STAGE_FIRST()
#pragma unroll 1
  for (int ci = 0; ci < 8; ++ci) {
    const int m0 = ci << 6;
    __syncthreads();  // B1: eM(ci) visible
    CHUNK_MFMA_R()
#pragma unroll
    for (int reg = 0; reg < 4; ++reg) {
      int row = rt * 16 + quad * 4 + reg;
      int c0 = ct0 * 16 + lr, c1 = c0 + 16;
      float d20 = fmaxf(sqN[row] + sqMp[m0 + c0] - 2.f * acc0[reg], 0.f);
      float d21 = fmaxf(sqN[row] + sqMp[m0 + c1] - 2.f * acc1[reg], 0.f);
      if (__float_as_uint(d20) <= 0x42C80000u) {
        int bk0 = min(63, (int)(d20 * 0.64f));
        atomicAdd(&hist[bk0 * 32 + (row >> 1)], 1u << (16 * (row & 1)));
      }
      if (__float_as_uint(d21) <= 0x42C80000u) {
        int bk1 = min(63, (int)(d21 * 0.64f));
        atomicAdd(&hist[bk1 * 32 + (row >> 1)], 1u << (16 * (row & 1)));
      }
    }
    __syncthreads();  // B2: eM frag reads done -> restage safe
    RESTAGE(ci)
  }
  __syncthreads();  // hist complete

  // ============ bound extraction + cross-part share ============
  if (tid < 64) {
    int cum = 0, kb = 63;
    const int sh = 16 * (tid & 1);
#pragma unroll 1
    for (int k2 = 0; k2 < 64; ++k2) {
      cum += (hist[k2 * 32 + (tid >> 1)] >> sh) & 0xFFFFu;
      if (cum >= 24) { kb = k2; break; }
    }
    float edge = (float)(kb + 2) * 1.5625f;
    atomicMin(&thr_g[gbase + tid], __float_as_uint(edge));
    unsigned tg = thr_g[gbase + tid];  // import (stale-larger is safe)
    int kImp = min(63, (int)(__uint_as_float(tg) * 0.64f));
    collectK[tid] = min(kb, kImp);
    cnt[tid] = 0;
  }
#pragma unroll
  for (int i = 0; i < 6; ++i) {  // cand sentinel init (64*48 = 3072)
    cand[tid + 512 * i] = ~0ULL;
  }
  __syncthreads();  // collectK/cnt/cand ready; pass-1 eM reads done

  // ================= PASS 2: collect =================
  STAGE_FIRST()
#pragma unroll 1
  for (int ci = 0; ci < 8; ++ci) {
    const int m0 = ci << 6;
    __syncthreads();  // B1
    CHUNK_MFMA_R()
#pragma unroll
    for (int reg = 0; reg < 4; ++reg) {
      int row = rt * 16 + quad * 4 + reg;
      int c0 = ct0 * 16 + lr, c1 = c0 + 16;
      float d20 = fmaxf(sqN[row] + sqMp[m0 + c0] - 2.f * acc0[reg], 0.f);
      float d21 = fmaxf(sqN[row] + sqMp[m0 + c1] - 2.f * acc1[reg], 0.f);
      int kc = collectK[row];
      unsigned bi0 = __float_as_uint(d20), bi1 = __float_as_uint(d21);
      int bk0 = min(63, (int)(d20 * 0.64f));
      int bk1 = min(63, (int)(d21 * 0.64f));
      if (bk0 <= kc && bi0 <= 0x42C80000u) {
        int pos = atomicAdd(&cnt[row], 1);
        if (pos < 48) cand[row * 48 + pos] = ((unsigned long long)bi0 << 32) | (unsigned)(m00 + m0 + c0);
      }
      if (bk1 <= kc && bi1 <= 0x42C80000u) {
        int pos = atomicAdd(&cnt[row], 1);
        if (pos < 48) cand[row * 48 + pos] = ((unsigned long long)bi1 << 32) | (unsigned)(m00 + m0 + c1);
      }
    }
    __syncthreads();  // B2
    RESTAGE(ci)
  }
  __syncthreads();  // cand complete, visible to all

  // ====== sorted top-24 extraction: 8 lanes per row, shfl_xor min-reduce ======
  {
    const int row8 = tid >> 3, sub = tid & 7;
    unsigned long long last = 0;
    unsigned long long* op = part + ((size_t)bid * 64 + row8) * 24;
#pragma unroll 1
    for (int k = 0; k < 24; ++k) {
      unsigned long long lm = ~0ULL;
#pragma unroll
      for (int j2 = 0; j2 < 6; ++j2) {
        int p2 = sub + 8 * j2;
        unsigned long long v2 = cand[row8 * 48 + p2];
        if ((k == 0 || v2 > last) && v2 < lm) lm = v2;
      }
#pragma unroll
      for (int s2 = 1; s2 < 8; s2 <<= 1) {
        unsigned long long o2 = __shfl_xor(lm, s2);
        if (o2 < lm) lm = o2;
      }
      if (sub == 0) op[k] = lm;  // sentinels ok; k_merge cuts
      last = lm;
    }
  }
}

// ---------------- K3b: merge 8 sorted partials per row (256 blocks x 64 thr)
__global__ __launch_bounds__(64) void k_merge(const unsigned long long* __restrict__ part,
                                              int* __restrict__ row_idx,
                                              int* __restrict__ row_cnt,
                                              int* __restrict__ col_cnt) {
  const int row = blockIdx.x * 64 + threadIdx.x;  // b*4096 + n
  const int b = row >> 12;
  const int n = row & 4095;
  const int nt = n >> 6, r = n & 63;
  const size_t gb = (size_t)(((b << 6) | nt) << 3);  // block base (b,nt,mp=0)
  unsigned long long h[8];
  int pp[8];
#pragma unroll
  for (int t = 0; t < 8; ++t) {
    h[t] = part[((gb + t) * 64 + r) * 24];
    pp[t] = 0;
  }
  int cnt = 0;
  const int base = row * KNN;
  for (int k = 0; k < 24; ++k) {
    int bs = 0;
    unsigned long long mv = h[0];
#pragma unroll
    for (int t = 1; t < 8; ++t)
      if (h[t] < mv) { mv = h[t]; bs = t; }
    if ((unsigned)(mv >> 32) > 0x42C80000u) break;  // sentinel / beyond threshold
    int mi = (int)(mv & 0xFFFFFFFFu);
    row_idx[base + cnt] = mi;
    atomicAdd(&col_cnt[(b << 12) + mi], 1);
    ++cnt;
    int np = ++pp[bs];
    h[bs] = (np < 24) ? part[((gb + bs) * 64 + r) * 24 + np] : ~0ULL;
  }
  row_cnt[row] = cnt;
#pragma unroll 4
  for (int j = cnt; j < 24; ++j) row_idx[base + j] = n;  // pad with self (valid gather idx)
}

// ---------------- K4: exclusive scan of col_cnt (16384 entries), 1 block
__global__ __launch_bounds__(256) void k_scan(const int* __restrict__ col_cnt,
                                              int* __restrict__ col_start,
                                              int* __restrict__ col_cursor) {
  __shared__ int part[256];
  const int tid = threadIdx.x;
  const int base = tid * 64;
  int s = 0;
  for (int j = 0; j < 64; ++j) s += col_cnt[base + j];
  part[tid] = s;
  __syncthreads();
  for (int off = 1; off < 256; off <<= 1) {
    int v = (tid >= off) ? part[tid - off] : 0;
    __syncthreads();
    part[tid] += v;
    __syncthreads();
  }
  int run = part[tid] - s;
  for (int j = 0; j < 64; ++j) {
    col_start[base + j] = run;
    col_cursor[base + j] = run;
    run += col_cnt[base + j];
  }
}

// ---------------- K5: fill CSC column lists (256 blocks x 64 thr)
__global__ __launch_bounds__(64) void k_fill(const int* __restrict__ row_idx,
                                             const int* __restrict__ row_cnt,
                                             int* __restrict__ col_cursor,
                                             int* __restrict__ col_list) {
  const int row = blockIdx.x * 64 + threadIdx.x;
  const int b = row >> 12;
  const int cnt = row_cnt[row];
  for (int j = 0; j < cnt; ++j) {
    int m = row_idx[row * KNN + j];
    int pos = atomicAdd(&col_cursor[(b << 12) + m], 1);
    col_list[pos] = row & 4095;
  }
}

#define BF2F_LO(u) __uint_as_float(((u) & 0xFFFFu) << 16)
#define BF2F_HI(u) __uint_as_float((u) & 0xFFFF0000u)

// ---------------- K6 v20: Yd from bf16 xlin; OUTPUT bf16 too (halves k_out2's gather)
__global__ __launch_bounds__(256) void k_yd(const unsigned short* __restrict__ xlin_h,
                                            const int* __restrict__ col_cnt,
                                            const int* __restrict__ col_start,
                                            const int* __restrict__ col_list,
                                            unsigned short* __restrict__ yd_h) {
  const int le = threadIdx.x >> 6;
  const int c4 = threadIdx.x & 63;
  const int be = blockIdx.x * 4 + le;
  const int b = be >> 12;
  const int deg = col_cnt[be];
  const int start = col_start[be];
  float4 acc = make_float4(0.f, 0.f, 0.f, 0.f);
  int j = 0;
  for (; j + 3 < deg; j += 4) {
    int ma = col_list[start + j], mb2 = col_list[start + j + 1];
    int mc = col_list[start + j + 2], md = col_list[start + j + 3];
    uint2 va = *(const uint2*)&xlin_h[(((size_t)(b << 12) + ma) << 8) + c4 * 4];
    uint2 vb = *(const uint2*)&xlin_h[(((size_t)(b << 12) + mb2) << 8) + c4 * 4];
    uint2 vc = *(const uint2*)&xlin_h[(((size_t)(b << 12) + mc) << 8) + c4 * 4];
    uint2 vd = *(const uint2*)&xlin_h[(((size_t)(b << 12) + md) << 8) + c4 * 4];
    acc.x += (BF2F_LO(va.x) + BF2F_LO(vb.x)) + (BF2F_LO(vc.x) + BF2F_LO(vd.x));
    acc.y += (BF2F_HI(va.x) + BF2F_HI(vb.x)) + (BF2F_HI(vc.x) + BF2F_HI(vd.x));
    acc.z += (BF2F_LO(va.y) + BF2F_LO(vb.y)) + (BF2F_LO(vc.y) + BF2F_LO(vd.y));
    acc.w += (BF2F_HI(va.y) + BF2F_HI(vb.y)) + (BF2F_HI(vc.y) + BF2F_HI(vd.y));
  }
  for (; j < deg; ++j) {
    int m = col_list[start + j];
    uint2 v = *(const uint2*)&xlin_h[(((size_t)(b << 12) + m) << 8) + c4 * 4];
    acc.x += BF2F_LO(v.x); acc.y += BF2F_HI(v.x);
    acc.z += BF2F_LO(v.y); acc.w += BF2F_HI(v.y);
  }
  float inv = 1.f / (float)deg;
  unsigned p0 = (unsigned)f2bf(acc.x * inv) | ((unsigned)f2bf(acc.y * inv) << 16);
  unsigned p1 = (unsigned)f2bf(acc.z * inv) | ((unsigned)f2bf(acc.w * inv) << 16);
  *(uint2*)&yd_h[((size_t)be << 8) + c4 * 4] = make_uint2(p0, p1);
}

// ---------------- K7 v20: fused g = avg(Yd gather) + residual x + BN partial sums.
// Replaces k_out2 + k_res_bn: saves 16MB outf re-read + 16MB rewrite + 1 launch.
// BN sums: per-thread over its 4 rows -> LDS ds_add_f32 pre-reduce (4 contenders/ch)
// -> 2 global atomics per channel per block (1024/address total).
__global__ __launch_bounds__(256) void k_out2(const unsigned short* __restrict__ yd_h,
                                              const int* __restrict__ row_idx,
                                              const int* __restrict__ row_cnt,
                                              const float* __restrict__ x,
                                              float* __restrict__ outf,
                                              float* __restrict__ bn_sum,
                                              float* __restrict__ bn_sumsq) {
  __shared__ float xt[16 * 260];   // [j][c] residual tile (transposed from [B,C,N])
  __shared__ float bnS[256], bnQ[256];
  const int b = blockIdx.x >> 8;
  const int nt = blockIdx.x & 255;
  const int n0g = nt * 16;
  const int tid = threadIdx.x;
  const int le = tid >> 6;
  const int c4 = tid & 63;
  bnS[tid] = 0.f;
  bnQ[tid] = 0.f;
#pragma unroll
  for (int i = 0; i < 16; ++i) {
    int idx = tid + 256 * i;
    int c = idx >> 4, j = idx & 15;
    xt[j * 260 + c] = x[((size_t)(b * CD + c)) * NB + n0g + j];
  }
  __syncthreads();
  float4 s4 = make_float4(0.f, 0.f, 0.f, 0.f);
  float4 q4 = make_float4(0.f, 0.f, 0.f, 0.f);
  for (int ii = 0; ii < 4; ++ii) {
    int jr = le * 4 + ii;
    int n = n0g + jr;
    int row = (b << 12) + n;
    int cnt = row_cnt[row];
    int idx[24];
    const int4* ip = (const int4*)(row_idx + (size_t)row * KNN);
#pragma unroll
    for (int t = 0; t < 6; ++t) {
      int4 v = ip[t];
      idx[4 * t] = v.x; idx[4 * t + 1] = v.y; idx[4 * t + 2] = v.z; idx[4 * t + 3] = v.w;
    }
    float4 acc = make_float4(0.f, 0.f, 0.f, 0.f);
#pragma unroll
    for (int j = 0; j < 24; ++j) {
      float wgt = (j < cnt) ? 1.f : 0.f;
      uint2 v = *(const uint2*)&yd_h[(((size_t)(b << 12) + idx[j]) << 8) + c4 * 4];
      acc.x = fmaf(wgt, BF2F_LO(v.x), acc.x);
      acc.y = fmaf(wgt, BF2F_HI(v.x), acc.y);
      acc.z = fmaf(wgt, BF2F_LO(v.y), acc.z);
      acc.w = fmaf(wgt, BF2F_HI(v.y), acc.w);
    }
    float inv = 1.f / (float)cnt;
    float4 xv = *(const float4*)&xt[jr * 260 + 4 * c4];
    float4 o;
    o.x = fmaf(acc.x, inv, xv.x);
    o.y = fmaf(acc.y, inv, xv.y);
    o.z = fmaf(acc.z, inv, xv.z);
    o.w = fmaf(acc.w, inv, xv.w);
    *(float4*)&outf[((size_t)row << 8) + c4 * 4] = o;
    s4.x += o.x; s4.y += o.y; s4.z += o.z; s4.w += o.w;
    q4.x = fmaf(o.x, o.x, q4.x); q4.y = fmaf(o.y, o.y, q4.y);
    q4.z = fmaf(o.z, o.z, q4.z); q4.w = fmaf(o.w, o.w, q4.w);
  }
  atomicAdd(&bnS[4 * c4 + 0], s4.x);
  atomicAdd(&bnS[4 * c4 + 1], s4.y);
  atomicAdd(&bnS[4 * c4 + 2], s4.z);
  atomicAdd(&bnS[4 * c4 + 3], s4.w);
  atomicAdd(&bnQ[4 * c4 + 0], q4.x);
  atomicAdd(&bnQ[4 * c4 + 1], q4.y);
  atomicAdd(&bnQ[4 * c4 + 2], q4.z);
  atomicAdd(&bnQ[4 * c4 + 3], q4.w);
  __syncthreads();
  atomicAdd(&bn_sum[tid], bnS[tid]);
  atomicAdd(&bn_sumsq[tid], bnQ[tid]);
}

// ---------------- K10: BN (per-block recompute) + SiLU + transpose
__global__ __launch_bounds__(256) void k_write(const float* __restrict__ outf,
                                               const float* __restrict__ bn_sum,
                                               const float* __restrict__ bn_sumsq,
                                               const float* __restrict__ gamma,
                                               const float* __restrict__ beta,
                                               float* __restrict__ out) {
  __shared__ float tile[64 * 257];
  __shared__ float sc[256], sh[256];
  const int b = blockIdx.x >> 6;
  const int n0 = (blockIdx.x & 63) << 6;
  const int tid = threadIdx.x;
  {
    const float inv = 1.f / 16384.f;
    float mean = bn_sum[tid] * inv;
    float var = bn_sumsq[tid] * inv - mean * mean;
    float scf = gamma[tid] * rsqrtf(var + 1e-5f);
    sc[tid] = scf;
    sh[tid] = beta[tid] - mean * scf;
  }
  __syncthreads();
#pragma unroll 4
  for (int i = 0; i < 64; ++i) {
    int idx = tid + 256 * i;
    int n = idx >> 8, c = idx & 255;
    float v = outf[(((size_t)(b << 12) + n0 + n) << 8) + c];
    v = fmaf(v, sc[c], sh[c]);
    float w = v / (1.f + expf(-v));  // SiLU
    tile[n * 257 + c] = w;
  }
  __syncthreads();
  const int nl = tid & 63;
  const int cg = tid >> 6;
#pragma unroll 4
  for (int j = 0; j < 64; ++j) {
    int c = cg * 64 + j;
    out[((size_t)(b * CD + c)) * NB + n0 + nl] = tile[nl * 257 + c];
  }
}

extern "C" void kernel_launch(void* const* d_in, const int* in_sizes, int n_in,
                              void* d_out, int out_size, void* d_ws, size_t ws_size,
                              hipStream_t stream) {
  const float* x      = (const float*)d_in[0];
  const float* fc_w   = (const float*)d_in[1];
  const float* fc_b   = (const float*)d_in[2];
  const float* dist_w = (const float*)d_in[3];
  const float* gamma  = (const float*)d_in[4];
  const float* beta   = (const float*)d_in[5];
  float* out = (float*)d_out;
  char* ws = (char*)d_ws;

  const size_t OFF_EHL   = 0;                   // 4 MB
  const size_t OFF_XLIN  = (size_t)4 << 20;     // 8 MB used (bf16)
  const size_t OFF_YD    = (size_t)20 << 20;    // 8 MB used (bf16); part overlay spans yd+outf (both dead then)
  const size_t OFF_OUTF  = (size_t)36 << 20;    // 16 MB
  const size_t OFF_SQ    = (size_t)52 << 20;
  const size_t OFF_RIDX  = OFF_SQ + 65536;
  const size_t OFF_RCNT  = OFF_RIDX + 1572864;
  const size_t OFF_CCNT  = OFF_RCNT + 65536;
  const size_t OFF_CSTART = OFF_CCNT + 65536;
  const size_t OFF_CCUR  = OFF_CSTART + 65536;
  const size_t OFF_CLIST = OFF_CCUR + 65536;
  const size_t OFF_BNS   = OFF_CLIST + 1572864;
  const size_t OFF_BNQ   = OFF_BNS + 1024;
  const size_t OFF_THRG  = OFF_BNQ + 1024;      // 64 KB global per-row kNN threshold
  const size_t OFF_WHL   = OFF_THRG + 65536;    // 256 KB fc_w bf16 hi/lo split
  const size_t TOTAL = OFF_WHL + 262144;
  if (ws_size < TOTAL) return;

  unsigned* emb_hl = (unsigned*)(ws + OFF_EHL);
  unsigned short* xlin_h = (unsigned short*)(ws + OFF_XLIN);
  unsigned short* yd_h = (unsigned short*)(ws + OFF_YD);
  float* outf  = (float*)(ws + OFF_OUTF);
  unsigned long long* part = (unsigned long long*)(ws + OFF_YD);  // 25.2 MB overlay (yd+outf dead here)
  float* sq    = (float*)(ws + OFF_SQ);
  int* row_idx = (int*)(ws + OFF_RIDX);
  int* row_cnt = (int*)(ws + OFF_RCNT);
  int* col_cnt = (int*)(ws + OFF_CCNT);
  int* col_start = (int*)(ws + OFF_CSTART);
  int* col_cursor = (int*)(ws + OFF_CCUR);
  int* col_list = (int*)(ws + OFF_CLIST);
  float* bn_sum = (float*)(ws + OFF_BNS);
  float* bn_sumsq = (float*)(ws + OFF_BNQ);
  unsigned* thr_g = (unsigned*)(ws + OFF_THRG);
  unsigned* w_hl = (unsigned*)(ws + OFF_WHL);

  hipMemsetAsync(col_cnt, 0, 65536, stream);
  hipMemsetAsync(bn_sum, 0, 2048, stream);

  k_emb<<<256, 256, 0, stream>>>(x, dist_w, emb_hl, sq, thr_g);
  k_wsplit<<<32, 256, 0, stream>>>(fc_w, w_hl);
  k_xlin<<<1024, 512, 0, stream>>>(x, w_hl, fc_b, xlin_h);
  k_distp<<<2048, 512, 0, stream>>>(emb_hl, sq, thr_g, part);
  k_merge<<<256, 64, 0, stream>>>(part, row_idx, row_cnt, col_cnt);
  k_scan<<<1, 256, 0, stream>>>(col_cnt, col_start, col_cursor);
  k_fill<<<256, 64, 0, stream>>>(row_idx, row_cnt, col_cursor, col_list);
  k_yd<<<4096, 256, 0, stream>>>(xlin_h, col_cnt, col_start, col_list, yd_h);
  k_out2<<<1024, 256, 0, stream>>>(yd_h, row_idx, row_cnt, x, outf, bn_sum, bn_sumsq);
  k_write<<<256, 256, 0, stream>>>(outf, bn_sum, bn_sumsq, gamma, beta, out);
}